// Round 2
// baseline (685.928 us; speedup 1.0000x reference)
//
#include <hip/hip_runtime.h>

// Problem constants (B,S,D,H fixed by the reference)
#define Bsz 4
#define Ssz 2048
#define Dsz 1024
#define Hsz 4
#define HDsz 256
#define Msz 8192  // Bsz*Ssz

typedef unsigned short u16;
typedef __attribute__((ext_vector_type(8))) short bf16x8;  // 8 bf16 in 4 VGPRs
typedef __attribute__((ext_vector_type(4))) float f32x4;

__device__ __forceinline__ u16 f2b(float f) {  // fp32 -> bf16 RNE
  unsigned u = __float_as_uint(f);
  return (u16)((u + 0x7FFFu + ((u >> 16) & 1u)) >> 16);
}
__device__ __forceinline__ unsigned pk2(float a, float b) {
  return (unsigned)f2b(a) | ((unsigned)f2b(b) << 16);
}

// async global->LDS, 16B per lane; LDS dest = wave-uniform base + lane*16
typedef const unsigned int __attribute__((address_space(1)))* gcp;
typedef unsigned int __attribute__((address_space(3)))* lcp;
__device__ __forceinline__ void gld16(const u16* g, u16* l) {
  __builtin_amdgcn_global_load_lds((gcp)g, (lcp)l, 16, 0, 0);
}

// ---------------------------------------------------------------------------
// fp32 -> bf16 elementwise
// ---------------------------------------------------------------------------
__global__ __launch_bounds__(256) void cvt_bf16(const float4* __restrict__ in,
                                                u16* __restrict__ outp) {
  size_t i = (size_t)blockIdx.x * 256 + threadIdx.x;
  float4 v = in[i];
  uint2 r; r.x = pk2(v.x, v.y); r.y = pk2(v.z, v.w);
  *(uint2*)(outp + i * 4) = r;
}

// ---------------------------------------------------------------------------
// bf16 MFMA GEMM: C[M,N] = A[M,K]*W[N,K]^T (+bias).
// 128x128 tile, BK=32, global_load_lds width-16 staging, DOUBLE-BUFFERED
// LDS with prefetch issued before compute (one barrier per K-step: the
// barrier drains the prefetch that had the whole previous compute phase
// to land). 4 waves x (4x4 of 16x16x32 MFMA). M=8192, N=K=1024.
// ---------------------------------------------------------------------------
__global__ __launch_bounds__(256) void gemm_lds(const u16* __restrict__ A16,
                                                const u16* __restrict__ Wb,
                                                const float* __restrict__ bias,
                                                float* __restrict__ C32,
                                                u16* __restrict__ Cbf) {
  __shared__ u16 sA[2][128 * 32];
  __shared__ u16 sB[2][128 * 32];
  const int tid = threadIdx.x;
  const int lane = tid & 63, quad = lane >> 4, l15 = lane & 15;
  const int w = tid >> 6;
  const int mw = (w >> 1) * 64, nw = (w & 1) * 64;
  const int m0 = blockIdx.y * 128, n0 = blockIdx.x * 128;
  const int r0 = tid >> 2, seg = (tid & 3) * 8;  // 4 lanes x 16B per row
  const u16* ga0 = A16 + (size_t)(m0 + r0) * Dsz + seg;
  const u16* gb0 = Wb + (size_t)(n0 + r0) * Dsz + seg;
  f32x4 acc[4][4] = {};
  {  // prologue: prefetch k0=0 into buffer 0
    gld16(ga0, &sA[0][w * 512]);
    gld16(ga0 + (size_t)64 * Dsz, &sA[0][2048 + w * 512]);
    gld16(gb0, &sB[0][w * 512]);
    gld16(gb0 + (size_t)64 * Dsz, &sB[0][2048 + w * 512]);
  }
  int buf = 0;
  for (int k0 = 0; k0 < Dsz; k0 += 32) {
    __syncthreads();  // drains prefetch vmcnt for 'buf'; fences prev reads
    if (k0 + 32 < Dsz) {
      const int kn = k0 + 32, bn = buf ^ 1;
      gld16(ga0 + kn, &sA[bn][w * 512]);
      gld16(ga0 + (size_t)64 * Dsz + kn, &sA[bn][2048 + w * 512]);
      gld16(gb0 + kn, &sB[bn][w * 512]);
      gld16(gb0 + (size_t)64 * Dsz + kn, &sB[bn][2048 + w * 512]);
    }
    bf16x8 af[4], bfr[4];
#pragma unroll
    for (int i = 0; i < 4; ++i) {
      af[i] = *(const bf16x8*)&sA[buf][(mw + i * 16 + l15) * 32 + quad * 8];
      bfr[i] = *(const bf16x8*)&sB[buf][(nw + i * 16 + l15) * 32 + quad * 8];
    }
#pragma unroll
    for (int i = 0; i < 4; ++i)
#pragma unroll
      for (int j = 0; j < 4; ++j)
        acc[i][j] = __builtin_amdgcn_mfma_f32_16x16x32_bf16(af[i], bfr[j], acc[i][j], 0, 0, 0);
    buf ^= 1;
  }
#pragma unroll
  for (int j = 0; j < 4; ++j) {
    const int n = n0 + nw + j * 16 + l15;
    const float bv = bias ? bias[n] : 0.f;
#pragma unroll
    for (int i = 0; i < 4; ++i) {
#pragma unroll
      for (int r = 0; r < 4; ++r) {
        const int m = m0 + mw + i * 16 + quad * 4 + r;
        const float val = acc[i][j][r] + bv;
        const size_t idx = (size_t)m * Dsz + n;
        if (C32) C32[idx] = val;
        if (Cbf) Cbf[idx] = f2b(val);
      }
    }
  }
}

// ---------------------------------------------------------------------------
// V [b][s][h*256+e] fp32 -> V^T bf16 [bh][e][s]
// ---------------------------------------------------------------------------
__global__ __launch_bounds__(256) void transpose_v(const float* __restrict__ V,
                                                   u16* __restrict__ Vt) {
  __shared__ u16 tile[32 * 36];
  const int t = threadIdx.x;
  const int s0 = blockIdx.x * 32, e0 = blockIdx.y * 32, bh = blockIdx.z;
  const int b = bh >> 2, h = bh & 3;
  {
    const int s_l = t >> 3, e8 = (t & 7) * 4;
    float4 v = *(const float4*)(V + ((size_t)(b * Ssz) + s0 + s_l) * Dsz + h * HDsz + e0 + e8);
    uint2 r; r.x = pk2(v.x, v.y); r.y = pk2(v.z, v.w);
    *(uint2*)&tile[s_l * 36 + e8] = r;
  }
  __syncthreads();
  {
    const int e_l = t >> 3, s4 = (t & 7) * 4;
    u16 a = tile[(s4 + 0) * 36 + e_l], b2 = tile[(s4 + 1) * 36 + e_l];
    u16 c = tile[(s4 + 2) * 36 + e_l], d = tile[(s4 + 3) * 36 + e_l];
    uint2 r; r.x = (unsigned)a | ((unsigned)b2 << 16);
    r.y = (unsigned)c | ((unsigned)d << 16);
    *(uint2*)(Vt + ((size_t)bh * HDsz + e0 + e_l) * Ssz + s0 + s4) = r;
  }
}

// ---------------------------------------------------------------------------
// Flash attention, bf16 MFMA, flash-decoding split-K.
// Q-block = 128 rows, 8 waves (512 threads): same 64 KB double-buffered
// K/V LDS as before now feeds 2x the waves -> 16 waves/CU at 2 blocks/CU.
// Work split into 32 chunks per bh (table below, heaviest first, sizes
// 4..24 KV tiles; 32 chunks x 16 bh = 512 blocks = exactly full residency).
// qt 0..3: single chunk (normalized direct). qt 4..11: 2 chunks.
// qt 12..15: 3 chunks. Non-primary chunks write unnormalized O to Pb
// (fp32, 16 slots/bh x 128KB = d_out scratch); all chunks of split qt
// write (m,l) to mlb; attn_merge combines.
//
// K/V staged via global_load_lds (width 16), LDS dest linear, bank
// conflicts avoided by XOR-swizzling the 16B slot on the GLOBAL source
// and applying the same involution on the ds_read side:
//   sK phys slot p at row r holds logical slot p ^ (r&7)       (row = s)
//   sV phys slot p at row r holds logical slot p ^ ((r>>1)&3)  (row = e)
// One __syncthreads per KV tile; prefetch of tile k+1 is issued right
// after the barrier so its latency hides under QK/softmax/PV of tile k.
// ---------------------------------------------------------------------------
#define CH(qt, k, lo, hi) \
  ((unsigned)(qt) | ((unsigned)(k) << 8) | ((unsigned)(lo) << 16) | ((unsigned)(hi) << 24))

__global__ __launch_bounds__(512, 4) void attn_mfma(const u16* __restrict__ Qg,
                                                    const u16* __restrict__ Kg,
                                                    const u16* __restrict__ Vtg,
                                                    float* __restrict__ At,
                                                    float* __restrict__ Pb,
                                                    float* __restrict__ mlb) {
  static const unsigned int tab[32] = {
      CH(11, 0, 0, 24), CH(11, 1, 24, 48), CH(10, 0, 0, 22), CH(10, 1, 22, 44),
      CH(15, 0, 0, 22), CH(15, 1, 22, 43), CH(15, 2, 43, 64), CH(9, 0, 0, 20),
      CH(9, 1, 20, 40),  CH(14, 0, 0, 20), CH(14, 1, 20, 40), CH(14, 2, 40, 60),
      CH(13, 0, 0, 19),  CH(13, 1, 19, 38), CH(13, 2, 38, 56), CH(8, 0, 0, 18),
      CH(8, 1, 18, 36),  CH(12, 0, 0, 18), CH(12, 1, 18, 35), CH(12, 2, 35, 52),
      CH(7, 0, 0, 16),   CH(7, 1, 16, 32), CH(3, 0, 0, 16),   CH(6, 0, 0, 14),
      CH(6, 1, 14, 28),  CH(5, 0, 0, 12),  CH(5, 1, 12, 24),  CH(2, 0, 0, 12),
      CH(4, 0, 0, 10),   CH(4, 1, 10, 20), CH(1, 0, 0, 8),    CH(0, 0, 0, 4)};
  const unsigned int e = tab[blockIdx.x];
  const int qt = e & 255, ck = (e >> 8) & 255;
  const int kt_lo = (e >> 16) & 255, kt_hi = e >> 24;
  const int nc = (qt < 4) ? 1 : ((qt < 12) ? 2 : 3);
  const int bh = blockIdx.y, b = bh >> 2, h = bh & 3;
  const int tid = threadIdx.x, w = tid >> 6, lane = tid & 63;
  const int quad = lane >> 4, l15 = lane & 15;
  __shared__ u16 sK[2][32 * 256];   // [buf][s-row][d-col], slots swizzled by row&7
  __shared__ u16 sV[2][256 * 32];   // [buf][e-row][s-col], slots swizzled by (row>>1)&3
  const int q0w = qt * 128 + w * 16;
  bf16x8 qf[8];
  {
    const u16* qp = Qg + ((size_t)(b * Ssz) + q0w + l15) * Dsz + h * HDsz + quad * 8;
#pragma unroll
    for (int dd = 0; dd < 8; ++dd) qf[dd] = *(const bf16x8*)(qp + dd * 32);
  }
  f32x4 o[16] = {};
  float m_old = -1e30f, l = 0.f;
  // Staging source pointers (per-thread; swizzled GLOBAL column, linear LDS):
  // K: thread covers row (tid>>5)+i*16, 16B slot (tid&31); content slot is
  //    (tid&31)^(row&7); row&7 == (tid>>5)&7 for both calls.
  // V: thread covers row (tid>>2)+i*128, slot (tid&3); content slot is
  //    (tid&3)^((row>>1)&3); (row>>1)&3 == (tid>>3)&3 for both calls.
  const u16* kstage = Kg + ((size_t)(b * Ssz) + (tid >> 5)) * Dsz + h * HDsz
                      + (((tid & 31) ^ ((tid >> 5) & 7)) << 3);
  const u16* vstage = Vtg + ((size_t)bh * HDsz + (tid >> 2)) * Ssz
                      + (((tid & 3) ^ ((tid >> 3) & 3)) << 3);
  int bufc = 0;
  {  // prologue: prefetch first tile into buffer 0
    const u16* kp = kstage + (size_t)(kt_lo * 32) * Dsz;
    const u16* vp = vstage + kt_lo * 32;
#pragma unroll
    for (int i = 0; i < 2; ++i) {
      gld16(kp + (size_t)i * 16 * Dsz, &sK[0][w * 512 + i * 4096]);
      gld16(vp + (size_t)i * 128 * Ssz, &sV[0][w * 512 + i * 4096]);
    }
  }
  for (int kt = kt_lo; kt < kt_hi; ++kt) {
    const int j0 = kt * 32;
    __syncthreads();  // drains prefetch vmcnt; fences prev compute's LDS reads
    if (kt + 1 < kt_hi) {  // prefetch next tile into the other buffer
      const u16* kp = kstage + (size_t)((kt + 1) * 32) * Dsz;
      const u16* vp = vstage + (kt + 1) * 32;
      const int bn = bufc ^ 1;
#pragma unroll
      for (int i = 0; i < 2; ++i) {
        gld16(kp + (size_t)i * 16 * Dsz, &sK[bn][w * 512 + i * 4096]);
        gld16(vp + (size_t)i * 128 * Ssz, &sV[bn][w * 512 + i * 4096]);
      }
    }
    f32x4 s0v = {}, s1v = {};
#pragma unroll
    for (int dd = 0; dd < 8; ++dd) {
      const int c0 = ((dd * 4 + quad) ^ (l15 & 7)) << 3;  // (16+l15)&7 == l15&7
      bf16x8 a0 = *(const bf16x8*)&sK[bufc][l15 * 256 + c0];
      bf16x8 a1 = *(const bf16x8*)&sK[bufc][(16 + l15) * 256 + c0];
      s0v = __builtin_amdgcn_mfma_f32_16x16x32_bf16(a0, qf[dd], s0v, 0, 0, 0);
      s1v = __builtin_amdgcn_mfma_f32_16x16x32_bf16(a1, qf[dd], s1v, 0, 0, 0);
    }
    const int qg = q0w + l15;
    float p[8];
#pragma unroll
    for (int r = 0; r < 4; ++r) {
      const int kg = j0 + quad * 4 + r;
      p[r] = (kg <= qg) ? s0v[r] : -1e30f;
      p[4 + r] = (kg + 16 <= qg) ? s1v[r] : -1e30f;
    }
    float mt = p[0];
#pragma unroll
    for (int i = 1; i < 8; ++i) mt = fmaxf(mt, p[i]);
    mt = fmaxf(mt, __shfl_xor(mt, 16));
    mt = fmaxf(mt, __shfl_xor(mt, 32));
    const float m_new = fmaxf(m_old, mt);
    const float alpha = __expf(m_old - m_new);
    float ts = 0.f;
#pragma unroll
    for (int i = 0; i < 8; ++i) { p[i] = __expf(p[i] - m_new); ts += p[i]; }
    ts += __shfl_xor(ts, 16);
    ts += __shfl_xor(ts, 32);
    l = l * alpha + ts;
    m_old = m_new;
    if (!__all(alpha == 1.0f)) {
      const float a0_ = __shfl(alpha, (lane & 48) | (quad * 4 + 0));
      const float a1_ = __shfl(alpha, (lane & 48) | (quad * 4 + 1));
      const float a2_ = __shfl(alpha, (lane & 48) | (quad * 4 + 2));
      const float a3_ = __shfl(alpha, (lane & 48) | (quad * 4 + 3));
#pragma unroll
      for (int ds = 0; ds < 16; ++ds) {
        o[ds][0] *= a0_; o[ds][1] *= a1_; o[ds][2] *= a2_; o[ds][3] *= a3_;
      }
    }
    float xx[8];
#pragma unroll
    for (int i = 0; i < 8; ++i) xx[i] = __shfl_xor(p[i], 16);
    const bool qe = (quad & 1) == 0;
    float Alo[8], Ahi[8];
#pragma unroll
    for (int i = 0; i < 4; ++i) {
      Alo[i] = qe ? p[i] : xx[i];
      Alo[4 + i] = qe ? xx[i] : p[i];
      Ahi[i] = qe ? p[4 + i] : xx[4 + i];
      Ahi[4 + i] = qe ? xx[4 + i] : p[4 + i];
    }
    float zz[8];
    const bool sendlo = (quad & 1) != 0;
#pragma unroll
    for (int i = 0; i < 8; ++i) zz[i] = __shfl_xor(sendlo ? Alo[i] : Ahi[i], 32);
    float fin[8];
#pragma unroll
    for (int i = 0; i < 8; ++i)
      fin[i] = (quad == 0) ? Alo[i] : (quad == 3) ? Ahi[i] : zz[i];
    uint4 pkv;
    pkv.x = pk2(fin[0], fin[1]); pkv.y = pk2(fin[2], fin[3]);
    pkv.z = pk2(fin[4], fin[5]); pkv.w = pk2(fin[6], fin[7]);
    bf16x8 pf = *(bf16x8*)&pkv;
    const int vc0 = (quad ^ ((l15 >> 1) & 3)) << 3;  // (row>>1)&3 == (l15>>1)&3
#pragma unroll
    for (int ds = 0; ds < 16; ++ds) {
      bf16x8 bv = *(const bf16x8*)&sV[bufc][(ds * 16 + l15) * 32 + vc0];
      o[ds] = __builtin_amdgcn_mfma_f32_16x16x32_bf16(pf, bv, o[ds], 0, 0, 0);
    }
    bufc ^= 1;
  }
  if (nc == 1) {  // qt 0..3: single chunk, write normalized
    float lr[4];
#pragma unroll
    for (int r = 0; r < 4; ++r) lr[r] = 1.f / __shfl(l, (lane & 48) | (quad * 4 + r));
    float* ob = At + ((size_t)bh * Ssz + q0w + quad * 4) * HDsz + l15;
#pragma unroll
    for (int r = 0; r < 4; ++r)
#pragma unroll
      for (int ds = 0; ds < 16; ++ds)
        ob[(size_t)r * HDsz + ds * 16] = o[ds][r] * lr[r];
  } else {
    float* dst;
    if (ck == 0) {
      dst = At + ((size_t)bh * Ssz + q0w + quad * 4) * HDsz + l15;
    } else {
      const int sec = (qt < 12) ? (qt - 4) : (8 + (qt - 12) * 2 + (ck - 1));
      dst = Pb + (size_t)(bh * 16 + sec) * 32768
            + (size_t)(w * 16 + quad * 4) * HDsz + l15;
    }
#pragma unroll
    for (int r = 0; r < 4; ++r)
#pragma unroll
      for (int ds = 0; ds < 16; ++ds)
        dst[(size_t)r * HDsz + ds * 16] = o[ds][r];
    if (lane < 16) {
      const int mlbase = ((bh * 12 + (qt - 4)) * 3 + ck) * 256;
      const int mlrow = w * 16 + l15;
      mlb[mlbase + mlrow] = m_old;
      mlb[mlbase + 128 + mlrow] = l;
    }
  }
}

// ---------------------------------------------------------------------------
// Merge the split-K chunks for qt>=4: O = sum_c O_c*e^{m_c-m} / sum_c l_c*
// e^{m_c-m}.  grid (12, 16): blockIdx.x = qt-4, nc = 2 (qt<12) or 3.
// ---------------------------------------------------------------------------
__global__ __launch_bounds__(256) void attn_merge(float* __restrict__ At,
                                                  const float* __restrict__ Pb,
                                                  const float* __restrict__ mlb) {
  const int qq = blockIdx.x, bh = blockIdx.y;
  const int qt = qq + 4;
  const int nc = (qt < 12) ? 2 : 3;
  const int t = threadIdx.x;
  const int mlbase = (bh * 12 + qq) * 3 * 256;
  const int sec1 = (qt < 12) ? (qt - 4) : (8 + (qt - 12) * 2);
  float4* abase = (float4*)(At + ((size_t)bh * Ssz + (size_t)qt * 128) * HDsz);
  const float4* p1 = (const float4*)(Pb + (size_t)(bh * 16 + sec1) * 32768);
  const float4* p2 = p1 + 8192;
#pragma unroll
  for (int i = 0; i < 32; ++i) {
    const int f = i * 256 + t;  // f4 index 0..8191, coalesced
    const int qr = f >> 6;
    const float m0 = mlb[mlbase + qr],       l0 = mlb[mlbase + 128 + qr];
    const float m1 = mlb[mlbase + 256 + qr], l1 = mlb[mlbase + 384 + qr];
    float mm = fmaxf(m0, m1);
    float m2 = -1e30f, l2 = 0.f;
    if (nc == 3) {
      m2 = mlb[mlbase + 512 + qr]; l2 = mlb[mlbase + 640 + qr];
      mm = fmaxf(mm, m2);
    }
    const float w0 = __expf(m0 - mm), w1 = __expf(m1 - mm);
    const float w2 = (nc == 3) ? __expf(m2 - mm) : 0.f;
    const float inv = 1.f / (l0 * w0 + l1 * w1 + l2 * w2);
    float4 av = abase[f];
    float4 pv = p1[f];
    float4 ov;
    ov.x = av.x * w0 + pv.x * w1;
    ov.y = av.y * w0 + pv.y * w1;
    ov.z = av.z * w0 + pv.z * w1;
    ov.w = av.w * w0 + pv.w * w1;
    if (nc == 3) {
      float4 qv = p2[f];
      ov.x += qv.x * w2; ov.y += qv.y * w2;
      ov.z += qv.z * w2; ov.w += qv.w * w2;
    }
    ov.x *= inv; ov.y *= inv; ov.z *= inv; ov.w *= inv;
    abase[f] = ov;
  }
}

// ---------------------------------------------------------------------------
// Fused: sq=elu(q)+1, sk=elu(k)+1 (in place) + denq = sq.z, denk = sk.z.
// One wave per row; grid 8192 x 256.
// ---------------------------------------------------------------------------
__global__ __launch_bounds__(256) void eludens(float* __restrict__ Qb,
                                               float* __restrict__ Kb,
                                               const float* __restrict__ z,
                                               float* __restrict__ dq,
                                               float* __restrict__ dk) {
  const int wid = threadIdx.x >> 6, lane = threadIdx.x & 63;
  const int r = blockIdx.x * 4 + wid;
  const int b = r >> 13, h = (r >> 11) & 3, s = r & 2047;
  const size_t base = ((size_t)(b * Ssz + s)) * Dsz + h * HDsz + lane * 4;
  float4 z4 = *(const float4*)(z + h * HDsz + lane * 4);
  float4 q = *(float4*)(Qb + base);
  q.x = q.x > 0.f ? q.x + 1.f : __expf(q.x);
  q.y = q.y > 0.f ? q.y + 1.f : __expf(q.y);
  q.z = q.z > 0.f ? q.z + 1.f : __expf(q.z);
  q.w = q.w > 0.f ? q.w + 1.f : __expf(q.w);
  *(float4*)(Qb + base) = q;
  float4 k = *(float4*)(Kb + base);
  k.x = k.x > 0.f ? k.x + 1.f : __expf(k.x);
  k.y = k.y > 0.f ? k.y + 1.f : __expf(k.y);
  k.z = k.z > 0.f ? k.z + 1.f : __expf(k.z);
  k.w = k.w > 0.f ? k.w + 1.f : __expf(k.w);
  *(float4*)(Kb + base) = k;
  float pq = q.x * z4.x + q.y * z4.y + q.z * z4.z + q.w * z4.w;
  float pk = k.x * z4.x + k.y * z4.y + k.z * z4.z + k.w * z4.w;
#pragma unroll
  for (int off = 32; off; off >>= 1) {
    pq += __shfl_down(pq, off);
    pk += __shfl_down(pk, off);
  }
  if (lane == 0) { dq[r] = pq; dk[r] = pk; }
}

// ---------------------------------------------------------------------------
// Per-head MFMA GEMM: acc[m,e] = sum_d Asrc[m,h*256+d] * mem[h][d][e].
// mode 0: blend = g*acc/den + (1-g)*At -> bf16 row-major (bfout)
// mode 1: Vio = v - acc/den (fp32 in place)
// ---------------------------------------------------------------------------
__global__ __launch_bounds__(256) void memread_mfma(const float* __restrict__ Asrc,
                                                    const float* __restrict__ mem,
                                                    const float* __restrict__ dens,
                                                    const float* __restrict__ betas,
                                                    const float* __restrict__ At,
                                                    float* __restrict__ Vio,
                                                    u16* __restrict__ bfout, int mode) {
  const int h = blockIdx.z;
  const int tid = threadIdx.x, lane = tid & 63, w = tid >> 6;
  const int quad = lane >> 4, l15 = lane & 15;
  const int mw = (w >> 1) * 64, ew = (w & 1) * 64;
  const int m0 = blockIdx.y * 128, e0t = blockIdx.x * 128;
  __shared__ u16 sA[128 * 40];  // [m][k]
  __shared__ u16 sB[128 * 40];  // [e][k]
  const int srow = tid >> 1, sseg = (tid & 1) * 16;
  const int k4 = (tid & 7) * 4, e4 = (tid >> 3) * 4;
  f32x4 acc[4][4] = {};
  for (int k0 = 0; k0 < HDsz; k0 += 32) {
    __syncthreads();
    {
      const float* ap = Asrc + (size_t)(m0 + srow) * Dsz + h * HDsz + k0 + sseg;
      float4 f0 = *(const float4*)ap, f1 = *(const float4*)(ap + 4);
      float4 f2 = *(const float4*)(ap + 8), f3 = *(const float4*)(ap + 12);
      uint4 u0, u1;
      u0.x = pk2(f0.x, f0.y); u0.y = pk2(f0.z, f0.w);
      u0.z = pk2(f1.x, f1.y); u0.w = pk2(f1.z, f1.w);
      u1.x = pk2(f2.x, f2.y); u1.y = pk2(f2.z, f2.w);
      u1.z = pk2(f3.x, f3.y); u1.w = pk2(f3.z, f3.w);
      u16* dst = &sA[srow * 40 + sseg];
      *(uint4*)dst = u0; *(uint4*)(dst + 8) = u1;
    }
    {
      const float* bp = mem + (size_t)h * 65536 + (size_t)(k0 + k4) * HDsz + e0t + e4;
      float4 r0 = *(const float4*)bp;
      float4 r1 = *(const float4*)(bp + HDsz);
      float4 r2 = *(const float4*)(bp + 2 * HDsz);
      float4 r3 = *(const float4*)(bp + 3 * HDsz);
      const float* rr[4] = {(const float*)&r0, (const float*)&r1,
                            (const float*)&r2, (const float*)&r3};
#pragma unroll
      for (int c = 0; c < 4; ++c) {
        uint2 u;
        u.x = pk2(rr[0][c], rr[1][c]);
        u.y = pk2(rr[2][c], rr[3][c]);
        *(uint2*)&sB[(e4 + c) * 40 + k4] = u;
      }
    }
    __syncthreads();
    bf16x8 af[4], bfr[4];
#pragma unroll
    for (int i = 0; i < 4; ++i) {
      af[i] = *(const bf16x8*)&sA[(mw + i * 16 + l15) * 40 + quad * 8];
      bfr[i] = *(const bf16x8*)&sB[(ew + i * 16 + l15) * 40 + quad * 8];
    }
#pragma unroll
    for (int i = 0; i < 4; ++i)
#pragma unroll
      for (int j = 0; j < 4; ++j)
        acc[i][j] = __builtin_amdgcn_mfma_f32_16x16x32_bf16(af[i], bfr[j], acc[i][j], 0, 0, 0);
  }
  const float g = 1.f / (1.f + __expf(-betas[h]));
#pragma unroll
  for (int i = 0; i < 4; ++i) {
#pragma unroll
    for (int r = 0; r < 4; ++r) {
      const int m = m0 + mw + i * 16 + quad * 4 + r;
      const int b = m >> 11, s = m & 2047;
      const int rowidx = ((b << 2) + h) * Ssz + s;
      const float inv = 1.f / (dens[rowidx] + 1e-6f);
#pragma unroll
      for (int j = 0; j < 4; ++j) {
        const int e = e0t + ew + j * 16 + l15;
        const float av = acc[i][j][r] * inv;
        if (mode == 0) {
          const float a = At[(size_t)rowidx * HDsz + e];
          bfout[(size_t)m * Dsz + h * HDsz + e] = f2b(g * av + (1.f - g) * a);
        } else {
          float* p = Vio + (size_t)m * Dsz + h * HDsz + e;
          *p = *p - av;
        }
      }
    }
  }
}

// ---------------------------------------------------------------------------
// mem partials: P[(h*16+chunk)][d][e] = sum_{m in chunk} sk[m,..d]*W[m,..e]
// ---------------------------------------------------------------------------
__global__ __launch_bounds__(256) void mem_update_mfma(const float* __restrict__ SK,
                                                       const float* __restrict__ W,
                                                       float* __restrict__ P) {
  const int de = blockIdx.x;
  const int d0 = (de >> 1) * 128, e0 = (de & 1) * 128;
  const int h = blockIdx.y, chunk = blockIdx.z;
  const int m0 = chunk * 512;
  const int tid = threadIdx.x, lane = tid & 63, w = tid >> 6;
  const int quad = lane >> 4, l15 = lane & 15;
  const int dw = (w >> 1) * 64, ew = (w & 1) * 64;
  __shared__ u16 sA[128 * 40];  // [d][m]
  __shared__ u16 sB[128 * 40];  // [e][m]
  const int m4 = (tid & 7) * 4;
  const int c4 = (tid >> 3) * 4;
  f32x4 acc[4][4] = {};
  for (int mt = 0; mt < 512; mt += 32) {
    __syncthreads();
    const float* ka = SK + (size_t)(m0 + mt + m4) * Dsz + h * HDsz + d0 + c4;
    const float* wa = W + (size_t)(m0 + mt + m4) * Dsz + h * HDsz + e0 + c4;
    float4 a0 = *(const float4*)ka;
    float4 a1 = *(const float4*)(ka + Dsz);
    float4 a2 = *(const float4*)(ka + 2 * Dsz);
    float4 a3 = *(const float4*)(ka + 3 * Dsz);
    float4 b0 = *(const float4*)wa;
    float4 b1 = *(const float4*)(wa + Dsz);
    float4 b2 = *(const float4*)(wa + 2 * Dsz);
    float4 b3 = *(const float4*)(wa + 3 * Dsz);
    const float* aa[4] = {(const float*)&a0, (const float*)&a1,
                          (const float*)&a2, (const float*)&a3};
    const float* bb[4] = {(const float*)&b0, (const float*)&b1,
                          (const float*)&b2, (const float*)&b3};
#pragma unroll
    for (int c = 0; c < 4; ++c) {
      uint2 ua, ub2;
      ua.x = pk2(aa[0][c], aa[1][c]); ua.y = pk2(aa[2][c], aa[3][c]);
      ub2.x = pk2(bb[0][c], bb[1][c]); ub2.y = pk2(bb[2][c], bb[3][c]);
      *(uint2*)&sA[(c4 + c) * 40 + m4] = ua;
      *(uint2*)&sB[(c4 + c) * 40 + m4] = ub2;
    }
    __syncthreads();
    bf16x8 af[4], bfr[4];
#pragma unroll
    for (int i = 0; i < 4; ++i) {
      af[i] = *(const bf16x8*)&sA[(dw + i * 16 + l15) * 40 + quad * 8];
      bfr[i] = *(const bf16x8*)&sB[(ew + i * 16 + l15) * 40 + quad * 8];
    }
#pragma unroll
    for (int i = 0; i < 4; ++i)
#pragma unroll
      for (int j = 0; j < 4; ++j)
        acc[i][j] = __builtin_amdgcn_mfma_f32_16x16x32_bf16(af[i], bfr[j], acc[i][j], 0, 0, 0);
  }
  float* Pp = P + ((size_t)(h * 16 + chunk)) * 65536;
#pragma unroll
  for (int i = 0; i < 4; ++i)
#pragma unroll
    for (int r = 0; r < 4; ++r) {
      const int d = d0 + dw + i * 16 + quad * 4 + r;
#pragma unroll
      for (int j = 0; j < 4; ++j) {
        const int e = e0 + ew + j * 16 + l15;
        Pp[(size_t)d * HDsz + e] = acc[i][j][r];
      }
    }
}

// ---------------------------------------------------------------------------
// outmem = mem + 0.25 * sum_{chunk} P[h*16+chunk]
// ---------------------------------------------------------------------------
__global__ __launch_bounds__(256) void mem_reduce(const float4* __restrict__ P,
                                                  const float4* __restrict__ mem,
                                                  float4* __restrict__ outmem) {
  const int gid = blockIdx.x * 256 + threadIdx.x;
  const int h = gid >> 14, off = gid & 16383;
  float sx = 0.f, sy = 0.f, sz = 0.f, sw = 0.f;
#pragma unroll 4
  for (int c = 0; c < 16; ++c) {
    float4 v = P[((size_t)(h * 16 + c) << 14) + off];
    sx += v.x; sy += v.y; sz += v.z; sw += v.w;
  }
  float4 m = mem[gid];
  float4 o;
  o.x = m.x + 0.25f * sx; o.y = m.y + 0.25f * sy;
  o.z = m.z + 0.25f * sz; o.w = m.w + 0.25f * sw;
  outmem[gid] = o;
}

// ---------------------------------------------------------------------------
// z_new[h][d] = z[h][d] + (1/B) sum_{b,s} sk[b,h,s,d]
// grid 512 (4 h x 128 chunks of 64 rows), 256 threads (4 waves x 64 lanes,
// float4 per lane), block-level reduce, one atomic set per block.
// ---------------------------------------------------------------------------
__global__ __launch_bounds__(256) void z_update(const float* __restrict__ SK,
                                                const float* __restrict__ z_in,
                                                float* __restrict__ z_out) {
  __shared__ float4 red[256];
  const int h = blockIdx.x >> 7, chunk = blockIdx.x & 127;
  const int wid = threadIdx.x >> 6, lane = threadIdx.x & 63;
  const int m0 = chunk * 64;
  float4 s = {0.f, 0.f, 0.f, 0.f};
#pragma unroll
  for (int i = 0; i < 16; ++i) {
    const int row = m0 + i * 4 + wid;
    float4 v = *(const float4*)(SK + (size_t)row * Dsz + h * HDsz + lane * 4);
    s.x += v.x; s.y += v.y; s.z += v.z; s.w += v.w;
  }
  red[wid * 64 + lane] = s;
  __syncthreads();
  if (wid == 0) {
    float4 a = red[lane], b = red[64 + lane], c = red[128 + lane], d = red[192 + lane];
    a.x = (a.x + b.x + c.x + d.x) * 0.25f;
    a.y = (a.y + b.y + c.y + d.y) * 0.25f;
    a.z = (a.z + b.z + c.z + d.z) * 0.25f;
    a.w = (a.w + b.w + c.w + d.w) * 0.25f;
    if (chunk == 0) {
      const float4 z4 = *(const float4*)(z_in + h * HDsz + lane * 4);
      a.x += z4.x; a.y += z4.y; a.z += z4.z; a.w += z4.w;
    }
    float* zp = z_out + h * HDsz + lane * 4;
    atomicAdd(zp + 0, a.x);
    atomicAdd(zp + 1, a.y);
    atomicAdd(zp + 2, a.z);
    atomicAdd(zp + 3, a.w);
  }
}

// ---------------------------------------------------------------------------
extern "C" void kernel_launch(void* const* d_in, const int* in_sizes, int n_in,
                              void* d_out, int out_size, void* d_ws, size_t ws_size,
                              hipStream_t stream) {
  (void)in_sizes; (void)n_in; (void)out_size; (void)ws_size;
  const float* Hs = (const float*)d_in[0];
  const float* Wq = (const float*)d_in[1];
  const float* Wk = (const float*)d_in[2];
  const float* Wv = (const float*)d_in[3];
  const float* Wo = (const float*)d_in[4];
  const float* bo = (const float*)d_in[5];
  const float* betas = (const float*)d_in[6];
  const float* mem = (const float*)d_in[7];
  const float* z = (const float*)d_in[8];

  // fp32 workspace region
  float* ws = (float*)d_ws;
  float* Qb = ws;                    // 8388608 : Q fp32 -> sq
  float* Kb = ws + 8388608;          // K fp32 -> sk
  float* Vb = ws + 16777216;         // V fp32 -> W = v - delta
  float* At = ws + 25165824;         // attn out fp32 [bh][s][e]
  float* dq = ws + 33554432;         // 32768
  float* dk = ws + 33587200;         // 32768
  float* mlb = ws + 33619968;        // 147456 (16bh x 12qt x 3chunks x 256)
  // bf16 region
  u16* ub = (u16*)(ws + 33767424);
  u16* Wqb = ub;                     // 4 x 1048576 weight copies
  u16* Wkb = ub + 1048576;
  u16* Wvb = ub + 2097152;
  u16* Wob = ub + 3145728;
  u16* Qbf = ub + 4194304;           // bf16 Q; later reused as bf16 blend
  u16* Kbf = ub + 12582912;
  u16* Vt = ub + 20971520;           // 8388608 u16: Hs bf16 first, then V^T
  u16* Hsb = Vt;                     // alias: dead once transpose_v runs
  float* P = (float*)Vt;             // mem partials alias (dead after attn)
  float* Pb = (float*)d_out;         // split-attn secondary partials
                                     // (16 slots/bh x 32768 f = 33.5 MB),
                                     // written+read before final out GEMM

  float* out = (float*)d_out;                 // 8192x1024
  float* outmem = out + (size_t)Msz * Dsz;    // 4x256x256
  float* outz = outmem + Hsz * HDsz * HDsz;   // 4x256

  hipMemsetAsync(outz, 0, (size_t)(Hsz * HDsz) * sizeof(float), stream);

  cvt_bf16<<<1024, 256, 0, stream>>>((const float4*)Wq, Wqb);
  cvt_bf16<<<1024, 256, 0, stream>>>((const float4*)Wk, Wkb);
  cvt_bf16<<<1024, 256, 0, stream>>>((const float4*)Wv, Wvb);
  cvt_bf16<<<1024, 256, 0, stream>>>((const float4*)Wo, Wob);
  cvt_bf16<<<8192, 256, 0, stream>>>((const float4*)Hs, Hsb);

  dim3 gg(8, 64);  // N/128, M/128
  gemm_lds<<<gg, 256, 0, stream>>>(Hsb, Wqb, nullptr, Qb, Qbf);
  gemm_lds<<<gg, 256, 0, stream>>>(Hsb, Wkb, nullptr, Kb, Kbf);
  gemm_lds<<<gg, 256, 0, stream>>>(Hsb, Wvb, nullptr, Vb, nullptr);

  transpose_v<<<dim3(64, 8, 16), 256, 0, stream>>>(Vb, Vt);
  attn_mfma<<<dim3(32, 16), 512, 0, stream>>>(Qbf, Kbf, Vt, At, Pb, mlb);
  attn_merge<<<dim3(12, 16), 256, 0, stream>>>(At, Pb, mlb);

  eludens<<<8192, 256, 0, stream>>>(Qb, Kb, z, dq, dk);

  memread_mfma<<<dim3(2, 64, 4), 256, 0, stream>>>(Qb, mem, dq, betas, At, nullptr, Qbf, 0);
  memread_mfma<<<dim3(2, 64, 4), 256, 0, stream>>>(Kb, mem, dk, betas, nullptr, Vb, nullptr, 1);

  mem_update_mfma<<<dim3(4, 4, 16), 256, 0, stream>>>(Kb, Vb, P);
  mem_reduce<<<256, 256, 0, stream>>>((const float4*)P, (const float4*)mem, (float4*)outmem);
  z_update<<<512, 256, 0, stream>>>(Kb, z, outz);

  gemm_lds<<<gg, 256, 0, stream>>>(Qbf, Wob, bo, out, nullptr);
}

// Round 3
// 554.498 us; speedup vs baseline: 1.2370x; 1.2370x over previous
//
#include <hip/hip_runtime.h>

// Problem constants (B,S,D,H fixed by the reference)
#define Bsz 4
#define Ssz 2048
#define Dsz 1024
#define Hsz 4
#define HDsz 256
#define Msz 8192  // Bsz*Ssz

typedef unsigned short u16;
typedef __attribute__((ext_vector_type(8))) short bf16x8;  // 8 bf16 in 4 VGPRs
typedef __attribute__((ext_vector_type(4))) float f32x4;

__device__ __forceinline__ u16 f2b(float f) {  // fp32 -> bf16 RNE
  unsigned u = __float_as_uint(f);
  return (u16)((u + 0x7FFFu + ((u >> 16) & 1u)) >> 16);
}
__device__ __forceinline__ unsigned pk2(float a, float b) {
  return (unsigned)f2b(a) | ((unsigned)f2b(b) << 16);
}

// async global->LDS, 16B per lane; LDS dest = wave-uniform base + lane*16
typedef const unsigned int __attribute__((address_space(1)))* gcp;
typedef unsigned int __attribute__((address_space(3)))* lcp;
__device__ __forceinline__ void gld16(const u16* g, u16* l) {
  __builtin_amdgcn_global_load_lds((gcp)g, (lcp)l, 16, 0, 0);
}

// ---------------------------------------------------------------------------
// fp32 -> bf16 elementwise
// ---------------------------------------------------------------------------
__global__ __launch_bounds__(256) void cvt_bf16(const float4* __restrict__ in,
                                                u16* __restrict__ outp) {
  size_t i = (size_t)blockIdx.x * 256 + threadIdx.x;
  float4 v = in[i];
  uint2 r; r.x = pk2(v.x, v.y); r.y = pk2(v.z, v.w);
  *(uint2*)(outp + i * 4) = r;
}

// ---------------------------------------------------------------------------
// bf16 MFMA GEMM (m97 structure): C[M,N] = A[M,K]*W[N,K]^T (+bias).
// 128x128 tile, BK=32, global_load_lds width-16 staging, unpadded [128][32]
// LDS (16 KB -> 8 blocks/CU; explicit dbuf measured WORSE: fewer blocks,
// no pipeline gain -- round-2 regression). 4 waves x (4x4 of 16x16x32 MFMA).
// ---------------------------------------------------------------------------
__global__ __launch_bounds__(256) void gemm_lds(const u16* __restrict__ A16,
                                                const u16* __restrict__ Wb,
                                                const float* __restrict__ bias,
                                                float* __restrict__ C32,
                                                u16* __restrict__ Cbf) {
  __shared__ u16 sA[128 * 32];
  __shared__ u16 sB[128 * 32];
  const int tid = threadIdx.x;
  const int lane = tid & 63, quad = lane >> 4, l15 = lane & 15;
  const int w = tid >> 6;
  const int mw = (w >> 1) * 64, nw = (w & 1) * 64;
  const int m0 = blockIdx.y * 128, n0 = blockIdx.x * 128;
  const int r0 = tid >> 2, seg = (tid & 3) * 8;  // 4 lanes x 16B per row
  const u16* ga0 = A16 + (size_t)(m0 + r0) * Dsz + seg;
  const u16* gb0 = Wb + (size_t)(n0 + r0) * Dsz + seg;
  u16* lA0 = sA + w * 512;          // wave-uniform bases (u16 units)
  u16* lA1 = sA + 2048 + w * 512;
  u16* lB0 = sB + w * 512;
  u16* lB1 = sB + 2048 + w * 512;
  f32x4 acc[4][4] = {};
  for (int k0 = 0; k0 < Dsz; k0 += 32) {
    __syncthreads();
    gld16(ga0 + k0, lA0);
    gld16(ga0 + (size_t)64 * Dsz + k0, lA1);
    gld16(gb0 + k0, lB0);
    gld16(gb0 + (size_t)64 * Dsz + k0, lB1);
    __syncthreads();  // compiler drains vmcnt before barrier
    bf16x8 af[4], bfr[4];
#pragma unroll
    for (int i = 0; i < 4; ++i) {
      af[i] = *(const bf16x8*)&sA[(mw + i * 16 + l15) * 32 + quad * 8];
      bfr[i] = *(const bf16x8*)&sB[(nw + i * 16 + l15) * 32 + quad * 8];
    }
#pragma unroll
    for (int i = 0; i < 4; ++i)
#pragma unroll
      for (int j = 0; j < 4; ++j)
        acc[i][j] = __builtin_amdgcn_mfma_f32_16x16x32_bf16(af[i], bfr[j], acc[i][j], 0, 0, 0);
  }
#pragma unroll
  for (int j = 0; j < 4; ++j) {
    const int n = n0 + nw + j * 16 + l15;
    const float bv = bias ? bias[n] : 0.f;
#pragma unroll
    for (int i = 0; i < 4; ++i) {
#pragma unroll
      for (int r = 0; r < 4; ++r) {
        const int m = m0 + mw + i * 16 + quad * 4 + r;
        const float val = acc[i][j][r] + bv;
        const size_t idx = (size_t)m * Dsz + n;
        if (C32) C32[idx] = val;
        if (Cbf) Cbf[idx] = f2b(val);
      }
    }
  }
}

// ---------------------------------------------------------------------------
// V [b][s][h*256+e] fp32 -> V^T bf16 [bh][e][s]
// ---------------------------------------------------------------------------
__global__ __launch_bounds__(256) void transpose_v(const float* __restrict__ V,
                                                   u16* __restrict__ Vt) {
  __shared__ u16 tile[32 * 36];
  const int t = threadIdx.x;
  const int s0 = blockIdx.x * 32, e0 = blockIdx.y * 32, bh = blockIdx.z;
  const int b = bh >> 2, h = bh & 3;
  {
    const int s_l = t >> 3, e8 = (t & 7) * 4;
    float4 v = *(const float4*)(V + ((size_t)(b * Ssz) + s0 + s_l) * Dsz + h * HDsz + e0 + e8);
    uint2 r; r.x = pk2(v.x, v.y); r.y = pk2(v.z, v.w);
    *(uint2*)&tile[s_l * 36 + e8] = r;
  }
  __syncthreads();
  {
    const int e_l = t >> 3, s4 = (t & 7) * 4;
    u16 a = tile[(s4 + 0) * 36 + e_l], b2 = tile[(s4 + 1) * 36 + e_l];
    u16 c = tile[(s4 + 2) * 36 + e_l], d = tile[(s4 + 3) * 36 + e_l];
    uint2 r; r.x = (unsigned)a | ((unsigned)b2 << 16);
    r.y = (unsigned)c | ((unsigned)d << 16);
    *(uint2*)(Vt + ((size_t)bh * HDsz + e0 + e_l) * Ssz + s0 + s4) = r;
  }
}

// ---------------------------------------------------------------------------
// Flash attention, bf16 MFMA, flash-decoding split-K.
// 64-row Q-block, 4 waves (256 threads), VGPR ~88 + 64 acc -> no spill,
// 2 blocks/CU at 64 KB LDS (cross-block phase overlap hides barrier drain).
// Dispatch table: all 52 chunks per bh sorted by KV-tile count DESCENDING
// (heaviest first), so the grid's second occupancy wave runs tiny chunks.
//   qt >= 12: split into 2 chunks of qt+1 tiles each (cc=0/1).
//   qt < 12 : single chunk of 2qt+2 tiles.
// Split chunks write unnormalized O + (m,l); attn_merge combines.
//
// K/V tiles double-buffered in LDS via global_load_lds (width 16); LDS
// dest linear, bank conflicts avoided by XOR-swizzling the 16B slot on
// the GLOBAL source and applying the same involution on the ds_read side:
//   sK phys slot p at row r holds logical slot p ^ (r&7)       (row = s)
//   sV phys slot p at row r holds logical slot p ^ ((r>>1)&3)  (row = e)
// One __syncthreads per KV tile; prefetch of tile k+1 issued right after
// the barrier so its latency hides under QK/softmax/PV of tile k.
// s_setprio(1) around MFMA clusters (T5: independent blocks = phase
// diversity, the measured-positive regime for attn).
// ---------------------------------------------------------------------------
__global__ __launch_bounds__(256) void attn_mfma(const u16* __restrict__ Qg,
                                                 const u16* __restrict__ Kg,
                                                 const u16* __restrict__ Vtg,
                                                 float* __restrict__ At,
                                                 float* __restrict__ Pb,
                                                 float* __restrict__ mlb) {
  // entry = qt | (cc<<6) | (split<<7); sorted by chunk size desc
  static const unsigned char tab[52] = {
      (unsigned char)(31|0x80), (unsigned char)(31|0xC0),
      (unsigned char)(30|0x80), (unsigned char)(30|0xC0),
      (unsigned char)(29|0x80), (unsigned char)(29|0xC0),
      (unsigned char)(28|0x80), (unsigned char)(28|0xC0),
      (unsigned char)(27|0x80), (unsigned char)(27|0xC0),
      (unsigned char)(26|0x80), (unsigned char)(26|0xC0),
      (unsigned char)(25|0x80), (unsigned char)(25|0xC0),
      (unsigned char)(24|0x80), (unsigned char)(24|0xC0),
      (unsigned char)(23|0x80), (unsigned char)(23|0xC0),
      11,
      (unsigned char)(22|0x80), (unsigned char)(22|0xC0),
      (unsigned char)(21|0x80), (unsigned char)(21|0xC0),
      10,
      (unsigned char)(20|0x80), (unsigned char)(20|0xC0),
      (unsigned char)(19|0x80), (unsigned char)(19|0xC0),
      9,
      (unsigned char)(18|0x80), (unsigned char)(18|0xC0),
      (unsigned char)(17|0x80), (unsigned char)(17|0xC0),
      8,
      (unsigned char)(16|0x80), (unsigned char)(16|0xC0),
      (unsigned char)(15|0x80), (unsigned char)(15|0xC0),
      7,
      (unsigned char)(14|0x80), (unsigned char)(14|0xC0),
      (unsigned char)(13|0x80), (unsigned char)(13|0xC0),
      6,
      (unsigned char)(12|0x80), (unsigned char)(12|0xC0),
      5, 4, 3, 2, 1, 0};
  const int e = tab[blockIdx.x];
  const int qt = e & 63, cc = (e >> 6) & 1;
  const bool split = (e >> 7) != 0;
  const int bh = blockIdx.y, b = bh >> 2, h = bh & 3;
  const int tid = threadIdx.x, w = tid >> 6, lane = tid & 63;
  const int quad = lane >> 4, l15 = lane & 15;
  __shared__ u16 sK[2][32 * 256];   // [buf][s-row][d-col], slots swizzled by row&7
  __shared__ u16 sV[2][256 * 32];   // [buf][e-row][s-col], slots swizzled by (row>>1)&3
  const int q0w = qt * 64 + w * 16;
  bf16x8 qf[8];
  {
    const u16* qp = Qg + ((size_t)(b * Ssz) + q0w + l15) * Dsz + h * HDsz + quad * 8;
#pragma unroll
    for (int dd = 0; dd < 8; ++dd) qf[dd] = *(const bf16x8*)(qp + dd * 32);
  }
  f32x4 o[16] = {};
  float m_old = -1e30f, l = 0.f;
  const int nkt = 2 * qt + 2, half = qt + 1;
  const int kt_lo = (split && cc) ? half : 0;
  const int kt_hi = (split && !cc) ? half : nkt;
  // Staging source pointers (per-thread; swizzled GLOBAL column, linear LDS):
  const u16* kstage = Kg + ((size_t)(b * Ssz) + (tid >> 5)) * Dsz + h * HDsz
                      + (((tid & 31) ^ ((tid >> 5) & 7)) << 3);
  const u16* vstage = Vtg + ((size_t)bh * HDsz + (tid >> 2)) * Ssz
                      + (((tid & 3) ^ ((tid >> 3) & 3)) << 3);
  int bufc = 0;
  {  // prologue: prefetch first tile into buffer 0
    const u16* kp = kstage + (size_t)(kt_lo * 32) * Dsz;
    const u16* vp = vstage + kt_lo * 32;
#pragma unroll
    for (int i = 0; i < 4; ++i) {
      gld16(kp + (size_t)i * 8 * Dsz, &sK[0][w * 512 + i * 2048]);
      gld16(vp + (size_t)i * 64 * Ssz, &sV[0][w * 512 + i * 2048]);
    }
  }
  for (int kt = kt_lo; kt < kt_hi; ++kt) {
    const int j0 = kt * 32;
    __syncthreads();  // drains prefetch vmcnt; fences prev compute's LDS reads
    if (kt + 1 < kt_hi) {  // prefetch next tile into the other buffer
      const u16* kp = kstage + (size_t)((kt + 1) * 32) * Dsz;
      const u16* vp = vstage + (kt + 1) * 32;
      const int bn = bufc ^ 1;
#pragma unroll
      for (int i = 0; i < 4; ++i) {
        gld16(kp + (size_t)i * 8 * Dsz, &sK[bn][w * 512 + i * 2048]);
        gld16(vp + (size_t)i * 64 * Ssz, &sV[bn][w * 512 + i * 2048]);
      }
    }
    f32x4 s0v = {}, s1v = {};
    __builtin_amdgcn_s_setprio(1);
#pragma unroll
    for (int dd = 0; dd < 8; ++dd) {
      const int c0 = ((dd * 4 + quad) ^ (l15 & 7)) << 3;  // (16+l15)&7 == l15&7
      bf16x8 a0 = *(const bf16x8*)&sK[bufc][l15 * 256 + c0];
      bf16x8 a1 = *(const bf16x8*)&sK[bufc][(16 + l15) * 256 + c0];
      s0v = __builtin_amdgcn_mfma_f32_16x16x32_bf16(a0, qf[dd], s0v, 0, 0, 0);
      s1v = __builtin_amdgcn_mfma_f32_16x16x32_bf16(a1, qf[dd], s1v, 0, 0, 0);
    }
    __builtin_amdgcn_s_setprio(0);
    const int qg = q0w + l15;
    float p[8];
#pragma unroll
    for (int r = 0; r < 4; ++r) {
      const int kg = j0 + quad * 4 + r;
      p[r] = (kg <= qg) ? s0v[r] : -1e30f;
      p[4 + r] = (kg + 16 <= qg) ? s1v[r] : -1e30f;
    }
    float mt = p[0];
#pragma unroll
    for (int i = 1; i < 8; ++i) mt = fmaxf(mt, p[i]);
    mt = fmaxf(mt, __shfl_xor(mt, 16));
    mt = fmaxf(mt, __shfl_xor(mt, 32));
    const float m_new = fmaxf(m_old, mt);
    const float alpha = __expf(m_old - m_new);
    float ts = 0.f;
#pragma unroll
    for (int i = 0; i < 8; ++i) { p[i] = __expf(p[i] - m_new); ts += p[i]; }
    ts += __shfl_xor(ts, 16);
    ts += __shfl_xor(ts, 32);
    l = l * alpha + ts;
    m_old = m_new;
    if (!__all(alpha == 1.0f)) {
      const float a0_ = __shfl(alpha, (lane & 48) | (quad * 4 + 0));
      const float a1_ = __shfl(alpha, (lane & 48) | (quad * 4 + 1));
      const float a2_ = __shfl(alpha, (lane & 48) | (quad * 4 + 2));
      const float a3_ = __shfl(alpha, (lane & 48) | (quad * 4 + 3));
#pragma unroll
      for (int ds = 0; ds < 16; ++ds) {
        o[ds][0] *= a0_; o[ds][1] *= a1_; o[ds][2] *= a2_; o[ds][3] *= a3_;
      }
    }
    float xx[8];
#pragma unroll
    for (int i = 0; i < 8; ++i) xx[i] = __shfl_xor(p[i], 16);
    const bool qe = (quad & 1) == 0;
    float Alo[8], Ahi[8];
#pragma unroll
    for (int i = 0; i < 4; ++i) {
      Alo[i] = qe ? p[i] : xx[i];
      Alo[4 + i] = qe ? xx[i] : p[i];
      Ahi[i] = qe ? p[4 + i] : xx[4 + i];
      Ahi[4 + i] = qe ? xx[4 + i] : p[4 + i];
    }
    float zz[8];
    const bool sendlo = (quad & 1) != 0;
#pragma unroll
    for (int i = 0; i < 8; ++i) zz[i] = __shfl_xor(sendlo ? Alo[i] : Ahi[i], 32);
    float fin[8];
#pragma unroll
    for (int i = 0; i < 8; ++i)
      fin[i] = (quad == 0) ? Alo[i] : (quad == 3) ? Ahi[i] : zz[i];
    uint4 pkv;
    pkv.x = pk2(fin[0], fin[1]); pkv.y = pk2(fin[2], fin[3]);
    pkv.z = pk2(fin[4], fin[5]); pkv.w = pk2(fin[6], fin[7]);
    bf16x8 pf = *(bf16x8*)&pkv;
    const int vc0 = (quad ^ ((l15 >> 1) & 3)) << 3;  // (row>>1)&3 == (l15>>1)&3
    __builtin_amdgcn_s_setprio(1);
#pragma unroll
    for (int ds = 0; ds < 16; ++ds) {
      bf16x8 bv = *(const bf16x8*)&sV[bufc][(ds * 16 + l15) * 32 + vc0];
      o[ds] = __builtin_amdgcn_mfma_f32_16x16x32_bf16(pf, bv, o[ds], 0, 0, 0);
    }
    __builtin_amdgcn_s_setprio(0);
    bufc ^= 1;
  }
  if (!split) {
    float lr[4];
#pragma unroll
    for (int r = 0; r < 4; ++r) lr[r] = 1.f / __shfl(l, (lane & 48) | (quad * 4 + r));
    float* ob = At + ((size_t)bh * Ssz + q0w + quad * 4) * HDsz + l15;
#pragma unroll
    for (int r = 0; r < 4; ++r)
#pragma unroll
      for (int ds = 0; ds < 16; ++ds)
        ob[(size_t)r * HDsz + ds * 16] = o[ds][r] * lr[r];
  } else {
    float* dst;
    if (cc == 0)
      dst = At + ((size_t)bh * Ssz + q0w + quad * 4) * HDsz + l15;
    else
      dst = Pb + ((size_t)((bh * 20 + (qt - 12)) * 64) + w * 16 + quad * 4) * HDsz + l15;
#pragma unroll
    for (int r = 0; r < 4; ++r)
#pragma unroll
      for (int ds = 0; ds < 16; ++ds)
        dst[(size_t)r * HDsz + ds * 16] = o[ds][r];
    if (lane < 16) {
      const int idx = (bh * 20 + (qt - 12)) * 64 + w * 16 + l15;
      mlb[cc * 40960 + idx] = m_old;
      mlb[cc * 40960 + 20480 + idx] = l;
    }
  }
}

// ---------------------------------------------------------------------------
// Merge the two split-K chunks for qt>=12: O = (O0*e^{m0-m}+O1*e^{m1-m}) /
// (l0*e^{m0-m}+l1*e^{m1-m}).  grid (20, 16).
// ---------------------------------------------------------------------------
__global__ __launch_bounds__(256) void attn_merge(float* __restrict__ At,
                                                  const float* __restrict__ Pb,
                                                  const float* __restrict__ mlb) {
  const int qx = blockIdx.x, bh = blockIdx.y;
  const int t = threadIdx.x;
  const int slot = (bh * 20 + qx) * 64;
  float4* abase = (float4*)(At + ((size_t)bh * Ssz + (12 + qx) * 64) * HDsz);
  const float4* pbase = (const float4*)(Pb + (size_t)slot * HDsz);
#pragma unroll
  for (int i = 0; i < 16; ++i) {
    const int f = i * 256 + t;  // f4 index 0..4095, coalesced
    const int qr = f >> 6;
    const int idx = slot + qr;
    const float m0 = mlb[idx], l0 = mlb[20480 + idx];
    const float m1 = mlb[40960 + idx], l1 = mlb[61440 + idx];
    const float mm = fmaxf(m0, m1);
    const float w0 = __expf(m0 - mm), w1 = __expf(m1 - mm);
    const float inv = 1.f / (l0 * w0 + l1 * w1);
    float4 av = abase[f];
    float4 pv = pbase[f];
    float4 ov;
    ov.x = (av.x * w0 + pv.x * w1) * inv;
    ov.y = (av.y * w0 + pv.y * w1) * inv;
    ov.z = (av.z * w0 + pv.z * w1) * inv;
    ov.w = (av.w * w0 + pv.w * w1) * inv;
    abase[f] = ov;
  }
}

// ---------------------------------------------------------------------------
// Fused: sq=elu(q)+1, sk=elu(k)+1 (in place) + denq = sq.z, denk = sk.z.
// One wave per row; grid 8192 x 256.
// ---------------------------------------------------------------------------
__global__ __launch_bounds__(256) void eludens(float* __restrict__ Qb,
                                               float* __restrict__ Kb,
                                               const float* __restrict__ z,
                                               float* __restrict__ dq,
                                               float* __restrict__ dk) {
  const int wid = threadIdx.x >> 6, lane = threadIdx.x & 63;
  const int r = blockIdx.x * 4 + wid;
  const int b = r >> 13, h = (r >> 11) & 3, s = r & 2047;
  const size_t base = ((size_t)(b * Ssz + s)) * Dsz + h * HDsz + lane * 4;
  float4 z4 = *(const float4*)(z + h * HDsz + lane * 4);
  float4 q = *(float4*)(Qb + base);
  q.x = q.x > 0.f ? q.x + 1.f : __expf(q.x);
  q.y = q.y > 0.f ? q.y + 1.f : __expf(q.y);
  q.z = q.z > 0.f ? q.z + 1.f : __expf(q.z);
  q.w = q.w > 0.f ? q.w + 1.f : __expf(q.w);
  *(float4*)(Qb + base) = q;
  float4 k = *(float4*)(Kb + base);
  k.x = k.x > 0.f ? k.x + 1.f : __expf(k.x);
  k.y = k.y > 0.f ? k.y + 1.f : __expf(k.y);
  k.z = k.z > 0.f ? k.z + 1.f : __expf(k.z);
  k.w = k.w > 0.f ? k.w + 1.f : __expf(k.w);
  *(float4*)(Kb + base) = k;
  float pq = q.x * z4.x + q.y * z4.y + q.z * z4.z + q.w * z4.w;
  float pk = k.x * z4.x + k.y * z4.y + k.z * z4.z + k.w * z4.w;
#pragma unroll
  for (int off = 32; off; off >>= 1) {
    pq += __shfl_down(pq, off);
    pk += __shfl_down(pk, off);
  }
  if (lane == 0) { dq[r] = pq; dk[r] = pk; }
}

// ---------------------------------------------------------------------------
// Per-head MFMA GEMM: acc[m,e] = sum_d Asrc[m,h*256+d] * mem[h][d][e].
// mode 0: blend = g*acc/den + (1-g)*At -> bf16 row-major (bfout)
// mode 1: Vio = v - acc/den (fp32 in place)
// ---------------------------------------------------------------------------
__global__ __launch_bounds__(256) void memread_mfma(const float* __restrict__ Asrc,
                                                    const float* __restrict__ mem,
                                                    const float* __restrict__ dens,
                                                    const float* __restrict__ betas,
                                                    const float* __restrict__ At,
                                                    float* __restrict__ Vio,
                                                    u16* __restrict__ bfout, int mode) {
  const int h = blockIdx.z;
  const int tid = threadIdx.x, lane = tid & 63, w = tid >> 6;
  const int quad = lane >> 4, l15 = lane & 15;
  const int mw = (w >> 1) * 64, ew = (w & 1) * 64;
  const int m0 = blockIdx.y * 128, e0t = blockIdx.x * 128;
  __shared__ u16 sA[128 * 40];  // [m][k]
  __shared__ u16 sB[128 * 40];  // [e][k]
  const int srow = tid >> 1, sseg = (tid & 1) * 16;
  const int k4 = (tid & 7) * 4, e4 = (tid >> 3) * 4;
  f32x4 acc[4][4] = {};
  for (int k0 = 0; k0 < HDsz; k0 += 32) {
    __syncthreads();
    {
      const float* ap = Asrc + (size_t)(m0 + srow) * Dsz + h * HDsz + k0 + sseg;
      float4 f0 = *(const float4*)ap, f1 = *(const float4*)(ap + 4);
      float4 f2 = *(const float4*)(ap + 8), f3 = *(const float4*)(ap + 12);
      uint4 u0, u1;
      u0.x = pk2(f0.x, f0.y); u0.y = pk2(f0.z, f0.w);
      u0.z = pk2(f1.x, f1.y); u0.w = pk2(f1.z, f1.w);
      u1.x = pk2(f2.x, f2.y); u1.y = pk2(f2.z, f2.w);
      u1.z = pk2(f3.x, f3.y); u1.w = pk2(f3.z, f3.w);
      u16* dst = &sA[srow * 40 + sseg];
      *(uint4*)dst = u0; *(uint4*)(dst + 8) = u1;
    }
    {
      const float* bp = mem + (size_t)h * 65536 + (size_t)(k0 + k4) * HDsz + e0t + e4;
      float4 r0 = *(const float4*)bp;
      float4 r1 = *(const float4*)(bp + HDsz);
      float4 r2 = *(const float4*)(bp + 2 * HDsz);
      float4 r3 = *(const float4*)(bp + 3 * HDsz);
      const float* rr[4] = {(const float*)&r0, (const float*)&r1,
                            (const float*)&r2, (const float*)&r3};
#pragma unroll
      for (int c = 0; c < 4; ++c) {
        uint2 u;
        u.x = pk2(rr[0][c], rr[1][c]);
        u.y = pk2(rr[2][c], rr[3][c]);
        *(uint2*)&sB[(e4 + c) * 40 + k4] = u;
      }
    }
    __syncthreads();
    bf16x8 af[4], bfr[4];
#pragma unroll
    for (int i = 0; i < 4; ++i) {
      af[i] = *(const bf16x8*)&sA[(mw + i * 16 + l15) * 40 + quad * 8];
      bfr[i] = *(const bf16x8*)&sB[(ew + i * 16 + l15) * 40 + quad * 8];
    }
#pragma unroll
    for (int i = 0; i < 4; ++i)
#pragma unroll
      for (int j = 0; j < 4; ++j)
        acc[i][j] = __builtin_amdgcn_mfma_f32_16x16x32_bf16(af[i], bfr[j], acc[i][j], 0, 0, 0);
  }
  const float g = 1.f / (1.f + __expf(-betas[h]));
#pragma unroll
  for (int i = 0; i < 4; ++i) {
#pragma unroll
    for (int r = 0; r < 4; ++r) {
      const int m = m0 + mw + i * 16 + quad * 4 + r;
      const int b = m >> 11, s = m & 2047;
      const int rowidx = ((b << 2) + h) * Ssz + s;
      const float inv = 1.f / (dens[rowidx] + 1e-6f);
#pragma unroll
      for (int j = 0; j < 4; ++j) {
        const int e = e0t + ew + j * 16 + l15;
        const float av = acc[i][j][r] * inv;
        if (mode == 0) {
          const float a = At[(size_t)rowidx * HDsz + e];
          bfout[(size_t)m * Dsz + h * HDsz + e] = f2b(g * av + (1.f - g) * a);
        } else {
          float* p = Vio + (size_t)m * Dsz + h * HDsz + e;
          *p = *p - av;
        }
      }
    }
  }
}

// ---------------------------------------------------------------------------
// mem partials: P[(h*16+chunk)][d][e] = sum_{m in chunk} sk[m,..d]*W[m,..e]
// ---------------------------------------------------------------------------
__global__ __launch_bounds__(256) void mem_update_mfma(const float* __restrict__ SK,
                                                       const float* __restrict__ W,
                                                       float* __restrict__ P) {
  const int de = blockIdx.x;
  const int d0 = (de >> 1) * 128, e0 = (de & 1) * 128;
  const int h = blockIdx.y, chunk = blockIdx.z;
  const int m0 = chunk * 512;
  const int tid = threadIdx.x, lane = tid & 63, w = tid >> 6;
  const int quad = lane >> 4, l15 = lane & 15;
  const int dw = (w >> 1) * 64, ew = (w & 1) * 64;
  __shared__ u16 sA[128 * 40];  // [d][m]
  __shared__ u16 sB[128 * 40];  // [e][m]
  const int m4 = (tid & 7) * 4;
  const int c4 = (tid >> 3) * 4;
  f32x4 acc[4][4] = {};
  for (int mt = 0; mt < 512; mt += 32) {
    __syncthreads();
    const float* ka = SK + (size_t)(m0 + mt + m4) * Dsz + h * HDsz + d0 + c4;
    const float* wa = W + (size_t)(m0 + mt + m4) * Dsz + h * HDsz + e0 + c4;
    float4 a0 = *(const float4*)ka;
    float4 a1 = *(const float4*)(ka + Dsz);
    float4 a2 = *(const float4*)(ka + 2 * Dsz);
    float4 a3 = *(const float4*)(ka + 3 * Dsz);
    float4 b0 = *(const float4*)wa;
    float4 b1 = *(const float4*)(wa + Dsz);
    float4 b2 = *(const float4*)(wa + 2 * Dsz);
    float4 b3 = *(const float4*)(wa + 3 * Dsz);
    const float* aa[4] = {(const float*)&a0, (const float*)&a1,
                          (const float*)&a2, (const float*)&a3};
    const float* bb[4] = {(const float*)&b0, (const float*)&b1,
                          (const float*)&b2, (const float*)&b3};
#pragma unroll
    for (int c = 0; c < 4; ++c) {
      uint2 ua, ub2;
      ua.x = pk2(aa[0][c], aa[1][c]); ua.y = pk2(aa[2][c], aa[3][c]);
      ub2.x = pk2(bb[0][c], bb[1][c]); ub2.y = pk2(bb[2][c], bb[3][c]);
      *(uint2*)&sA[(c4 + c) * 40 + m4] = ua;
      *(uint2*)&sB[(c4 + c) * 40 + m4] = ub2;
    }
    __syncthreads();
    bf16x8 af[4], bfr[4];
#pragma unroll
    for (int i = 0; i < 4; ++i) {
      af[i] = *(const bf16x8*)&sA[(dw + i * 16 + l15) * 40 + quad * 8];
      bfr[i] = *(const bf16x8*)&sB[(ew + i * 16 + l15) * 40 + quad * 8];
    }
#pragma unroll
    for (int i = 0; i < 4; ++i)
#pragma unroll
      for (int j = 0; j < 4; ++j)
        acc[i][j] = __builtin_amdgcn_mfma_f32_16x16x32_bf16(af[i], bfr[j], acc[i][j], 0, 0, 0);
  }
  float* Pp = P + ((size_t)(h * 16 + chunk)) * 65536;
#pragma unroll
  for (int i = 0; i < 4; ++i)
#pragma unroll
    for (int r = 0; r < 4; ++r) {
      const int d = d0 + dw + i * 16 + quad * 4 + r;
#pragma unroll
      for (int j = 0; j < 4; ++j) {
        const int e = e0 + ew + j * 16 + l15;
        Pp[(size_t)d * HDsz + e] = acc[i][j][r];
      }
    }
}

// ---------------------------------------------------------------------------
// outmem = mem + 0.25 * sum_{chunk} P[h*16+chunk]
// ---------------------------------------------------------------------------
__global__ __launch_bounds__(256) void mem_reduce(const float4* __restrict__ P,
                                                  const float4* __restrict__ mem,
                                                  float4* __restrict__ outmem) {
  const int gid = blockIdx.x * 256 + threadIdx.x;
  const int h = gid >> 14, off = gid & 16383;
  float sx = 0.f, sy = 0.f, sz = 0.f, sw = 0.f;
#pragma unroll 4
  for (int c = 0; c < 16; ++c) {
    float4 v = P[((size_t)(h * 16 + c) << 14) + off];
    sx += v.x; sy += v.y; sz += v.z; sw += v.w;
  }
  float4 m = mem[gid];
  float4 o;
  o.x = m.x + 0.25f * sx; o.y = m.y + 0.25f * sy;
  o.z = m.z + 0.25f * sz; o.w = m.w + 0.25f * sw;
  outmem[gid] = o;
}

// ---------------------------------------------------------------------------
// z_new[h][d] = z[h][d] + (1/B) sum_{b,s} sk[b,h,s,d]
// grid 512 (4 h x 128 chunks of 64 rows), 256 threads (4 waves x 64 lanes,
// float4 per lane), block-level reduce, one atomic add per block.
// ---------------------------------------------------------------------------
__global__ __launch_bounds__(256) void z_update(const float* __restrict__ SK,
                                                const float* __restrict__ z_in,
                                                float* __restrict__ z_out) {
  __shared__ float4 red[256];
  const int h = blockIdx.x >> 7, chunk = blockIdx.x & 127;
  const int wid = threadIdx.x >> 6, lane = threadIdx.x & 63;
  const int m0 = chunk * 64;
  float4 s = {0.f, 0.f, 0.f, 0.f};
#pragma unroll
  for (int i = 0; i < 16; ++i) {
    const int row = m0 + i * 4 + wid;
    float4 v = *(const float4*)(SK + (size_t)row * Dsz + h * HDsz + lane * 4);
    s.x += v.x; s.y += v.y; s.z += v.z; s.w += v.w;
  }
  red[wid * 64 + lane] = s;
  __syncthreads();
  if (wid == 0) {
    float4 a = red[lane], b = red[64 + lane], c = red[128 + lane], d = red[192 + lane];
    a.x = (a.x + b.x + c.x + d.x) * 0.25f;
    a.y = (a.y + b.y + c.y + d.y) * 0.25f;
    a.z = (a.z + b.z + c.z + d.z) * 0.25f;
    a.w = (a.w + b.w + c.w + d.w) * 0.25f;
    if (chunk == 0) {
      const float4 z4 = *(const float4*)(z_in + h * HDsz + lane * 4);
      a.x += z4.x; a.y += z4.y; a.z += z4.z; a.w += z4.w;
    }
    float* zp = z_out + h * HDsz + lane * 4;
    atomicAdd(zp + 0, a.x);
    atomicAdd(zp + 1, a.y);
    atomicAdd(zp + 2, a.z);
    atomicAdd(zp + 3, a.w);
  }
}

// ---------------------------------------------------------------------------
extern "C" void kernel_launch(void* const* d_in, const int* in_sizes, int n_in,
                              void* d_out, int out_size, void* d_ws, size_t ws_size,
                              hipStream_t stream) {
  (void)in_sizes; (void)n_in; (void)out_size; (void)ws_size;
  const float* Hs = (const float*)d_in[0];
  const float* Wq = (const float*)d_in[1];
  const float* Wk = (const float*)d_in[2];
  const float* Wv = (const float*)d_in[3];
  const float* Wo = (const float*)d_in[4];
  const float* bo = (const float*)d_in[5];
  const float* betas = (const float*)d_in[6];
  const float* mem = (const float*)d_in[7];
  const float* z = (const float*)d_in[8];

  // fp32 workspace region
  float* ws = (float*)d_ws;
  float* Qb = ws;                    // 8388608 : Q fp32 -> sq
  float* Kb = ws + 8388608;          // K fp32 -> sk
  float* Vb = ws + 16777216;         // V fp32 -> W = v - delta
  float* At = ws + 25165824;         // attn out fp32 [bh][s][e]
  float* dq = ws + 33554432;         // 32768
  float* dk = ws + 33587200;         // 32768
  float* mlb = ws + 33619968;        // 81920 (4 planes x 20480)
  // bf16 region
  u16* ub = (u16*)(ws + 33701888);
  u16* Wqb = ub;                     // 4 x 1048576 weight copies
  u16* Wkb = ub + 1048576;
  u16* Wvb = ub + 2097152;
  u16* Wob = ub + 3145728;
  u16* Qbf = ub + 4194304;           // bf16 Q; later reused as bf16 blend
  u16* Kbf = ub + 12582912;
  u16* Vt = ub + 20971520;           // 8388608 u16: Hs bf16 first, then V^T
  u16* Hsb = Vt;                     // alias: dead once transpose_v runs
  float* P = (float*)Vt;             // mem partials alias (dead after attn)
  float* Pb = (float*)d_out;         // split-attn chunk-1 partials (21 MB),
                                     // written+read before final out GEMM

  float* out = (float*)d_out;                 // 8192x1024
  float* outmem = out + (size_t)Msz * Dsz;    // 4x256x256
  float* outz = outmem + Hsz * HDsz * HDsz;   // 4x256

  hipMemsetAsync(outz, 0, (size_t)(Hsz * HDsz) * sizeof(float), stream);

  cvt_bf16<<<1024, 256, 0, stream>>>((const float4*)Wq, Wqb);
  cvt_bf16<<<1024, 256, 0, stream>>>((const float4*)Wk, Wkb);
  cvt_bf16<<<1024, 256, 0, stream>>>((const float4*)Wv, Wvb);
  cvt_bf16<<<1024, 256, 0, stream>>>((const float4*)Wo, Wob);
  cvt_bf16<<<8192, 256, 0, stream>>>((const float4*)Hs, Hsb);

  dim3 gg(8, 64);  // N/128, M/128
  gemm_lds<<<gg, 256, 0, stream>>>(Hsb, Wqb, nullptr, Qb, Qbf);
  gemm_lds<<<gg, 256, 0, stream>>>(Hsb, Wkb, nullptr, Kb, Kbf);
  gemm_lds<<<gg, 256, 0, stream>>>(Hsb, Wvb, nullptr, Vb, nullptr);

  transpose_v<<<dim3(64, 8, 16), 256, 0, stream>>>(Vb, Vt);
  attn_mfma<<<dim3(52, 16), 256, 0, stream>>>(Qbf, Kbf, Vt, At, Pb, mlb);
  attn_merge<<<dim3(20, 16), 256, 0, stream>>>(At, Pb, mlb);

  eludens<<<8192, 256, 0, stream>>>(Qb, Kb, z, dq, dk);

  memread_mfma<<<dim3(2, 64, 4), 256, 0, stream>>>(Qb, mem, dq, betas, At, nullptr, Qbf, 0);
  memread_mfma<<<dim3(2, 64, 4), 256, 0, stream>>>(Kb, mem, dk, betas, nullptr, Vb, nullptr, 1);

  mem_update_mfma<<<dim3(4, 4, 16), 256, 0, stream>>>(Kb, Vb, P);
  mem_reduce<<<256, 256, 0, stream>>>((const float4*)P, (const float4*)mem, (float4*)outmem);
  z_update<<<512, 256, 0, stream>>>(Kb, z, outz);

  gemm_lds<<<gg, 256, 0, stream>>>(Qbf, Wob, bo, out, nullptr);
}

// Round 4
// 523.731 us; speedup vs baseline: 1.3097x; 1.0587x over previous
//
#include <hip/hip_runtime.h>

// Problem constants (B,S,D,H fixed by the reference)
#define Bsz 4
#define Ssz 2048
#define Dsz 1024
#define Hsz 4
#define HDsz 256
#define Msz 8192  // Bsz*Ssz

typedef unsigned short u16;
typedef __attribute__((ext_vector_type(8))) short bf16x8;  // 8 bf16 in 4 VGPRs
typedef __attribute__((ext_vector_type(4))) float f32x4;

__device__ __forceinline__ u16 f2b(float f) {  // fp32 -> bf16 RNE
  unsigned u = __float_as_uint(f);
  return (u16)((u + 0x7FFFu + ((u >> 16) & 1u)) >> 16);
}
__device__ __forceinline__ unsigned pk2(float a, float b) {
  return (unsigned)f2b(a) | ((unsigned)f2b(b) << 16);
}

// async global->LDS, 16B per lane; LDS dest = wave-uniform base + lane*16
typedef const unsigned int __attribute__((address_space(1)))* gcp;
typedef unsigned int __attribute__((address_space(3)))* lcp;
__device__ __forceinline__ void gld16(const u16* g, u16* l) {
  __builtin_amdgcn_global_load_lds((gcp)g, (lcp)l, 16, 0, 0);
}

// ---------------------------------------------------------------------------
// fp32 -> bf16 elementwise
// ---------------------------------------------------------------------------
__global__ __launch_bounds__(256) void cvt_bf16(const float4* __restrict__ in,
                                                u16* __restrict__ outp) {
  size_t i = (size_t)blockIdx.x * 256 + threadIdx.x;
  float4 v = in[i];
  uint2 r; r.x = pk2(v.x, v.y); r.y = pk2(v.z, v.w);
  *(uint2*)(outp + i * 4) = r;
}

// ---------------------------------------------------------------------------
// bf16 MFMA GEMM (m97 structure): C[M,N] = A[M,K]*W[N,K]^T (+bias).
// 128x128 tile, BK=32, global_load_lds width-16 staging, unpadded [128][32]
// LDS (16 KB -> 8 blocks/CU). 4 waves x (4x4 of 16x16x32 MFMA).
// XCD-aware block swizzle (T1): each XCD gets 8 consecutive m-panels so its
// L2 working set is 2MB A-panel + 2MB W instead of the full 16MB A.
// 512 blocks, 512%8==0 -> simple remap is bijective.
// ---------------------------------------------------------------------------
__global__ __launch_bounds__(256) void gemm_lds(const u16* __restrict__ A16,
                                                const u16* __restrict__ Wb,
                                                const float* __restrict__ bias,
                                                float* __restrict__ C32,
                                                u16* __restrict__ Cbf) {
  __shared__ u16 sA[128 * 32];
  __shared__ u16 sB[128 * 32];
  const int tid = threadIdx.x;
  const int lane = tid & 63, quad = lane >> 4, l15 = lane & 15;
  const int w = tid >> 6;
  const int mw = (w >> 1) * 64, nw = (w & 1) * 64;
  const int bid = blockIdx.y * 8 + blockIdx.x;
  const int nb = (bid & 7) * 64 + (bid >> 3);   // XCD swizzle
  const int m0 = (nb >> 3) * 128, n0 = (nb & 7) * 128;
  const int r0 = tid >> 2, seg = (tid & 3) * 8;  // 4 lanes x 16B per row
  const u16* ga0 = A16 + (size_t)(m0 + r0) * Dsz + seg;
  const u16* gb0 = Wb + (size_t)(n0 + r0) * Dsz + seg;
  u16* lA0 = sA + w * 512;          // wave-uniform bases (u16 units)
  u16* lA1 = sA + 2048 + w * 512;
  u16* lB0 = sB + w * 512;
  u16* lB1 = sB + 2048 + w * 512;
  f32x4 acc[4][4] = {};
  for (int k0 = 0; k0 < Dsz; k0 += 32) {
    __syncthreads();
    gld16(ga0 + k0, lA0);
    gld16(ga0 + (size_t)64 * Dsz + k0, lA1);
    gld16(gb0 + k0, lB0);
    gld16(gb0 + (size_t)64 * Dsz + k0, lB1);
    __syncthreads();  // compiler drains vmcnt before barrier
    bf16x8 af[4], bfr[4];
#pragma unroll
    for (int i = 0; i < 4; ++i) {
      af[i] = *(const bf16x8*)&sA[(mw + i * 16 + l15) * 32 + quad * 8];
      bfr[i] = *(const bf16x8*)&sB[(nw + i * 16 + l15) * 32 + quad * 8];
    }
#pragma unroll
    for (int i = 0; i < 4; ++i)
#pragma unroll
      for (int j = 0; j < 4; ++j)
        acc[i][j] = __builtin_amdgcn_mfma_f32_16x16x32_bf16(af[i], bfr[j], acc[i][j], 0, 0, 0);
  }
#pragma unroll
  for (int j = 0; j < 4; ++j) {
    const int n = n0 + nw + j * 16 + l15;
    const float bv = bias ? bias[n] : 0.f;
#pragma unroll
    for (int i = 0; i < 4; ++i) {
#pragma unroll
      for (int r = 0; r < 4; ++r) {
        const int m = m0 + mw + i * 16 + quad * 4 + r;
        const float val = acc[i][j][r] + bv;
        const size_t idx = (size_t)m * Dsz + n;
        if (C32) C32[idx] = val;
        if (Cbf) Cbf[idx] = f2b(val);
      }
    }
  }
}

// ---------------------------------------------------------------------------
// V [b][s][h*256+e] fp32 -> V^T bf16 [bh][e][s]
// ---------------------------------------------------------------------------
__global__ __launch_bounds__(256) void transpose_v(const float* __restrict__ V,
                                                   u16* __restrict__ Vt) {
  __shared__ u16 tile[32 * 36];
  const int t = threadIdx.x;
  const int s0 = blockIdx.x * 32, e0 = blockIdx.y * 32, bh = blockIdx.z;
  const int b = bh >> 2, h = bh & 3;
  {
    const int s_l = t >> 3, e8 = (t & 7) * 4;
    float4 v = *(const float4*)(V + ((size_t)(b * Ssz) + s0 + s_l) * Dsz + h * HDsz + e0 + e8);
    uint2 r; r.x = pk2(v.x, v.y); r.y = pk2(v.z, v.w);
    *(uint2*)&tile[s_l * 36 + e8] = r;
  }
  __syncthreads();
  {
    const int e_l = t >> 3, s4 = (t & 7) * 4;
    u16 a = tile[(s4 + 0) * 36 + e_l], b2 = tile[(s4 + 1) * 36 + e_l];
    u16 c = tile[(s4 + 2) * 36 + e_l], d = tile[(s4 + 3) * 36 + e_l];
    uint2 r; r.x = (unsigned)a | ((unsigned)b2 << 16);
    r.y = (unsigned)c | ((unsigned)d << 16);
    *(uint2*)(Vt + ((size_t)bh * HDsz + e0 + e_l) * Ssz + s0 + s4) = r;
  }
}

// ---------------------------------------------------------------------------
// Flash attention, bf16 MFMA, flash-decoding split-K.
// 64-row Q-block, 4 waves (256 threads).
// LDS = sK double-buffered (32KB) + sV SINGLE-buffered (16KB) = 48KB
//   -> 3 blocks/CU (was 2 at 64KB): 3-way cross-block phase overlap.
// Per tile: barrier A (Vbuf free, K(kt) landed) -> issue V(kt) + K(kt+1)
//   -> QK + softmax (covers the loads) -> barrier B (drains V) -> PV.
// V needs no double buffer because it is only read in PV, after barrier B.
// NO setprio: 4-wave barrier-locked blocks are the measured-negative regime
// (round-3 regression: VALUBusy 21->29, +12us).
// Dispatch table sorted by chunk size descending (heaviest first).
//   qt >= 12: split into 2 chunks of qt+1 tiles each (cc=0/1).
//   qt < 12 : single chunk of 2qt+2 tiles.
// Split chunks write unnormalized O + (m,l); attn_merge combines.
// Bank conflicts avoided by XOR-swizzling the 16B slot on the GLOBAL
// source and applying the same involution on the ds_read side:
//   sK phys slot p at row r holds logical slot p ^ (r&7)       (row = s)
//   sV phys slot p at row r holds logical slot p ^ ((r>>1)&3)  (row = e)
// ---------------------------------------------------------------------------
__global__ __launch_bounds__(256) void attn_mfma(const u16* __restrict__ Qg,
                                                 const u16* __restrict__ Kg,
                                                 const u16* __restrict__ Vtg,
                                                 float* __restrict__ At,
                                                 float* __restrict__ Pb,
                                                 float* __restrict__ mlb) {
  // entry = qt | (cc<<6) | (split<<7); sorted by chunk size desc
  static const unsigned char tab[52] = {
      (unsigned char)(31|0x80), (unsigned char)(31|0xC0),
      (unsigned char)(30|0x80), (unsigned char)(30|0xC0),
      (unsigned char)(29|0x80), (unsigned char)(29|0xC0),
      (unsigned char)(28|0x80), (unsigned char)(28|0xC0),
      (unsigned char)(27|0x80), (unsigned char)(27|0xC0),
      (unsigned char)(26|0x80), (unsigned char)(26|0xC0),
      (unsigned char)(25|0x80), (unsigned char)(25|0xC0),
      (unsigned char)(24|0x80), (unsigned char)(24|0xC0),
      (unsigned char)(23|0x80), (unsigned char)(23|0xC0),
      11,
      (unsigned char)(22|0x80), (unsigned char)(22|0xC0),
      (unsigned char)(21|0x80), (unsigned char)(21|0xC0),
      10,
      (unsigned char)(20|0x80), (unsigned char)(20|0xC0),
      (unsigned char)(19|0x80), (unsigned char)(19|0xC0),
      9,
      (unsigned char)(18|0x80), (unsigned char)(18|0xC0),
      (unsigned char)(17|0x80), (unsigned char)(17|0xC0),
      8,
      (unsigned char)(16|0x80), (unsigned char)(16|0xC0),
      (unsigned char)(15|0x80), (unsigned char)(15|0xC0),
      7,
      (unsigned char)(14|0x80), (unsigned char)(14|0xC0),
      (unsigned char)(13|0x80), (unsigned char)(13|0xC0),
      6,
      (unsigned char)(12|0x80), (unsigned char)(12|0xC0),
      5, 4, 3, 2, 1, 0};
  const int e = tab[blockIdx.x];
  const int qt = e & 63, cc = (e >> 6) & 1;
  const bool split = (e >> 7) != 0;
  const int bh = blockIdx.y, b = bh >> 2, h = bh & 3;
  const int tid = threadIdx.x, w = tid >> 6, lane = tid & 63;
  const int quad = lane >> 4, l15 = lane & 15;
  __shared__ u16 sK[2][32 * 256];   // [buf][s-row][d-col], slots swizzled by row&7
  __shared__ u16 sV[256 * 32];      // [e-row][s-col], slots swizzled by (row>>1)&3
  const int q0w = qt * 64 + w * 16;
  bf16x8 qf[8];
  {
    const u16* qp = Qg + ((size_t)(b * Ssz) + q0w + l15) * Dsz + h * HDsz + quad * 8;
#pragma unroll
    for (int dd = 0; dd < 8; ++dd) qf[dd] = *(const bf16x8*)(qp + dd * 32);
  }
  f32x4 o[16] = {};
  float m_old = -1e30f, l = 0.f;
  const int nkt = 2 * qt + 2, half = qt + 1;
  const int kt_lo = (split && cc) ? half : 0;
  const int kt_hi = (split && !cc) ? half : nkt;
  // Staging source pointers (per-thread; swizzled GLOBAL column, linear LDS):
  const u16* kstage = Kg + ((size_t)(b * Ssz) + (tid >> 5)) * Dsz + h * HDsz
                      + (((tid & 31) ^ ((tid >> 5) & 7)) << 3);
  const u16* vstage = Vtg + ((size_t)bh * HDsz + (tid >> 2)) * Ssz
                      + (((tid & 3) ^ ((tid >> 3) & 3)) << 3);
  int bufc = 0;
  {  // prologue: prefetch first K tile into buffer 0
    const u16* kp = kstage + (size_t)(kt_lo * 32) * Dsz;
#pragma unroll
    for (int i = 0; i < 4; ++i)
      gld16(kp + (size_t)i * 8 * Dsz, &sK[0][w * 512 + i * 2048]);
  }
  for (int kt = kt_lo; kt < kt_hi; ++kt) {
    const int j0 = kt * 32;
    __syncthreads();  // A: K(kt) landed; all waves done with sV (PV of kt-1)
    {  // stage V(kt) into the single V buffer; lands by barrier B
      const u16* vp = vstage + kt * 32;
#pragma unroll
      for (int i = 0; i < 4; ++i)
        gld16(vp + (size_t)i * 64 * Ssz, &sV[w * 512 + i * 2048]);
    }
    if (kt + 1 < kt_hi) {  // prefetch next K tile into the other buffer
      const u16* kp = kstage + (size_t)((kt + 1) * 32) * Dsz;
      const int bn = bufc ^ 1;
#pragma unroll
      for (int i = 0; i < 4; ++i)
        gld16(kp + (size_t)i * 8 * Dsz, &sK[bn][w * 512 + i * 2048]);
    }
    // QK^T: two half-chains per score vector (halves the dependent-MFMA depth)
    f32x4 s0a = {}, s0b = {}, s1a = {}, s1b = {};
#pragma unroll
    for (int dd = 0; dd < 4; ++dd) {
      const int c0 = ((dd * 4 + quad) ^ (l15 & 7)) << 3;  // (16+l15)&7 == l15&7
      const int c1 = (((dd + 4) * 4 + quad) ^ (l15 & 7)) << 3;
      bf16x8 a0 = *(const bf16x8*)&sK[bufc][l15 * 256 + c0];
      bf16x8 a1 = *(const bf16x8*)&sK[bufc][(16 + l15) * 256 + c0];
      bf16x8 b0 = *(const bf16x8*)&sK[bufc][l15 * 256 + c1];
      bf16x8 b1 = *(const bf16x8*)&sK[bufc][(16 + l15) * 256 + c1];
      s0a = __builtin_amdgcn_mfma_f32_16x16x32_bf16(a0, qf[dd], s0a, 0, 0, 0);
      s1a = __builtin_amdgcn_mfma_f32_16x16x32_bf16(a1, qf[dd], s1a, 0, 0, 0);
      s0b = __builtin_amdgcn_mfma_f32_16x16x32_bf16(b0, qf[dd + 4], s0b, 0, 0, 0);
      s1b = __builtin_amdgcn_mfma_f32_16x16x32_bf16(b1, qf[dd + 4], s1b, 0, 0, 0);
    }
    f32x4 s0v = s0a + s0b, s1v = s1a + s1b;
    const int qg = q0w + l15;
    float p[8];
#pragma unroll
    for (int r = 0; r < 4; ++r) {
      const int kg = j0 + quad * 4 + r;
      p[r] = (kg <= qg) ? s0v[r] : -1e30f;
      p[4 + r] = (kg + 16 <= qg) ? s1v[r] : -1e30f;
    }
    float mt = p[0];
#pragma unroll
    for (int i = 1; i < 8; ++i) mt = fmaxf(mt, p[i]);
    mt = fmaxf(mt, __shfl_xor(mt, 16));
    mt = fmaxf(mt, __shfl_xor(mt, 32));
    const float m_new = fmaxf(m_old, mt);
    const float alpha = __expf(m_old - m_new);
    float ts = 0.f;
#pragma unroll
    for (int i = 0; i < 8; ++i) { p[i] = __expf(p[i] - m_new); ts += p[i]; }
    ts += __shfl_xor(ts, 16);
    ts += __shfl_xor(ts, 32);
    l = l * alpha + ts;
    m_old = m_new;
    if (!__all(alpha == 1.0f)) {
      const float a0_ = __shfl(alpha, (lane & 48) | (quad * 4 + 0));
      const float a1_ = __shfl(alpha, (lane & 48) | (quad * 4 + 1));
      const float a2_ = __shfl(alpha, (lane & 48) | (quad * 4 + 2));
      const float a3_ = __shfl(alpha, (lane & 48) | (quad * 4 + 3));
#pragma unroll
      for (int ds = 0; ds < 16; ++ds) {
        o[ds][0] *= a0_; o[ds][1] *= a1_; o[ds][2] *= a2_; o[ds][3] *= a3_;
      }
    }
    float xx[8];
#pragma unroll
    for (int i = 0; i < 8; ++i) xx[i] = __shfl_xor(p[i], 16);
    const bool qe = (quad & 1) == 0;
    float Alo[8], Ahi[8];
#pragma unroll
    for (int i = 0; i < 4; ++i) {
      Alo[i] = qe ? p[i] : xx[i];
      Alo[4 + i] = qe ? xx[i] : p[i];
      Ahi[i] = qe ? p[4 + i] : xx[4 + i];
      Ahi[4 + i] = qe ? xx[4 + i] : p[4 + i];
    }
    float zz[8];
    const bool sendlo = (quad & 1) != 0;
#pragma unroll
    for (int i = 0; i < 8; ++i) zz[i] = __shfl_xor(sendlo ? Alo[i] : Ahi[i], 32);
    float fin[8];
#pragma unroll
    for (int i = 0; i < 8; ++i)
      fin[i] = (quad == 0) ? Alo[i] : (quad == 3) ? Ahi[i] : zz[i];
    uint4 pkv;
    pkv.x = pk2(fin[0], fin[1]); pkv.y = pk2(fin[2], fin[3]);
    pkv.z = pk2(fin[4], fin[5]); pkv.w = pk2(fin[6], fin[7]);
    bf16x8 pf = *(bf16x8*)&pkv;
    const int vc0 = (quad ^ ((l15 >> 1) & 3)) << 3;  // (row>>1)&3 == (l15>>1)&3
    __syncthreads();  // B: V(kt) landed (also early-drains K(kt+1))
#pragma unroll
    for (int ds = 0; ds < 16; ++ds) {
      bf16x8 bv = *(const bf16x8*)&sV[(ds * 16 + l15) * 32 + vc0];
      o[ds] = __builtin_amdgcn_mfma_f32_16x16x32_bf16(pf, bv, o[ds], 0, 0, 0);
    }
    bufc ^= 1;
  }
  if (!split) {
    float lr[4];
#pragma unroll
    for (int r = 0; r < 4; ++r) lr[r] = 1.f / __shfl(l, (lane & 48) | (quad * 4 + r));
    float* ob = At + ((size_t)bh * Ssz + q0w + quad * 4) * HDsz + l15;
#pragma unroll
    for (int r = 0; r < 4; ++r)
#pragma unroll
      for (int ds = 0; ds < 16; ++ds)
        ob[(size_t)r * HDsz + ds * 16] = o[ds][r] * lr[r];
  } else {
    float* dst;
    if (cc == 0)
      dst = At + ((size_t)bh * Ssz + q0w + quad * 4) * HDsz + l15;
    else
      dst = Pb + ((size_t)((bh * 20 + (qt - 12)) * 64) + w * 16 + quad * 4) * HDsz + l15;
#pragma unroll
    for (int r = 0; r < 4; ++r)
#pragma unroll
      for (int ds = 0; ds < 16; ++ds)
        dst[(size_t)r * HDsz + ds * 16] = o[ds][r];
    if (lane < 16) {
      const int idx = (bh * 20 + (qt - 12)) * 64 + w * 16 + l15;
      mlb[cc * 40960 + idx] = m_old;
      mlb[cc * 40960 + 20480 + idx] = l;
    }
  }
}

// ---------------------------------------------------------------------------
// Merge the two split-K chunks for qt>=12: O = (O0*e^{m0-m}+O1*e^{m1-m}) /
// (l0*e^{m0-m}+l1*e^{m1-m}).  grid (20, 16).
// ---------------------------------------------------------------------------
__global__ __launch_bounds__(256) void attn_merge(float* __restrict__ At,
                                                  const float* __restrict__ Pb,
                                                  const float* __restrict__ mlb) {
  const int qx = blockIdx.x, bh = blockIdx.y;
  const int t = threadIdx.x;
  const int slot = (bh * 20 + qx) * 64;
  float4* abase = (float4*)(At + ((size_t)bh * Ssz + (12 + qx) * 64) * HDsz);
  const float4* pbase = (const float4*)(Pb + (size_t)slot * HDsz);
#pragma unroll
  for (int i = 0; i < 16; ++i) {
    const int f = i * 256 + t;  // f4 index 0..4095, coalesced
    const int qr = f >> 6;
    const int idx = slot + qr;
    const float m0 = mlb[idx], l0 = mlb[20480 + idx];
    const float m1 = mlb[40960 + idx], l1 = mlb[61440 + idx];
    const float mm = fmaxf(m0, m1);
    const float w0 = __expf(m0 - mm), w1 = __expf(m1 - mm);
    const float inv = 1.f / (l0 * w0 + l1 * w1);
    float4 av = abase[f];
    float4 pv = pbase[f];
    float4 ov;
    ov.x = (av.x * w0 + pv.x * w1) * inv;
    ov.y = (av.y * w0 + pv.y * w1) * inv;
    ov.z = (av.z * w0 + pv.z * w1) * inv;
    ov.w = (av.w * w0 + pv.w * w1) * inv;
    abase[f] = ov;
  }
}

// ---------------------------------------------------------------------------
// Fused: sq=elu(q)+1, sk=elu(k)+1 (in place) + denq = sq.z, denk = sk.z.
// One wave per row; grid 8192 x 256.
// ---------------------------------------------------------------------------
__global__ __launch_bounds__(256) void eludens(float* __restrict__ Qb,
                                               float* __restrict__ Kb,
                                               const float* __restrict__ z,
                                               float* __restrict__ dq,
                                               float* __restrict__ dk) {
  const int wid = threadIdx.x >> 6, lane = threadIdx.x & 63;
  const int r = blockIdx.x * 4 + wid;
  const int b = r >> 13, h = (r >> 11) & 3, s = r & 2047;
  const size_t base = ((size_t)(b * Ssz + s)) * Dsz + h * HDsz + lane * 4;
  float4 z4 = *(const float4*)(z + h * HDsz + lane * 4);
  float4 q = *(float4*)(Qb + base);
  q.x = q.x > 0.f ? q.x + 1.f : __expf(q.x);
  q.y = q.y > 0.f ? q.y + 1.f : __expf(q.y);
  q.z = q.z > 0.f ? q.z + 1.f : __expf(q.z);
  q.w = q.w > 0.f ? q.w + 1.f : __expf(q.w);
  *(float4*)(Qb + base) = q;
  float4 k = *(float4*)(Kb + base);
  k.x = k.x > 0.f ? k.x + 1.f : __expf(k.x);
  k.y = k.y > 0.f ? k.y + 1.f : __expf(k.y);
  k.z = k.z > 0.f ? k.z + 1.f : __expf(k.z);
  k.w = k.w > 0.f ? k.w + 1.f : __expf(k.w);
  *(float4*)(Kb + base) = k;
  float pq = q.x * z4.x + q.y * z4.y + q.z * z4.z + q.w * z4.w;
  float pk = k.x * z4.x + k.y * z4.y + k.z * z4.z + k.w * z4.w;
#pragma unroll
  for (int off = 32; off; off >>= 1) {
    pq += __shfl_down(pq, off);
    pk += __shfl_down(pk, off);
  }
  if (lane == 0) { dq[r] = pq; dk[r] = pk; }
}

// ---------------------------------------------------------------------------
// Per-head MFMA GEMM: acc[m,e] = sum_d Asrc[m,h*256+d] * mem[h][d][e].
// mode 0: blend = g*acc/den + (1-g)*At -> bf16 row-major (bfout)
// mode 1: Vio = v - acc/den (fp32 in place)
// ---------------------------------------------------------------------------
__global__ __launch_bounds__(256) void memread_mfma(const float* __restrict__ Asrc,
                                                    const float* __restrict__ mem,
                                                    const float* __restrict__ dens,
                                                    const float* __restrict__ betas,
                                                    const float* __restrict__ At,
                                                    float* __restrict__ Vio,
                                                    u16* __restrict__ bfout, int mode) {
  const int h = blockIdx.z;
  const int tid = threadIdx.x, lane = tid & 63, w = tid >> 6;
  const int quad = lane >> 4, l15 = lane & 15;
  const int mw = (w >> 1) * 64, ew = (w & 1) * 64;
  const int m0 = blockIdx.y * 128, e0t = blockIdx.x * 128;
  __shared__ u16 sA[128 * 40];  // [m][k]
  __shared__ u16 sB[128 * 40];  // [e][k]
  const int srow = tid >> 1, sseg = (tid & 1) * 16;
  const int k4 = (tid & 7) * 4, e4 = (tid >> 3) * 4;
  f32x4 acc[4][4] = {};
  for (int k0 = 0; k0 < HDsz; k0 += 32) {
    __syncthreads();
    {
      const float* ap = Asrc + (size_t)(m0 + srow) * Dsz + h * HDsz + k0 + sseg;
      float4 f0 = *(const float4*)ap, f1 = *(const float4*)(ap + 4);
      float4 f2 = *(const float4*)(ap + 8), f3 = *(const float4*)(ap + 12);
      uint4 u0, u1;
      u0.x = pk2(f0.x, f0.y); u0.y = pk2(f0.z, f0.w);
      u0.z = pk2(f1.x, f1.y); u0.w = pk2(f1.z, f1.w);
      u1.x = pk2(f2.x, f2.y); u1.y = pk2(f2.z, f2.w);
      u1.z = pk2(f3.x, f3.y); u1.w = pk2(f3.z, f3.w);
      u16* dst = &sA[srow * 40 + sseg];
      *(uint4*)dst = u0; *(uint4*)(dst + 8) = u1;
    }
    {
      const float* bp = mem + (size_t)h * 65536 + (size_t)(k0 + k4) * HDsz + e0t + e4;
      float4 r0 = *(const float4*)bp;
      float4 r1 = *(const float4*)(bp + HDsz);
      float4 r2 = *(const float4*)(bp + 2 * HDsz);
      float4 r3 = *(const float4*)(bp + 3 * HDsz);
      const float* rr[4] = {(const float*)&r0, (const float*)&r1,
                            (const float*)&r2, (const float*)&r3};
#pragma unroll
      for (int c = 0; c < 4; ++c) {
        uint2 u;
        u.x = pk2(rr[0][c], rr[1][c]);
        u.y = pk2(rr[2][c], rr[3][c]);
        *(uint2*)&sB[(e4 + c) * 40 + k4] = u;
      }
    }
    __syncthreads();
    bf16x8 af[4], bfr[4];
#pragma unroll
    for (int i = 0; i < 4; ++i) {
      af[i] = *(const bf16x8*)&sA[(mw + i * 16 + l15) * 40 + quad * 8];
      bfr[i] = *(const bf16x8*)&sB[(ew + i * 16 + l15) * 40 + quad * 8];
    }
#pragma unroll
    for (int i = 0; i < 4; ++i)
#pragma unroll
      for (int j = 0; j < 4; ++j)
        acc[i][j] = __builtin_amdgcn_mfma_f32_16x16x32_bf16(af[i], bfr[j], acc[i][j], 0, 0, 0);
  }
  const float g = 1.f / (1.f + __expf(-betas[h]));
#pragma unroll
  for (int i = 0; i < 4; ++i) {
#pragma unroll
    for (int r = 0; r < 4; ++r) {
      const int m = m0 + mw + i * 16 + quad * 4 + r;
      const int b = m >> 11, s = m & 2047;
      const int rowidx = ((b << 2) + h) * Ssz + s;
      const float inv = 1.f / (dens[rowidx] + 1e-6f);
#pragma unroll
      for (int j = 0; j < 4; ++j) {
        const int e = e0t + ew + j * 16 + l15;
        const float av = acc[i][j][r] * inv;
        if (mode == 0) {
          const float a = At[(size_t)rowidx * HDsz + e];
          bfout[(size_t)m * Dsz + h * HDsz + e] = f2b(g * av + (1.f - g) * a);
        } else {
          float* p = Vio + (size_t)m * Dsz + h * HDsz + e;
          *p = *p - av;
        }
      }
    }
  }
}

// ---------------------------------------------------------------------------
// mem partials: P[(h*16+chunk)][d][e] = sum_{m in chunk} sk[m,..d]*W[m,..e]
// ---------------------------------------------------------------------------
__global__ __launch_bounds__(256) void mem_update_mfma(const float* __restrict__ SK,
                                                       const float* __restrict__ W,
                                                       float* __restrict__ P) {
  const int de = blockIdx.x;
  const int d0 = (de >> 1) * 128, e0 = (de & 1) * 128;
  const int h = blockIdx.y, chunk = blockIdx.z;
  const int m0 = chunk * 512;
  const int tid = threadIdx.x, lane = tid & 63, w = tid >> 6;
  const int quad = lane >> 4, l15 = lane & 15;
  const int dw = (w >> 1) * 64, ew = (w & 1) * 64;
  __shared__ u16 sA[128 * 40];  // [d][m]
  __shared__ u16 sB[128 * 40];  // [e][m]
  const int m4 = (tid & 7) * 4;
  const int c4 = (tid >> 3) * 4;
  f32x4 acc[4][4] = {};
  for (int mt = 0; mt < 512; mt += 32) {
    __syncthreads();
    const float* ka = SK + (size_t)(m0 + mt + m4) * Dsz + h * HDsz + d0 + c4;
    const float* wa = W + (size_t)(m0 + mt + m4) * Dsz + h * HDsz + e0 + c4;
    float4 a0 = *(const float4*)ka;
    float4 a1 = *(const float4*)(ka + Dsz);
    float4 a2 = *(const float4*)(ka + 2 * Dsz);
    float4 a3 = *(const float4*)(ka + 3 * Dsz);
    float4 b0 = *(const float4*)wa;
    float4 b1 = *(const float4*)(wa + Dsz);
    float4 b2 = *(const float4*)(wa + 2 * Dsz);
    float4 b3 = *(const float4*)(wa + 3 * Dsz);
    const float* aa[4] = {(const float*)&a0, (const float*)&a1,
                          (const float*)&a2, (const float*)&a3};
    const float* bb[4] = {(const float*)&b0, (const float*)&b1,
                          (const float*)&b2, (const float*)&b3};
#pragma unroll
    for (int c = 0; c < 4; ++c) {
      uint2 ua, ub2;
      ua.x = pk2(aa[0][c], aa[1][c]); ua.y = pk2(aa[2][c], aa[3][c]);
      ub2.x = pk2(bb[0][c], bb[1][c]); ub2.y = pk2(bb[2][c], bb[3][c]);
      *(uint2*)&sA[(c4 + c) * 40 + m4] = ua;
      *(uint2*)&sB[(c4 + c) * 40 + m4] = ub2;
    }
    __syncthreads();
    bf16x8 af[4], bfr[4];
#pragma unroll
    for (int i = 0; i < 4; ++i) {
      af[i] = *(const bf16x8*)&sA[(dw + i * 16 + l15) * 40 + quad * 8];
      bfr[i] = *(const bf16x8*)&sB[(ew + i * 16 + l15) * 40 + quad * 8];
    }
#pragma unroll
    for (int i = 0; i < 4; ++i)
#pragma unroll
      for (int j = 0; j < 4; ++j)
        acc[i][j] = __builtin_amdgcn_mfma_f32_16x16x32_bf16(af[i], bfr[j], acc[i][j], 0, 0, 0);
  }
  float* Pp = P + ((size_t)(h * 16 + chunk)) * 65536;
#pragma unroll
  for (int i = 0; i < 4; ++i)
#pragma unroll
    for (int r = 0; r < 4; ++r) {
      const int d = d0 + dw + i * 16 + quad * 4 + r;
#pragma unroll
      for (int j = 0; j < 4; ++j) {
        const int e = e0 + ew + j * 16 + l15;
        Pp[(size_t)d * HDsz + e] = acc[i][j][r];
      }
    }
}

// ---------------------------------------------------------------------------
// outmem = mem + 0.25 * sum_{chunk} P[h*16+chunk]
// ---------------------------------------------------------------------------
__global__ __launch_bounds__(256) void mem_reduce(const float4* __restrict__ P,
                                                  const float4* __restrict__ mem,
                                                  float4* __restrict__ outmem) {
  const int gid = blockIdx.x * 256 + threadIdx.x;
  const int h = gid >> 14, off = gid & 16383;
  float sx = 0.f, sy = 0.f, sz = 0.f, sw = 0.f;
#pragma unroll 4
  for (int c = 0; c < 16; ++c) {
    float4 v = P[((size_t)(h * 16 + c) << 14) + off];
    sx += v.x; sy += v.y; sz += v.z; sw += v.w;
  }
  float4 m = mem[gid];
  float4 o;
  o.x = m.x + 0.25f * sx; o.y = m.y + 0.25f * sy;
  o.z = m.z + 0.25f * sz; o.w = m.w + 0.25f * sw;
  outmem[gid] = o;
}

// ---------------------------------------------------------------------------
// z_new[h][d] = z[h][d] + (1/B) sum_{b,s} sk[b,h,s,d]
// grid 512 (4 h x 128 chunks of 64 rows), 256 threads (4 waves x 64 lanes,
// float4 per lane), block-level reduce, one atomic add per block.
// ---------------------------------------------------------------------------
__global__ __launch_bounds__(256) void z_update(const float* __restrict__ SK,
                                                const float* __restrict__ z_in,
                                                float* __restrict__ z_out) {
  __shared__ float4 red[256];
  const int h = blockIdx.x >> 7, chunk = blockIdx.x & 127;
  const int wid = threadIdx.x >> 6, lane = threadIdx.x & 63;
  const int m0 = chunk * 64;
  float4 s = {0.f, 0.f, 0.f, 0.f};
#pragma unroll
  for (int i = 0; i < 16; ++i) {
    const int row = m0 + i * 4 + wid;
    float4 v = *(const float4*)(SK + (size_t)row * Dsz + h * HDsz + lane * 4);
    s.x += v.x; s.y += v.y; s.z += v.z; s.w += v.w;
  }
  red[wid * 64 + lane] = s;
  __syncthreads();
  if (wid == 0) {
    float4 a = red[lane], b = red[64 + lane], c = red[128 + lane], d = red[192 + lane];
    a.x = (a.x + b.x + c.x + d.x) * 0.25f;
    a.y = (a.y + b.y + c.y + d.y) * 0.25f;
    a.z = (a.z + b.z + c.z + d.z) * 0.25f;
    a.w = (a.w + b.w + c.w + d.w) * 0.25f;
    if (chunk == 0) {
      const float4 z4 = *(const float4*)(z_in + h * HDsz + lane * 4);
      a.x += z4.x; a.y += z4.y; a.z += z4.z; a.w += z4.w;
    }
    float* zp = z_out + h * HDsz + lane * 4;
    atomicAdd(zp + 0, a.x);
    atomicAdd(zp + 1, a.y);
    atomicAdd(zp + 2, a.z);
    atomicAdd(zp + 3, a.w);
  }
}

// ---------------------------------------------------------------------------
extern "C" void kernel_launch(void* const* d_in, const int* in_sizes, int n_in,
                              void* d_out, int out_size, void* d_ws, size_t ws_size,
                              hipStream_t stream) {
  (void)in_sizes; (void)n_in; (void)out_size; (void)ws_size;
  const float* Hs = (const float*)d_in[0];
  const float* Wq = (const float*)d_in[1];
  const float* Wk = (const float*)d_in[2];
  const float* Wv = (const float*)d_in[3];
  const float* Wo = (const float*)d_in[4];
  const float* bo = (const float*)d_in[5];
  const float* betas = (const float*)d_in[6];
  const float* mem = (const float*)d_in[7];
  const float* z = (const float*)d_in[8];

  // fp32 workspace region
  float* ws = (float*)d_ws;
  float* Qb = ws;                    // 8388608 : Q fp32 -> sq
  float* Kb = ws + 8388608;          // K fp32 -> sk
  float* Vb = ws + 16777216;         // V fp32 -> W = v - delta
  float* At = ws + 25165824;         // attn out fp32 [bh][s][e]
  float* dq = ws + 33554432;         // 32768
  float* dk = ws + 33587200;         // 32768
  float* mlb = ws + 33619968;        // 81920 (4 planes x 20480)
  // bf16 region
  u16* ub = (u16*)(ws + 33701888);
  u16* Wqb = ub;                     // 4 x 1048576 weight copies
  u16* Wkb = ub + 1048576;
  u16* Wvb = ub + 2097152;
  u16* Wob = ub + 3145728;
  u16* Qbf = ub + 4194304;           // bf16 Q; later reused as bf16 blend
  u16* Kbf = ub + 12582912;
  u16* Vt = ub + 20971520;           // 8388608 u16: Hs bf16 first, then V^T
  u16* Hsb = Vt;                     // alias: dead once transpose_v runs
  float* P = (float*)Vt;             // mem partials alias (dead after attn)
  float* Pb = (float*)d_out;         // split-attn chunk-1 partials (21 MB),
                                     // written+read before final out GEMM

  float* out = (float*)d_out;                 // 8192x1024
  float* outmem = out + (size_t)Msz * Dsz;    // 4x256x256
  float* outz = outmem + Hsz * HDsz * HDsz;   // 4x256

  hipMemsetAsync(outz, 0, (size_t)(Hsz * HDsz) * sizeof(float), stream);

  cvt_bf16<<<1024, 256, 0, stream>>>((const float4*)Wq, Wqb);
  cvt_bf16<<<1024, 256, 0, stream>>>((const float4*)Wk, Wkb);
  cvt_bf16<<<1024, 256, 0, stream>>>((const float4*)Wv, Wvb);
  cvt_bf16<<<1024, 256, 0, stream>>>((const float4*)Wo, Wob);
  cvt_bf16<<<8192, 256, 0, stream>>>((const float4*)Hs, Hsb);

  dim3 gg(8, 64);  // N/128, M/128
  gemm_lds<<<gg, 256, 0, stream>>>(Hsb, Wqb, nullptr, Qb, Qbf);
  gemm_lds<<<gg, 256, 0, stream>>>(Hsb, Wkb, nullptr, Kb, Kbf);
  gemm_lds<<<gg, 256, 0, stream>>>(Hsb, Wvb, nullptr, Vb, nullptr);

  transpose_v<<<dim3(64, 8, 16), 256, 0, stream>>>(Vb, Vt);
  attn_mfma<<<dim3(52, 16), 256, 0, stream>>>(Qbf, Kbf, Vt, At, Pb, mlb);
  attn_merge<<<dim3(20, 16), 256, 0, stream>>>(At, Pb, mlb);

  eludens<<<8192, 256, 0, stream>>>(Qb, Kb, z, dq, dk);

  memread_mfma<<<dim3(2, 64, 4), 256, 0, stream>>>(Qb, mem, dq, betas, At, nullptr, Qbf, 0);
  memread_mfma<<<dim3(2, 64, 4), 256, 0, stream>>>(Kb, mem, dk, betas, nullptr, Vb, nullptr, 1);

  mem_update_mfma<<<dim3(4, 4, 16), 256, 0, stream>>>(Kb, Vb, P);
  mem_reduce<<<256, 256, 0, stream>>>((const float4*)P, (const float4*)mem, (float4*)outmem);
  z_update<<<512, 256, 0, stream>>>(Kb, z, outz);

  gemm_lds<<<gg, 256, 0, stream>>>(Qbf, Wob, bo, out, nullptr);
}

// Round 7
// 498.822 us; speedup vs baseline: 1.3751x; 1.0499x over previous
//
#include <hip/hip_runtime.h>

// Problem constants (B,S,D,H fixed by the reference)
#define Bsz 4
#define Ssz 2048
#define Dsz 1024
#define Hsz 4
#define HDsz 256
#define Msz 8192  // Bsz*Ssz
#define LOG2E 1.4426950408889634f

typedef unsigned short u16;
typedef __attribute__((ext_vector_type(8))) short bf16x8;  // 8 bf16 in 4 VGPRs
typedef __attribute__((ext_vector_type(4))) float f32x4;

__device__ __forceinline__ u16 f2b(float f) {  // fp32 -> bf16 RNE
  unsigned u = __float_as_uint(f);
  return (u16)((u + 0x7FFFu + ((u >> 16) & 1u)) >> 16);
}
__device__ __forceinline__ unsigned pk2(float a, float b) {
  return (unsigned)f2b(a) | ((unsigned)f2b(b) << 16);
}
__device__ __forceinline__ float ex2(float x) {  // 2^x, single v_exp_f32
#if __has_builtin(__builtin_amdgcn_exp2f)
  return __builtin_amdgcn_exp2f(x);
#else
  return exp2f(x);
#endif
}

// async global->LDS, 16B per lane; LDS dest = wave-uniform base + lane*16
typedef const unsigned int __attribute__((address_space(1)))* gcp;
typedef unsigned int __attribute__((address_space(3)))* lcp;
__device__ __forceinline__ void gld16(const u16* g, u16* l) {
  __builtin_amdgcn_global_load_lds((gcp)g, (lcp)l, 16, 0, 0);
}

// ---------------------------------------------------------------------------
// fp32 -> bf16 elementwise
// ---------------------------------------------------------------------------
__global__ __launch_bounds__(256) void cvt_bf16(const float4* __restrict__ in,
                                                u16* __restrict__ outp) {
  size_t i = (size_t)blockIdx.x * 256 + threadIdx.x;
  float4 v = in[i];
  uint2 r; r.x = pk2(v.x, v.y); r.y = pk2(v.z, v.w);
  *(uint2*)(outp + i * 4) = r;
}

// ---------------------------------------------------------------------------
// bf16 MFMA GEMM: C[M,N] = A[M,K]*W[N,K]^T (+bias).
// 128x128 tile, BK=64 (halves barrier/drain events vs BK=32; LDS 32KB still
// within the 3-blocks/CU VGPR cap). global_load_lds width-16 staging.
// Rows are 128B -> every row starts at bank 0, so the 16B slot index is
// XOR-swizzled with (row&7) on the GLOBAL source and the same involution is
// applied on the ds_read side: 8 lanes per slot-position, uniform over 8
// positions = b128 floor (conflict-free).
// XCD-aware block swizzle (T1). cbfs scales the bf16 output only (used to
// pre-scale Q by log2e for the exp2-domain attention).
// ---------------------------------------------------------------------------
__global__ __launch_bounds__(256) void gemm_lds(const u16* __restrict__ A16,
                                                const u16* __restrict__ Wb,
                                                const float* __restrict__ bias,
                                                float* __restrict__ C32,
                                                u16* __restrict__ Cbf,
                                                float cbfs) {
  __shared__ u16 sA[128 * 64];
  __shared__ u16 sB[128 * 64];
  const int tid = threadIdx.x;
  const int lane = tid & 63, quad = lane >> 4, l15 = lane & 15;
  const int w = tid >> 6;
  const int mw = (w >> 1) * 64, nw = (w & 1) * 64;
  const int bid = blockIdx.y * 8 + blockIdx.x;
  const int nb = (bid & 7) * 64 + (bid >> 3);   // XCD swizzle
  const int m0 = (nb >> 3) * 128, n0 = (nb & 7) * 128;
  // staging: thread t covers row (t>>3)+32i, phys 16B slot (t&7);
  // content = logical slot (t&7)^(row&7); row&7 == (t>>3)&7 for all i.
  const int r0 = tid >> 3;
  const int seg = ((tid & 7) ^ (r0 & 7)) * 8;   // logical col (elems)
  const u16* ga0 = A16 + (size_t)(m0 + r0) * Dsz + seg;
  const u16* gb0 = Wb + (size_t)(n0 + r0) * Dsz + seg;
  f32x4 acc[4][4] = {};
  for (int k0 = 0; k0 < Dsz; k0 += 64) {
    __syncthreads();
#pragma unroll
    for (int i = 0; i < 4; ++i) {
      gld16(ga0 + (size_t)(i * 32) * Dsz + k0, sA + i * 2048 + w * 512);
      gld16(gb0 + (size_t)(i * 32) * Dsz + k0, sB + i * 2048 + w * 512);
    }
    __syncthreads();  // compiler drains vmcnt before barrier
#pragma unroll
    for (int dd = 0; dd < 2; ++dd) {
      bf16x8 af[4], bfr[4];
#pragma unroll
      for (int i = 0; i < 4; ++i) {
        const int sl = ((quad + 4 * dd) ^ (l15 & 7)) * 8;
        af[i] = *(const bf16x8*)&sA[(mw + i * 16 + l15) * 64 + sl];
        bfr[i] = *(const bf16x8*)&sB[(nw + i * 16 + l15) * 64 + sl];
      }
#pragma unroll
      for (int i = 0; i < 4; ++i)
#pragma unroll
        for (int j = 0; j < 4; ++j)
          acc[i][j] = __builtin_amdgcn_mfma_f32_16x16x32_bf16(af[i], bfr[j], acc[i][j], 0, 0, 0);
    }
  }
#pragma unroll
  for (int j = 0; j < 4; ++j) {
    const int n = n0 + nw + j * 16 + l15;
    const float bv = bias ? bias[n] : 0.f;
#pragma unroll
    for (int i = 0; i < 4; ++i) {
#pragma unroll
      for (int r = 0; r < 4; ++r) {
        const int m = m0 + mw + i * 16 + quad * 4 + r;
        const float val = acc[i][j][r] + bv;
        const size_t idx = (size_t)m * Dsz + n;
        if (C32) C32[idx] = val;
        if (Cbf) Cbf[idx] = f2b(val * cbfs);
      }
    }
  }
}

// ---------------------------------------------------------------------------
// V [b][s][h*256+e] fp32 -> V^T bf16 [bh][e][s]
// ---------------------------------------------------------------------------
__global__ __launch_bounds__(256) void transpose_v(const float* __restrict__ V,
                                                   u16* __restrict__ Vt) {
  __shared__ u16 tile[32 * 36];
  const int t = threadIdx.x;
  const int s0 = blockIdx.x * 32, e0 = blockIdx.y * 32, bh = blockIdx.z;
  const int b = bh >> 2, h = bh & 3;
  {
    const int s_l = t >> 3, e8 = (t & 7) * 4;
    float4 v = *(const float4*)(V + ((size_t)(b * Ssz) + s0 + s_l) * Dsz + h * HDsz + e0 + e8);
    uint2 r; r.x = pk2(v.x, v.y); r.y = pk2(v.z, v.w);
    *(uint2*)&tile[s_l * 36 + e8] = r;
  }
  __syncthreads();
  {
    const int e_l = t >> 3, s4 = (t & 7) * 4;
    u16 a = tile[(s4 + 0) * 36 + e_l], b2 = tile[(s4 + 1) * 36 + e_l];
    u16 c = tile[(s4 + 2) * 36 + e_l], d = tile[(s4 + 3) * 36 + e_l];
    uint2 r; r.x = (unsigned)a | ((unsigned)b2 << 16);
    r.y = (unsigned)c | ((unsigned)d << 16);
    *(uint2*)(Vt + ((size_t)bh * HDsz + e0 + e_l) * Ssz + s0 + s4) = r;
  }
}

// ---------------------------------------------------------------------------
// Flash attention, bf16 MFMA, flash-decoding split-K.  EXP2-DOMAIN:
// Q bf16 is pre-scaled by log2e, so scores are log2-domain; exp -> exp2,
// (m,l) stored in log2-domain (merge uses exp2 as well).
// 64-row Q-block, 4 waves; sK dbuf (32KB) + sV single (16KB) = 48KB,
// 3 blocks/CU.  Per tile: barrier A -> issue V(kt)+K(kt+1) -> QK+softmax
// (covers loads) -> barrier B -> PV.
// VALU diet (round-4 showed VALUBusy 33% vs MfmaUtil 11%):
//  - defer-max (T13): skip o-rescale + m-update when all(mt-m_old<=11)
//  - pack p->bf16 FIRST, then 8 bpermutes + 4 selects redistribute the
//    pk-words for the PV A-operand (replaces 16 bpermutes + ~40 selects)
//  - ex2 = v_exp_f32 directly (no per-exp mul)
// NO setprio (measured-negative for barrier-locked blocks, round 3).
// ---------------------------------------------------------------------------
__global__ __launch_bounds__(256) void attn_mfma(const u16* __restrict__ Qg,
                                                 const u16* __restrict__ Kg,
                                                 const u16* __restrict__ Vtg,
                                                 float* __restrict__ At,
                                                 float* __restrict__ Pb,
                                                 float* __restrict__ mlb) {
  // entry = qt | (cc<<6) | (split<<7); sorted by chunk size desc
  static const unsigned char tab[52] = {
      (unsigned char)(31|0x80), (unsigned char)(31|0xC0),
      (unsigned char)(30|0x80), (unsigned char)(30|0xC0),
      (unsigned char)(29|0x80), (unsigned char)(29|0xC0),
      (unsigned char)(28|0x80), (unsigned char)(28|0xC0),
      (unsigned char)(27|0x80), (unsigned char)(27|0xC0),
      (unsigned char)(26|0x80), (unsigned char)(26|0xC0),
      (unsigned char)(25|0x80), (unsigned char)(25|0xC0),
      (unsigned char)(24|0x80), (unsigned char)(24|0xC0),
      (unsigned char)(23|0x80), (unsigned char)(23|0xC0),
      11,
      (unsigned char)(22|0x80), (unsigned char)(22|0xC0),
      (unsigned char)(21|0x80), (unsigned char)(21|0xC0),
      10,
      (unsigned char)(20|0x80), (unsigned char)(20|0xC0),
      (unsigned char)(19|0x80), (unsigned char)(19|0xC0),
      9,
      (unsigned char)(18|0x80), (unsigned char)(18|0xC0),
      (unsigned char)(17|0x80), (unsigned char)(17|0xC0),
      8,
      (unsigned char)(16|0x80), (unsigned char)(16|0xC0),
      (unsigned char)(15|0x80), (unsigned char)(15|0xC0),
      7,
      (unsigned char)(14|0x80), (unsigned char)(14|0xC0),
      (unsigned char)(13|0x80), (unsigned char)(13|0xC0),
      6,
      (unsigned char)(12|0x80), (unsigned char)(12|0xC0),
      5, 4, 3, 2, 1, 0};
  const int e = tab[blockIdx.x];
  const int qt = e & 63, cc = (e >> 6) & 1;
  const bool split = (e >> 7) != 0;
  const int bh = blockIdx.y, b = bh >> 2, h = bh & 3;
  const int tid = threadIdx.x, w = tid >> 6, lane = tid & 63;
  const int quad = lane >> 4, l15 = lane & 15;
  __shared__ u16 sK[2][32 * 256];   // [buf][s-row][d-col], slots swizzled by row&7
  __shared__ u16 sV[256 * 32];      // [e-row][s-col], slots swizzled by (row>>1)&3
  const int q0w = qt * 64 + w * 16;
  bf16x8 qf[8];
  {
    const u16* qp = Qg + ((size_t)(b * Ssz) + q0w + l15) * Dsz + h * HDsz + quad * 8;
#pragma unroll
    for (int dd = 0; dd < 8; ++dd) qf[dd] = *(const bf16x8*)(qp + dd * 32);
  }
  f32x4 o[16] = {};
  float m_old = -1e30f, l = 0.f;
  const int nkt = 2 * qt + 2, half = qt + 1;
  const int kt_lo = (split && cc) ? half : 0;
  const int kt_hi = (split && !cc) ? half : nkt;
  // Staging source pointers (per-thread; swizzled GLOBAL column, linear LDS):
  const u16* kstage = Kg + ((size_t)(b * Ssz) + (tid >> 5)) * Dsz + h * HDsz
                      + (((tid & 31) ^ ((tid >> 5) & 7)) << 3);
  const u16* vstage = Vtg + ((size_t)bh * HDsz + (tid >> 2)) * Ssz
                      + (((tid & 3) ^ ((tid >> 3) & 3)) << 3);
  int bufc = 0;
  {  // prologue: prefetch first K tile into buffer 0
    const u16* kp = kstage + (size_t)(kt_lo * 32) * Dsz;
#pragma unroll
    for (int i = 0; i < 4; ++i)
      gld16(kp + (size_t)i * 8 * Dsz, &sK[0][w * 512 + i * 2048]);
  }
  for (int kt = kt_lo; kt < kt_hi; ++kt) {
    const int j0 = kt * 32;
    __syncthreads();  // A: K(kt) landed; all waves done with sV (PV of kt-1)
    {  // stage V(kt) into the single V buffer; lands by barrier B
      const u16* vp = vstage + kt * 32;
#pragma unroll
      for (int i = 0; i < 4; ++i)
        gld16(vp + (size_t)i * 64 * Ssz, &sV[w * 512 + i * 2048]);
    }
    if (kt + 1 < kt_hi) {  // prefetch next K tile into the other buffer
      const u16* kp = kstage + (size_t)((kt + 1) * 32) * Dsz;
      const int bn = bufc ^ 1;
#pragma unroll
      for (int i = 0; i < 4; ++i)
        gld16(kp + (size_t)i * 8 * Dsz, &sK[bn][w * 512 + i * 2048]);
    }
    // QK^T: two half-chains per score vector (halves dependent-MFMA depth)
    f32x4 s0a = {}, s0b = {}, s1a = {}, s1b = {};
#pragma unroll
    for (int dd = 0; dd < 4; ++dd) {
      const int c0 = ((dd * 4 + quad) ^ (l15 & 7)) << 3;  // (16+l15)&7 == l15&7
      const int c1 = (((dd + 4) * 4 + quad) ^ (l15 & 7)) << 3;
      bf16x8 a0 = *(const bf16x8*)&sK[bufc][l15 * 256 + c0];
      bf16x8 a1 = *(const bf16x8*)&sK[bufc][(16 + l15) * 256 + c0];
      bf16x8 b0 = *(const bf16x8*)&sK[bufc][l15 * 256 + c1];
      bf16x8 b1 = *(const bf16x8*)&sK[bufc][(16 + l15) * 256 + c1];
      s0a = __builtin_amdgcn_mfma_f32_16x16x32_bf16(a0, qf[dd], s0a, 0, 0, 0);
      s1a = __builtin_amdgcn_mfma_f32_16x16x32_bf16(a1, qf[dd], s1a, 0, 0, 0);
      s0b = __builtin_amdgcn_mfma_f32_16x16x32_bf16(b0, qf[dd + 4], s0b, 0, 0, 0);
      s1b = __builtin_amdgcn_mfma_f32_16x16x32_bf16(b1, qf[dd + 4], s1b, 0, 0, 0);
    }
    f32x4 s0v = s0a + s0b, s1v = s1a + s1b;
    const int qg = q0w + l15;
    float p[8];
#pragma unroll
    for (int r = 0; r < 4; ++r) {
      const int kg = j0 + quad * 4 + r;
      p[r] = (kg <= qg) ? s0v[r] : -1e30f;
      p[4 + r] = (kg + 16 <= qg) ? s1v[r] : -1e30f;
    }
    // row max over 32 k (4 quads share q = q0w+l15)
    float mt = fmaxf(fmaxf(fmaxf(p[0], p[1]), fmaxf(p[2], p[3])),
                     fmaxf(fmaxf(p[4], p[5]), fmaxf(p[6], p[7])));
    mt = fmaxf(mt, __shfl_xor(mt, 16));
    mt = fmaxf(mt, __shfl_xor(mt, 32));
    // defer-max: keep m_old when max growth <= 11 (log2 units; p <= 2^11)
    const bool keep = __all(mt - m_old <= 11.0f);
    const float m_new = keep ? m_old : fmaxf(m_old, mt);
    float ts = 0.f;
#pragma unroll
    for (int i = 0; i < 8; ++i) { p[i] = ex2(p[i] - m_new); ts += p[i]; }
    ts += __shfl_xor(ts, 16);
    ts += __shfl_xor(ts, 32);
    if (keep) {
      l += ts;
    } else {
      const float alpha = ex2(m_old - m_new);
      l = l * alpha + ts;
      m_old = m_new;
      const float a0_ = __shfl(alpha, (lane & 48) | (quad * 4 + 0));
      const float a1_ = __shfl(alpha, (lane & 48) | (quad * 4 + 1));
      const float a2_ = __shfl(alpha, (lane & 48) | (quad * 4 + 2));
      const float a3_ = __shfl(alpha, (lane & 48) | (quad * 4 + 3));
#pragma unroll
      for (int ds = 0; ds < 16; ++ds) {
        o[ds][0] *= a0_; o[ds][1] *= a1_; o[ds][2] *= a2_; o[ds][3] *= a3_;
      }
    }
    // pack first (4 pk2), then redistribute pk-words: lane(quad,l15) pulls
    // k = quad*8..+7 for q=l15.  src lanes: l15 | (2*(quad&1)+(j>>1))<<4;
    // a-words (k<16, from s0v) if quad<2 else b-words (s1v).
    const unsigned a0p = pk2(p[0], p[1]), a1p = pk2(p[2], p[3]);
    const unsigned b0p = pk2(p[4], p[5]), b1p = pk2(p[6], p[7]);
    const int sAl = l15 | ((quad & 1) << 5);
    const int sBl = sAl | 16;
    const unsigned xa0 = __shfl(a0p, sAl), xa1 = __shfl(a1p, sAl);
    const unsigned xb0 = __shfl(b0p, sAl), xb1 = __shfl(b1p, sAl);
    const unsigned ya0 = __shfl(a0p, sBl), ya1 = __shfl(a1p, sBl);
    const unsigned yb0 = __shfl(b0p, sBl), yb1 = __shfl(b1p, sBl);
    const bool hi2 = quad >= 2;
    uint4 pkv;
    pkv.x = hi2 ? xb0 : xa0;
    pkv.y = hi2 ? xb1 : xa1;
    pkv.z = hi2 ? yb0 : ya0;
    pkv.w = hi2 ? yb1 : ya1;
    bf16x8 pf = *(bf16x8*)&pkv;
    const int vc0 = (quad ^ ((l15 >> 1) & 3)) << 3;  // (row>>1)&3 == (l15>>1)&3
    __syncthreads();  // B: V(kt) landed (also early-drains K(kt+1))
#pragma unroll
    for (int ds = 0; ds < 16; ++ds) {
      bf16x8 bv = *(const bf16x8*)&sV[(ds * 16 + l15) * 32 + vc0];
      o[ds] = __builtin_amdgcn_mfma_f32_16x16x32_bf16(pf, bv, o[ds], 0, 0, 0);
    }
    bufc ^= 1;
  }
  if (!split) {
    float lr[4];
#pragma unroll
    for (int r = 0; r < 4; ++r) lr[r] = 1.f / __shfl(l, (lane & 48) | (quad * 4 + r));
    float* ob = At + ((size_t)bh * Ssz + q0w + quad * 4) * HDsz + l15;
#pragma unroll
    for (int r = 0; r < 4; ++r)
#pragma unroll
      for (int ds = 0; ds < 16; ++ds)
        ob[(size_t)r * HDsz + ds * 16] = o[ds][r] * lr[r];
  } else {
    float* dst;
    if (cc == 0)
      dst = At + ((size_t)bh * Ssz + q0w + quad * 4) * HDsz + l15;
    else
      dst = Pb + ((size_t)((bh * 20 + (qt - 12)) * 64) + w * 16 + quad * 4) * HDsz + l15;
#pragma unroll
    for (int r = 0; r < 4; ++r)
#pragma unroll
      for (int ds = 0; ds < 16; ++ds)
        dst[(size_t)r * HDsz + ds * 16] = o[ds][r];
    if (lane < 16) {
      const int idx = (bh * 20 + (qt - 12)) * 64 + w * 16 + l15;
      mlb[cc * 40960 + idx] = m_old;   // log2-domain
      mlb[cc * 40960 + 20480 + idx] = l;
    }
  }
}

// ---------------------------------------------------------------------------
// Merge the two split-K chunks for qt>=12 (log2-domain m):
// O = (O0*2^{m0-m}+O1*2^{m1-m}) / (l0*2^{m0-m}+l1*2^{m1-m}).  grid (20, 16).
// ---------------------------------------------------------------------------
__global__ __launch_bounds__(256) void attn_merge(float* __restrict__ At,
                                                  const float* __restrict__ Pb,
                                                  const float* __restrict__ mlb) {
  const int qx = blockIdx.x, bh = blockIdx.y;
  const int t = threadIdx.x;
  const int slot = (bh * 20 + qx) * 64;
  float4* abase = (float4*)(At + ((size_t)bh * Ssz + (12 + qx) * 64) * HDsz);
  const float4* pbase = (const float4*)(Pb + (size_t)slot * HDsz);
#pragma unroll
  for (int i = 0; i < 16; ++i) {
    const int f = i * 256 + t;  // f4 index 0..4095, coalesced
    const int qr = f >> 6;
    const int idx = slot + qr;
    const float m0 = mlb[idx], l0 = mlb[20480 + idx];
    const float m1 = mlb[40960 + idx], l1 = mlb[61440 + idx];
    const float mm = fmaxf(m0, m1);
    const float w0 = ex2(m0 - mm), w1 = ex2(m1 - mm);
    const float inv = 1.f / (l0 * w0 + l1 * w1);
    float4 av = abase[f];
    float4 pv = pbase[f];
    float4 ov;
    ov.x = (av.x * w0 + pv.x * w1) * inv;
    ov.y = (av.y * w0 + pv.y * w1) * inv;
    ov.z = (av.z * w0 + pv.z * w1) * inv;
    ov.w = (av.w * w0 + pv.w * w1) * inv;
    abase[f] = ov;
  }
}

// ---------------------------------------------------------------------------
// Fused: sq=elu(q)+1, sk=elu(k)+1 (in place) + denq = sq.z, denk = sk.z.
// One wave per row; grid 8192 x 256.
// ---------------------------------------------------------------------------
__global__ __launch_bounds__(256) void eludens(float* __restrict__ Qb,
                                               float* __restrict__ Kb,
                                               const float* __restrict__ z,
                                               float* __restrict__ dq,
                                               float* __restrict__ dk) {
  const int wid = threadIdx.x >> 6, lane = threadIdx.x & 63;
  const int r = blockIdx.x * 4 + wid;
  const int b = r >> 13, h = (r >> 11) & 3, s = r & 2047;
  const size_t base = ((size_t)(b * Ssz + s)) * Dsz + h * HDsz + lane * 4;
  float4 z4 = *(const float4*)(z + h * HDsz + lane * 4);
  float4 q = *(float4*)(Qb + base);
  q.x = q.x > 0.f ? q.x + 1.f : __expf(q.x);
  q.y = q.y > 0.f ? q.y + 1.f : __expf(q.y);
  q.z = q.z > 0.f ? q.z + 1.f : __expf(q.z);
  q.w = q.w > 0.f ? q.w + 1.f : __expf(q.w);
  *(float4*)(Qb + base) = q;
  float4 k = *(float4*)(Kb + base);
  k.x = k.x > 0.f ? k.x + 1.f : __expf(k.x);
  k.y = k.y > 0.f ? k.y + 1.f : __expf(k.y);
  k.z = k.z > 0.f ? k.z + 1.f : __expf(k.z);
  k.w = k.w > 0.f ? k.w + 1.f : __expf(k.w);
  *(float4*)(Kb + base) = k;
  float pq = q.x * z4.x + q.y * z4.y + q.z * z4.z + q.w * z4.w;
  float pk = k.x * z4.x + k.y * z4.y + k.z * z4.z + k.w * z4.w;
#pragma unroll
  for (int off = 32; off; off >>= 1) {
    pq += __shfl_down(pq, off);
    pk += __shfl_down(pk, off);
  }
  if (lane == 0) { dq[r] = pq; dk[r] = pk; }
}

// ---------------------------------------------------------------------------
// Per-head MFMA GEMM: acc[m,e] = sum_d Asrc[m,h*256+d] * mem[h][d][e].
// mode 0: blend = g*acc/den + (1-g)*At -> bf16 row-major (bfout)
// mode 1: Vio = v - acc/den (fp32 in place)
// ---------------------------------------------------------------------------
__global__ __launch_bounds__(256) void memread_mfma(const float* __restrict__ Asrc,
                                                    const float* __restrict__ mem,
                                                    const float* __restrict__ dens,
                                                    const float* __restrict__ betas,
                                                    const float* __restrict__ At,
                                                    float* __restrict__ Vio,
                                                    u16* __restrict__ bfout, int mode) {
  const int h = blockIdx.z;
  const int tid = threadIdx.x, lane = tid & 63, w = tid >> 6;
  const int quad = lane >> 4, l15 = lane & 15;
  const int mw = (w >> 1) * 64, ew = (w & 1) * 64;
  const int m0 = blockIdx.y * 128, e0t = blockIdx.x * 128;
  __shared__ u16 sA[128 * 40];  // [m][k]
  __shared__ u16 sB[128 * 40];  // [e][k]
  const int srow = tid >> 1, sseg = (tid & 1) * 16;
  const int k4 = (tid & 7) * 4, e4 = (tid >> 3) * 4;
  f32x4 acc[4][4] = {};
  for (int k0 = 0; k0 < HDsz; k0 += 32) {
    __syncthreads();
    {
      const float* ap = Asrc + (size_t)(m0 + srow) * Dsz + h * HDsz + k0 + sseg;
      float4 f0 = *(const float4*)ap, f1 = *(const float4*)(ap + 4);
      float4 f2 = *(const float4*)(ap + 8), f3 = *(const float4*)(ap + 12);
      uint4 u0, u1;
      u0.x = pk2(f0.x, f0.y); u0.y = pk2(f0.z, f0.w);
      u0.z = pk2(f1.x, f1.y); u0.w = pk2(f1.z, f1.w);
      u1.x = pk2(f2.x, f2.y); u1.y = pk2(f2.z, f2.w);
      u1.z = pk2(f3.x, f3.y); u1.w = pk2(f3.z, f3.w);
      u16* dst = &sA[srow * 40 + sseg];
      *(uint4*)dst = u0; *(uint4*)(dst + 8) = u1;
    }
    {
      const float* bp = mem + (size_t)h * 65536 + (size_t)(k0 + k4) * HDsz + e0t + e4;
      float4 r0 = *(const float4*)bp;
      float4 r1 = *(const float4*)(bp + HDsz);
      float4 r2 = *(const float4*)(bp + 2 * HDsz);
      float4 r3 = *(const float4*)(bp + 3 * HDsz);
      const float* rr[4] = {(const float*)&r0, (const float*)&r1,
                            (const float*)&r2, (const float*)&r3};
#pragma unroll
      for (int c = 0; c < 4; ++c) {
        uint2 u;
        u.x = pk2(rr[0][c], rr[1][c]);
        u.y = pk2(rr[2][c], rr[3][c]);
        *(uint2*)&sB[(e4 + c) * 40 + k4] = u;
      }
    }
    __syncthreads();
    bf16x8 af[4], bfr[4];
#pragma unroll
    for (int i = 0; i < 4; ++i) {
      af[i] = *(const bf16x8*)&sA[(mw + i * 16 + l15) * 40 + quad * 8];
      bfr[i] = *(const bf16x8*)&sB[(ew + i * 16 + l15) * 40 + quad * 8];
    }
#pragma unroll
    for (int i = 0; i < 4; ++i)
#pragma unroll
      for (int j = 0; j < 4; ++j)
        acc[i][j] = __builtin_amdgcn_mfma_f32_16x16x32_bf16(af[i], bfr[j], acc[i][j], 0, 0, 0);
  }
  const float g = 1.f / (1.f + __expf(-betas[h]));
#pragma unroll
  for (int i = 0; i < 4; ++i) {
#pragma unroll
    for (int r = 0; r < 4; ++r) {
      const int m = m0 + mw + i * 16 + quad * 4 + r;
      const int b = m >> 11, s = m & 2047;
      const int rowidx = ((b << 2) + h) * Ssz + s;
      const float inv = 1.f / (dens[rowidx] + 1e-6f);
#pragma unroll
      for (int j = 0; j < 4; ++j) {
        const int e = e0t + ew + j * 16 + l15;
        const float av = acc[i][j][r] * inv;
        if (mode == 0) {
          const float a = At[(size_t)rowidx * HDsz + e];
          bfout[(size_t)m * Dsz + h * HDsz + e] = f2b(g * av + (1.f - g) * a);
        } else {
          float* p = Vio + (size_t)m * Dsz + h * HDsz + e;
          *p = *p - av;
        }
      }
    }
  }
}

// ---------------------------------------------------------------------------
// mem partials: P[(h*16+chunk)][d][e] = sum_{m in chunk} sk[m,..d]*W[m,..e]
// ---------------------------------------------------------------------------
__global__ __launch_bounds__(256) void mem_update_mfma(const float* __restrict__ SK,
                                                       const float* __restrict__ W,
                                                       float* __restrict__ P) {
  const int de = blockIdx.x;
  const int d0 = (de >> 1) * 128, e0 = (de & 1) * 128;
  const int h = blockIdx.y, chunk = blockIdx.z;
  const int m0 = chunk * 512;
  const int tid = threadIdx.x, lane = tid & 63, w = tid >> 6;
  const int quad = lane >> 4, l15 = lane & 15;
  const int dw = (w >> 1) * 64, ew = (w & 1) * 64;
  __shared__ u16 sA[128 * 40];  // [d][m]
  __shared__ u16 sB[128 * 40];  // [e][m]
  const int m4 = (tid & 7) * 4;
  const int c4 = (tid >> 3) * 4;
  f32x4 acc[4][4] = {};
  for (int mt = 0; mt < 512; mt += 32) {
    __syncthreads();
    const float* ka = SK + (size_t)(m0 + mt + m4) * Dsz + h * HDsz + d0 + c4;
    const float* wa = W + (size_t)(m0 + mt + m4) * Dsz + h * HDsz + e0 + c4;
    float4 a0 = *(const float4*)ka;
    float4 a1 = *(const float4*)(ka + Dsz);
    float4 a2 = *(const float4*)(ka + 2 * Dsz);
    float4 a3 = *(const float4*)(ka + 3 * Dsz);
    float4 b0 = *(const float4*)wa;
    float4 b1 = *(const float4*)(wa + Dsz);
    float4 b2 = *(const float4*)(wa + 2 * Dsz);
    float4 b3 = *(const float4*)(wa + 3 * Dsz);
    const float* aa[4] = {(const float*)&a0, (const float*)&a1,
                          (const float*)&a2, (const float*)&a3};
    const float* bb[4] = {(const float*)&b0, (const float*)&b1,
                          (const float*)&b2, (const float*)&b3};
#pragma unroll
    for (int c = 0; c < 4; ++c) {
      uint2 ua, ub2;
      ua.x = pk2(aa[0][c], aa[1][c]); ua.y = pk2(aa[2][c], aa[3][c]);
      ub2.x = pk2(bb[0][c], bb[1][c]); ub2.y = pk2(bb[2][c], bb[3][c]);
      *(uint2*)&sA[(c4 + c) * 40 + m4] = ua;
      *(uint2*)&sB[(c4 + c) * 40 + m4] = ub2;
    }
    __syncthreads();
    bf16x8 af[4], bfr[4];
#pragma unroll
    for (int i = 0; i < 4; ++i) {
      af[i] = *(const bf16x8*)&sA[(dw + i * 16 + l15) * 40 + quad * 8];
      bfr[i] = *(const bf16x8*)&sB[(ew + i * 16 + l15) * 40 + quad * 8];
    }
#pragma unroll
    for (int i = 0; i < 4; ++i)
#pragma unroll
      for (int j = 0; j < 4; ++j)
        acc[i][j] = __builtin_amdgcn_mfma_f32_16x16x32_bf16(af[i], bfr[j], acc[i][j], 0, 0, 0);
  }
  float* Pp = P + ((size_t)(h * 16 + chunk)) * 65536;
#pragma unroll
  for (int i = 0; i < 4; ++i)
#pragma unroll
    for (int r = 0; r < 4; ++r) {
      const int d = d0 + dw + i * 16 + quad * 4 + r;
#pragma unroll
      for (int j = 0; j < 4; ++j) {
        const int e = e0 + ew + j * 16 + l15;
        Pp[(size_t)d * HDsz + e] = acc[i][j][r];
      }
    }
}

// ---------------------------------------------------------------------------
// outmem = mem + 0.25 * sum_{chunk} P[h*16+chunk]
// ---------------------------------------------------------------------------
__global__ __launch_bounds__(256) void mem_reduce(const float4* __restrict__ P,
                                                  const float4* __restrict__ mem,
                                                  float4* __restrict__ outmem) {
  const int gid = blockIdx.x * 256 + threadIdx.x;
  const int h = gid >> 14, off = gid & 16383;
  float sx = 0.f, sy = 0.f, sz = 0.f, sw = 0.f;
#pragma unroll 4
  for (int c = 0; c < 16; ++c) {
    float4 v = P[((size_t)(h * 16 + c) << 14) + off];
    sx += v.x; sy += v.y; sz += v.z; sw += v.w;
  }
  float4 m = mem[gid];
  float4 o;
  o.x = m.x + 0.25f * sx; o.y = m.y + 0.25f * sy;
  o.z = m.z + 0.25f * sz; o.w = m.w + 0.25f * sw;
  outmem[gid] = o;
}

// ---------------------------------------------------------------------------
// z_new[h][d] = z[h][d] + (1/B) sum_{b,s} sk[b,h,s,d]
// grid 512 (4 h x 128 chunks of 64 rows), 256 threads (4 waves x 64 lanes,
// float4 per lane), block-level reduce, one atomic add per block.
// ---------------------------------------------------------------------------
__global__ __launch_bounds__(256) void z_update(const float* __restrict__ SK,
                                                const float* __restrict__ z_in,
                                                float* __restrict__ z_out) {
  __shared__ float4 red[256];
  const int h = blockIdx.x >> 7, chunk = blockIdx.x & 127;
  const int wid = threadIdx.x >> 6, lane = threadIdx.x & 63;
  const int m0 = chunk * 64;
  float4 s = {0.f, 0.f, 0.f, 0.f};
#pragma unroll
  for (int i = 0; i < 16; ++i) {
    const int row = m0 + i * 4 + wid;
    float4 v = *(const float4*)(SK + (size_t)row * Dsz + h * HDsz + lane * 4);
    s.x += v.x; s.y += v.y; s.z += v.z; s.w += v.w;
  }
  red[wid * 64 + lane] = s;
  __syncthreads();
  if (wid == 0) {
    float4 a = red[lane], b = red[64 + lane], c = red[128 + lane], d = red[192 + lane];
    a.x = (a.x + b.x + c.x + d.x) * 0.25f;
    a.y = (a.y + b.y + c.y + d.y) * 0.25f;
    a.z = (a.z + b.z + c.z + d.z) * 0.25f;
    a.w = (a.w + b.w + c.w + d.w) * 0.25f;
    if (chunk == 0) {
      const float4 z4 = *(const float4*)(z_in + h * HDsz + lane * 4);
      a.x += z4.x; a.y += z4.y; a.z += z4.z; a.w += z4.w;
    }
    float* zp = z_out + h * HDsz + lane * 4;
    atomicAdd(zp + 0, a.x);
    atomicAdd(zp + 1, a.y);
    atomicAdd(zp + 2, a.z);
    atomicAdd(zp + 3, a.w);
  }
}

// ---------------------------------------------------------------------------
extern "C" void kernel_launch(void* const* d_in, const int* in_sizes, int n_in,
                              void* d_out, int out_size, void* d_ws, size_t ws_size,
                              hipStream_t stream) {
  (void)in_sizes; (void)n_in; (void)out_size; (void)ws_size;
  const float* Hs = (const float*)d_in[0];
  const float* Wq = (const float*)d_in[1];
  const float* Wk = (const float*)d_in[2];
  const float* Wv = (const float*)d_in[3];
  const float* Wo = (const float*)d_in[4];
  const float* bo = (const float*)d_in[5];
  const float* betas = (const float*)d_in[6];
  const float* mem = (const float*)d_in[7];
  const float* z = (const float*)d_in[8];

  // fp32 workspace region
  float* ws = (float*)d_ws;
  float* Qb = ws;                    // 8388608 : Q fp32 -> sq
  float* Kb = ws + 8388608;          // K fp32 -> sk
  float* Vb = ws + 16777216;         // V fp32 -> W = v - delta
  float* At = ws + 25165824;         // attn out fp32 [bh][s][e]
  float* dq = ws + 33554432;         // 32768
  float* dk = ws + 33587200;         // 32768
  float* mlb = ws + 33619968;        // 81920 (4 planes x 20480)
  // bf16 region
  u16* ub = (u16*)(ws + 33701888);
  u16* Wqb = ub;                     // 4 x 1048576 weight copies
  u16* Wkb = ub + 1048576;
  u16* Wvb = ub + 2097152;
  u16* Wob = ub + 3145728;
  u16* Qbf = ub + 4194304;           // bf16 Q (log2e-scaled); later bf16 blend
  u16* Kbf = ub + 12582912;
  u16* Vt = ub + 20971520;           // 8388608 u16: Hs bf16 first, then V^T
  u16* Hsb = Vt;                     // alias: dead once transpose_v runs
  float* P = (float*)Vt;             // mem partials alias (dead after attn)
  float* Pb = (float*)d_out;         // split-attn chunk-1 partials (21 MB),
                                     // written+read before final out GEMM

  float* out = (float*)d_out;                 // 8192x1024
  float* outmem = out + (size_t)Msz * Dsz;    // 4x256x256
  float* outz = outmem + Hsz * HDsz * HDsz;   // 4x256

  hipMemsetAsync(outz, 0, (size_t)(Hsz * HDsz) * sizeof(float), stream);

  cvt_bf16<<<1024, 256, 0, stream>>>((const float4*)Wq, Wqb);
  cvt_bf16<<<1024, 256, 0, stream>>>((const float4*)Wk, Wkb);
  cvt_bf16<<<1024, 256, 0, stream>>>((const float4*)Wv, Wvb);
  cvt_bf16<<<1024, 256, 0, stream>>>((const float4*)Wo, Wob);
  cvt_bf16<<<8192, 256, 0, stream>>>((const float4*)Hs, Hsb);

  dim3 gg(8, 64);  // N/128, M/128
  gemm_lds<<<gg, 256, 0, stream>>>(Hsb, Wqb, nullptr, Qb, Qbf, LOG2E);
  gemm_lds<<<gg, 256, 0, stream>>>(Hsb, Wkb, nullptr, Kb, Kbf, 1.f);
  gemm_lds<<<gg, 256, 0, stream>>>(Hsb, Wvb, nullptr, Vb, nullptr, 1.f);

  transpose_v<<<dim3(64, 8, 16), 256, 0, stream>>>(Vb, Vt);
  attn_mfma<<<dim3(52, 16), 256, 0, stream>>>(Qbf, Kbf, Vt, At, Pb, mlb);
  attn_merge<<<dim3(20, 16), 256, 0, stream>>>(At, Pb, mlb);

  eludens<<<8192, 256, 0, stream>>>(Qb, Kb, z, dq, dk);

  memread_mfma<<<dim3(2, 64, 4), 256, 0, stream>>>(Qb, mem, dq, betas, At, nullptr, Qbf, 0);
  memread_mfma<<<dim3(2, 64, 4), 256, 0, stream>>>(Kb, mem, dk, betas, nullptr, Vb, nullptr, 1);

  mem_update_mfma<<<dim3(4, 4, 16), 256, 0, stream>>>(Kb, Vb, P);
  mem_reduce<<<256, 256, 0, stream>>>((const float4*)P, (const float4*)mem, (float4*)outmem);
  z_update<<<512, 256, 0, stream>>>(Kb, z, outz);

  gemm_lds<<<gg, 256, 0, stream>>>(Qbf, Wob, bo, out, nullptr, 1.f);
}

// Round 8
// 487.098 us; speedup vs baseline: 1.4082x; 1.0241x over previous
//
#include <hip/hip_runtime.h>

// Problem constants (B,S,D,H fixed by the reference)
#define Bsz 4
#define Ssz 2048
#define Dsz 1024
#define Hsz 4
#define HDsz 256
#define Msz 8192  // Bsz*Ssz
#define LOG2E 1.4426950408889634f

typedef unsigned short u16;
typedef __attribute__((ext_vector_type(8))) short bf16x8;  // 8 bf16 in 4 VGPRs
typedef __attribute__((ext_vector_type(4))) float f32x4;

__device__ __forceinline__ u16 f2b(float f) {  // fp32 -> bf16 RNE
  unsigned u = __float_as_uint(f);
  return (u16)((u + 0x7FFFu + ((u >> 16) & 1u)) >> 16);
}
__device__ __forceinline__ unsigned pk2(float a, float b) {
  return (unsigned)f2b(a) | ((unsigned)f2b(b) << 16);
}
__device__ __forceinline__ float ex2(float x) {  // 2^x, single v_exp_f32
#if __has_builtin(__builtin_amdgcn_exp2f)
  return __builtin_amdgcn_exp2f(x);
#else
  return exp2f(x);
#endif
}

// async global->LDS, 16B per lane; LDS dest = wave-uniform base + lane*16
typedef const unsigned int __attribute__((address_space(1)))* gcp;
typedef unsigned int __attribute__((address_space(3)))* lcp;
__device__ __forceinline__ void gld16(const u16* g, u16* l) {
  __builtin_amdgcn_global_load_lds((gcp)g, (lcp)l, 16, 0, 0);
}

// ---------------------------------------------------------------------------
// fp32 -> bf16 elementwise
// ---------------------------------------------------------------------------
__global__ __launch_bounds__(256) void cvt_bf16(const float4* __restrict__ in,
                                                u16* __restrict__ outp) {
  size_t i = (size_t)blockIdx.x * 256 + threadIdx.x;
  float4 v = in[i];
  uint2 r; r.x = pk2(v.x, v.y); r.y = pk2(v.z, v.w);
  *(uint2*)(outp + i * 4) = r;
}

// ---------------------------------------------------------------------------
// bf16 MFMA GEMM: C[M,N] = A[M,K]*W[N,K]^T (+bias).
// 128x128 tile, BK=64, global_load_lds width-16 staging, XOR slot swizzle
// (content slot = phys ^ (row&7)) on the GLOBAL source + same involution on
// ds_read -> conflict-free b128 reads. XCD-aware block swizzle (T1).
// cbfs scales the bf16 output only (log2e pre-scale for exp2-domain attn).
// ---------------------------------------------------------------------------
__global__ __launch_bounds__(256) void gemm_lds(const u16* __restrict__ A16,
                                                const u16* __restrict__ Wb,
                                                const float* __restrict__ bias,
                                                float* __restrict__ C32,
                                                u16* __restrict__ Cbf,
                                                float cbfs) {
  __shared__ u16 sA[128 * 64];
  __shared__ u16 sB[128 * 64];
  const int tid = threadIdx.x;
  const int lane = tid & 63, quad = lane >> 4, l15 = lane & 15;
  const int w = tid >> 6;
  const int mw = (w >> 1) * 64, nw = (w & 1) * 64;
  const int bid = blockIdx.y * 8 + blockIdx.x;
  const int nb = (bid & 7) * 64 + (bid >> 3);   // XCD swizzle
  const int m0 = (nb >> 3) * 128, n0 = (nb & 7) * 128;
  const int r0 = tid >> 3;
  const int seg = ((tid & 7) ^ (r0 & 7)) * 8;   // logical col (elems)
  const u16* ga0 = A16 + (size_t)(m0 + r0) * Dsz + seg;
  const u16* gb0 = Wb + (size_t)(n0 + r0) * Dsz + seg;
  f32x4 acc[4][4] = {};
  for (int k0 = 0; k0 < Dsz; k0 += 64) {
    __syncthreads();
#pragma unroll
    for (int i = 0; i < 4; ++i) {
      gld16(ga0 + (size_t)(i * 32) * Dsz + k0, sA + i * 2048 + w * 512);
      gld16(gb0 + (size_t)(i * 32) * Dsz + k0, sB + i * 2048 + w * 512);
    }
    __syncthreads();  // compiler drains vmcnt before barrier
#pragma unroll
    for (int dd = 0; dd < 2; ++dd) {
      bf16x8 af[4], bfr[4];
#pragma unroll
      for (int i = 0; i < 4; ++i) {
        const int sl = ((quad + 4 * dd) ^ (l15 & 7)) * 8;
        af[i] = *(const bf16x8*)&sA[(mw + i * 16 + l15) * 64 + sl];
        bfr[i] = *(const bf16x8*)&sB[(nw + i * 16 + l15) * 64 + sl];
      }
#pragma unroll
      for (int i = 0; i < 4; ++i)
#pragma unroll
        for (int j = 0; j < 4; ++j)
          acc[i][j] = __builtin_amdgcn_mfma_f32_16x16x32_bf16(af[i], bfr[j], acc[i][j], 0, 0, 0);
    }
  }
#pragma unroll
  for (int j = 0; j < 4; ++j) {
    const int n = n0 + nw + j * 16 + l15;
    const float bv = bias ? bias[n] : 0.f;
#pragma unroll
    for (int i = 0; i < 4; ++i) {
#pragma unroll
      for (int r = 0; r < 4; ++r) {
        const int m = m0 + mw + i * 16 + quad * 4 + r;
        const float val = acc[i][j][r] + bv;
        const size_t idx = (size_t)m * Dsz + n;
        if (C32) C32[idx] = val;
        if (Cbf) Cbf[idx] = f2b(val * cbfs);
      }
    }
  }
}

// ---------------------------------------------------------------------------
// V [b][s][h*256+e] fp32 -> V^T bf16 [bh][e][s]
// ---------------------------------------------------------------------------
__global__ __launch_bounds__(256) void transpose_v(const float* __restrict__ V,
                                                   u16* __restrict__ Vt) {
  __shared__ u16 tile[32 * 36];
  const int t = threadIdx.x;
  const int s0 = blockIdx.x * 32, e0 = blockIdx.y * 32, bh = blockIdx.z;
  const int b = bh >> 2, h = bh & 3;
  {
    const int s_l = t >> 3, e8 = (t & 7) * 4;
    float4 v = *(const float4*)(V + ((size_t)(b * Ssz) + s0 + s_l) * Dsz + h * HDsz + e0 + e8);
    uint2 r; r.x = pk2(v.x, v.y); r.y = pk2(v.z, v.w);
    *(uint2*)&tile[s_l * 36 + e8] = r;
  }
  __syncthreads();
  {
    const int e_l = t >> 3, s4 = (t & 7) * 4;
    u16 a = tile[(s4 + 0) * 36 + e_l], b2 = tile[(s4 + 1) * 36 + e_l];
    u16 c = tile[(s4 + 2) * 36 + e_l], d = tile[(s4 + 3) * 36 + e_l];
    uint2 r; r.x = (unsigned)a | ((unsigned)b2 << 16);
    r.y = (unsigned)c | ((unsigned)d << 16);
    *(uint2*)(Vt + ((size_t)bh * HDsz + e0 + e_l) * Ssz + s0 + s4) = r;
  }
}

// ---------------------------------------------------------------------------
// bf16 [b,s][h*256+c] -> bf16 [bh][c][s]  (used for SKb->SKt and Wb16->Wt)
// ---------------------------------------------------------------------------
__global__ __launch_bounds__(256) void transpose_b16(const u16* __restrict__ src,
                                                     u16* __restrict__ dst) {
  __shared__ u16 tile[32 * 36];
  const int t = threadIdx.x;
  const int s0 = blockIdx.x * 32, c0 = blockIdx.y * 32, bh = blockIdx.z;
  const int b = bh >> 2, h = bh & 3;
  {
    const int s_l = t >> 3, c8 = (t & 7) * 4;
    uint2 v = *(const uint2*)(src + ((size_t)(b * Ssz) + s0 + s_l) * Dsz + h * HDsz + c0 + c8);
    *(uint2*)&tile[s_l * 36 + c8] = v;
  }
  __syncthreads();
  {
    const int c_l = t >> 3, s4 = (t & 7) * 4;
    u16 a = tile[(s4 + 0) * 36 + c_l], b2 = tile[(s4 + 1) * 36 + c_l];
    u16 c = tile[(s4 + 2) * 36 + c_l], d = tile[(s4 + 3) * 36 + c_l];
    uint2 r; r.x = (unsigned)a | ((unsigned)b2 << 16);
    r.y = (unsigned)c | ((unsigned)d << 16);
    *(uint2*)(dst + ((size_t)bh * HDsz + c0 + c_l) * Ssz + s0 + s4) = r;
  }
}

// ---------------------------------------------------------------------------
// mem fp32 [h][d][e] -> memT bf16 [h][e][d].  grid (8, 8, 4).
// ---------------------------------------------------------------------------
__global__ __launch_bounds__(256) void transpose_mem(const float* __restrict__ mem,
                                                     u16* __restrict__ memT) {
  __shared__ u16 tile[32 * 36];
  const int t = threadIdx.x;
  const int d0 = blockIdx.x * 32, e0 = blockIdx.y * 32, h = blockIdx.z;
  {
    const int d_l = t >> 3, e8 = (t & 7) * 4;
    float4 v = *(const float4*)(mem + (size_t)h * 65536 + (size_t)(d0 + d_l) * HDsz + e0 + e8);
    uint2 r; r.x = pk2(v.x, v.y); r.y = pk2(v.z, v.w);
    *(uint2*)&tile[d_l * 36 + e8] = r;
  }
  __syncthreads();
  {
    const int e_l = t >> 3, d4 = (t & 7) * 4;
    u16 a = tile[(d4 + 0) * 36 + e_l], b2 = tile[(d4 + 1) * 36 + e_l];
    u16 c = tile[(d4 + 2) * 36 + e_l], d = tile[(d4 + 3) * 36 + e_l];
    uint2 r; r.x = (unsigned)a | ((unsigned)b2 << 16);
    r.y = (unsigned)c | ((unsigned)d << 16);
    *(uint2*)(memT + (size_t)h * 65536 + (size_t)(e0 + e_l) * HDsz + d0 + d4) = r;
  }
}

// ---------------------------------------------------------------------------
// Flash attention, bf16 MFMA, flash-decoding split-K.  EXP2-DOMAIN.
// (unchanged from round 7: 64-row Q-block, sK dbuf + sV single = 48KB,
// 3 blocks/CU, defer-max, pack-then-shuffle, ex2.)
// ---------------------------------------------------------------------------
__global__ __launch_bounds__(256) void attn_mfma(const u16* __restrict__ Qg,
                                                 const u16* __restrict__ Kg,
                                                 const u16* __restrict__ Vtg,
                                                 float* __restrict__ At,
                                                 float* __restrict__ Pb,
                                                 float* __restrict__ mlb) {
  // entry = qt | (cc<<6) | (split<<7); sorted by chunk size desc
  static const unsigned char tab[52] = {
      (unsigned char)(31|0x80), (unsigned char)(31|0xC0),
      (unsigned char)(30|0x80), (unsigned char)(30|0xC0),
      (unsigned char)(29|0x80), (unsigned char)(29|0xC0),
      (unsigned char)(28|0x80), (unsigned char)(28|0xC0),
      (unsigned char)(27|0x80), (unsigned char)(27|0xC0),
      (unsigned char)(26|0x80), (unsigned char)(26|0xC0),
      (unsigned char)(25|0x80), (unsigned char)(25|0xC0),
      (unsigned char)(24|0x80), (unsigned char)(24|0xC0),
      (unsigned char)(23|0x80), (unsigned char)(23|0xC0),
      11,
      (unsigned char)(22|0x80), (unsigned char)(22|0xC0),
      (unsigned char)(21|0x80), (unsigned char)(21|0xC0),
      10,
      (unsigned char)(20|0x80), (unsigned char)(20|0xC0),
      (unsigned char)(19|0x80), (unsigned char)(19|0xC0),
      9,
      (unsigned char)(18|0x80), (unsigned char)(18|0xC0),
      (unsigned char)(17|0x80), (unsigned char)(17|0xC0),
      8,
      (unsigned char)(16|0x80), (unsigned char)(16|0xC0),
      (unsigned char)(15|0x80), (unsigned char)(15|0xC0),
      7,
      (unsigned char)(14|0x80), (unsigned char)(14|0xC0),
      (unsigned char)(13|0x80), (unsigned char)(13|0xC0),
      6,
      (unsigned char)(12|0x80), (unsigned char)(12|0xC0),
      5, 4, 3, 2, 1, 0};
  const int e = tab[blockIdx.x];
  const int qt = e & 63, cc = (e >> 6) & 1;
  const bool split = (e >> 7) != 0;
  const int bh = blockIdx.y, b = bh >> 2, h = bh & 3;
  const int tid = threadIdx.x, w = tid >> 6, lane = tid & 63;
  const int quad = lane >> 4, l15 = lane & 15;
  __shared__ u16 sK[2][32 * 256];   // [buf][s-row][d-col], slots swizzled by row&7
  __shared__ u16 sV[256 * 32];      // [e-row][s-col], slots swizzled by (row>>1)&3
  const int q0w = qt * 64 + w * 16;
  bf16x8 qf[8];
  {
    const u16* qp = Qg + ((size_t)(b * Ssz) + q0w + l15) * Dsz + h * HDsz + quad * 8;
#pragma unroll
    for (int dd = 0; dd < 8; ++dd) qf[dd] = *(const bf16x8*)(qp + dd * 32);
  }
  f32x4 o[16] = {};
  float m_old = -1e30f, l = 0.f;
  const int nkt = 2 * qt + 2, half = qt + 1;
  const int kt_lo = (split && cc) ? half : 0;
  const int kt_hi = (split && !cc) ? half : nkt;
  const u16* kstage = Kg + ((size_t)(b * Ssz) + (tid >> 5)) * Dsz + h * HDsz
                      + (((tid & 31) ^ ((tid >> 5) & 7)) << 3);
  const u16* vstage = Vtg + ((size_t)bh * HDsz + (tid >> 2)) * Ssz
                      + (((tid & 3) ^ ((tid >> 3) & 3)) << 3);
  int bufc = 0;
  {  // prologue: prefetch first K tile into buffer 0
    const u16* kp = kstage + (size_t)(kt_lo * 32) * Dsz;
#pragma unroll
    for (int i = 0; i < 4; ++i)
      gld16(kp + (size_t)i * 8 * Dsz, &sK[0][w * 512 + i * 2048]);
  }
  for (int kt = kt_lo; kt < kt_hi; ++kt) {
    const int j0 = kt * 32;
    __syncthreads();  // A: K(kt) landed; all waves done with sV (PV of kt-1)
    {  // stage V(kt) into the single V buffer; lands by barrier B
      const u16* vp = vstage + kt * 32;
#pragma unroll
      for (int i = 0; i < 4; ++i)
        gld16(vp + (size_t)i * 64 * Ssz, &sV[w * 512 + i * 2048]);
    }
    if (kt + 1 < kt_hi) {  // prefetch next K tile into the other buffer
      const u16* kp = kstage + (size_t)((kt + 1) * 32) * Dsz;
      const int bn = bufc ^ 1;
#pragma unroll
      for (int i = 0; i < 4; ++i)
        gld16(kp + (size_t)i * 8 * Dsz, &sK[bn][w * 512 + i * 2048]);
    }
    // QK^T: two half-chains per score vector (halves dependent-MFMA depth)
    f32x4 s0a = {}, s0b = {}, s1a = {}, s1b = {};
#pragma unroll
    for (int dd = 0; dd < 4; ++dd) {
      const int c0 = ((dd * 4 + quad) ^ (l15 & 7)) << 3;  // (16+l15)&7 == l15&7
      const int c1 = (((dd + 4) * 4 + quad) ^ (l15 & 7)) << 3;
      bf16x8 a0 = *(const bf16x8*)&sK[bufc][l15 * 256 + c0];
      bf16x8 a1 = *(const bf16x8*)&sK[bufc][(16 + l15) * 256 + c0];
      bf16x8 b0 = *(const bf16x8*)&sK[bufc][l15 * 256 + c1];
      bf16x8 b1 = *(const bf16x8*)&sK[bufc][(16 + l15) * 256 + c1];
      s0a = __builtin_amdgcn_mfma_f32_16x16x32_bf16(a0, qf[dd], s0a, 0, 0, 0);
      s1a = __builtin_amdgcn_mfma_f32_16x16x32_bf16(a1, qf[dd], s1a, 0, 0, 0);
      s0b = __builtin_amdgcn_mfma_f32_16x16x32_bf16(b0, qf[dd + 4], s0b, 0, 0, 0);
      s1b = __builtin_amdgcn_mfma_f32_16x16x32_bf16(b1, qf[dd + 4], s1b, 0, 0, 0);
    }
    f32x4 s0v = s0a + s0b, s1v = s1a + s1b;
    const int qg = q0w + l15;
    float p[8];
#pragma unroll
    for (int r = 0; r < 4; ++r) {
      const int kg = j0 + quad * 4 + r;
      p[r] = (kg <= qg) ? s0v[r] : -1e30f;
      p[4 + r] = (kg + 16 <= qg) ? s1v[r] : -1e30f;
    }
    float mt = fmaxf(fmaxf(fmaxf(p[0], p[1]), fmaxf(p[2], p[3])),
                     fmaxf(fmaxf(p[4], p[5]), fmaxf(p[6], p[7])));
    mt = fmaxf(mt, __shfl_xor(mt, 16));
    mt = fmaxf(mt, __shfl_xor(mt, 32));
    // defer-max: keep m_old when max growth <= 11 (log2 units; p <= 2^11)
    const bool keep = __all(mt - m_old <= 11.0f);
    const float m_new = keep ? m_old : fmaxf(m_old, mt);
    float ts = 0.f;
#pragma unroll
    for (int i = 0; i < 8; ++i) { p[i] = ex2(p[i] - m_new); ts += p[i]; }
    ts += __shfl_xor(ts, 16);
    ts += __shfl_xor(ts, 32);
    if (keep) {
      l += ts;
    } else {
      const float alpha = ex2(m_old - m_new);
      l = l * alpha + ts;
      m_old = m_new;
      const float a0_ = __shfl(alpha, (lane & 48) | (quad * 4 + 0));
      const float a1_ = __shfl(alpha, (lane & 48) | (quad * 4 + 1));
      const float a2_ = __shfl(alpha, (lane & 48) | (quad * 4 + 2));
      const float a3_ = __shfl(alpha, (lane & 48) | (quad * 4 + 3));
#pragma unroll
      for (int ds = 0; ds < 16; ++ds) {
        o[ds][0] *= a0_; o[ds][1] *= a1_; o[ds][2] *= a2_; o[ds][3] *= a3_;
      }
    }
    const unsigned a0p = pk2(p[0], p[1]), a1p = pk2(p[2], p[3]);
    const unsigned b0p = pk2(p[4], p[5]), b1p = pk2(p[6], p[7]);
    const int sAl = l15 | ((quad & 1) << 5);
    const int sBl = sAl | 16;
    const unsigned xa0 = __shfl(a0p, sAl), xa1 = __shfl(a1p, sAl);
    const unsigned xb0 = __shfl(b0p, sAl), xb1 = __shfl(b1p, sAl);
    const unsigned ya0 = __shfl(a0p, sBl), ya1 = __shfl(a1p, sBl);
    const unsigned yb0 = __shfl(b0p, sBl), yb1 = __shfl(b1p, sBl);
    const bool hi2 = quad >= 2;
    uint4 pkv;
    pkv.x = hi2 ? xb0 : xa0;
    pkv.y = hi2 ? xb1 : xa1;
    pkv.z = hi2 ? yb0 : ya0;
    pkv.w = hi2 ? yb1 : ya1;
    bf16x8 pf = *(bf16x8*)&pkv;
    const int vc0 = (quad ^ ((l15 >> 1) & 3)) << 3;  // (row>>1)&3 == (l15>>1)&3
    __syncthreads();  // B: V(kt) landed (also early-drains K(kt+1))
#pragma unroll
    for (int ds = 0; ds < 16; ++ds) {
      bf16x8 bv = *(const bf16x8*)&sV[(ds * 16 + l15) * 32 + vc0];
      o[ds] = __builtin_amdgcn_mfma_f32_16x16x32_bf16(pf, bv, o[ds], 0, 0, 0);
    }
    bufc ^= 1;
  }
  if (!split) {
    float lr[4];
#pragma unroll
    for (int r = 0; r < 4; ++r) lr[r] = 1.f / __shfl(l, (lane & 48) | (quad * 4 + r));
    float* ob = At + ((size_t)bh * Ssz + q0w + quad * 4) * HDsz + l15;
#pragma unroll
    for (int r = 0; r < 4; ++r)
#pragma unroll
      for (int ds = 0; ds < 16; ++ds)
        ob[(size_t)r * HDsz + ds * 16] = o[ds][r] * lr[r];
  } else {
    float* dst;
    if (cc == 0)
      dst = At + ((size_t)bh * Ssz + q0w + quad * 4) * HDsz + l15;
    else
      dst = Pb + ((size_t)((bh * 20 + (qt - 12)) * 64) + w * 16 + quad * 4) * HDsz + l15;
#pragma unroll
    for (int r = 0; r < 4; ++r)
#pragma unroll
      for (int ds = 0; ds < 16; ++ds)
        dst[(size_t)r * HDsz + ds * 16] = o[ds][r];
    if (lane < 16) {
      const int idx = (bh * 20 + (qt - 12)) * 64 + w * 16 + l15;
      mlb[cc * 40960 + idx] = m_old;   // log2-domain
      mlb[cc * 40960 + 20480 + idx] = l;
    }
  }
}

// ---------------------------------------------------------------------------
// Merge the two split-K chunks for qt>=12 (log2-domain m).  grid (20, 16).
// ---------------------------------------------------------------------------
__global__ __launch_bounds__(256) void attn_merge(float* __restrict__ At,
                                                  const float* __restrict__ Pb,
                                                  const float* __restrict__ mlb) {
  const int qx = blockIdx.x, bh = blockIdx.y;
  const int t = threadIdx.x;
  const int slot = (bh * 20 + qx) * 64;
  float4* abase = (float4*)(At + ((size_t)bh * Ssz + (12 + qx) * 64) * HDsz);
  const float4* pbase = (const float4*)(Pb + (size_t)slot * HDsz);
#pragma unroll
  for (int i = 0; i < 16; ++i) {
    const int f = i * 256 + t;  // f4 index 0..4095, coalesced
    const int qr = f >> 6;
    const int idx = slot + qr;
    const float m0 = mlb[idx], l0 = mlb[20480 + idx];
    const float m1 = mlb[40960 + idx], l1 = mlb[61440 + idx];
    const float mm = fmaxf(m0, m1);
    const float w0 = ex2(m0 - mm), w1 = ex2(m1 - mm);
    const float inv = 1.f / (l0 * w0 + l1 * w1);
    float4 av = abase[f];
    float4 pv = pbase[f];
    float4 ov;
    ov.x = (av.x * w0 + pv.x * w1) * inv;
    ov.y = (av.y * w0 + pv.y * w1) * inv;
    ov.z = (av.z * w0 + pv.z * w1) * inv;
    ov.w = (av.w * w0 + pv.w * w1) * inv;
    abase[f] = ov;
  }
}

// ---------------------------------------------------------------------------
// Fused: sq=elu(q)+1, sk=elu(k)+1 (fp32 in place + bf16 copies) +
// denq = sq.z, denk = sk.z.  One wave per row; grid 8192 x 256.
// ---------------------------------------------------------------------------
__global__ __launch_bounds__(256) void eludens(float* __restrict__ Qb,
                                               float* __restrict__ Kb,
                                               const float* __restrict__ z,
                                               float* __restrict__ dq,
                                               float* __restrict__ dk,
                                               u16* __restrict__ SQb,
                                               u16* __restrict__ SKb) {
  const int wid = threadIdx.x >> 6, lane = threadIdx.x & 63;
  const int r = blockIdx.x * 4 + wid;
  const int b = r >> 13, h = (r >> 11) & 3, s = r & 2047;
  const size_t base = ((size_t)(b * Ssz + s)) * Dsz + h * HDsz + lane * 4;
  float4 z4 = *(const float4*)(z + h * HDsz + lane * 4);
  float4 q = *(float4*)(Qb + base);
  q.x = q.x > 0.f ? q.x + 1.f : __expf(q.x);
  q.y = q.y > 0.f ? q.y + 1.f : __expf(q.y);
  q.z = q.z > 0.f ? q.z + 1.f : __expf(q.z);
  q.w = q.w > 0.f ? q.w + 1.f : __expf(q.w);
  *(float4*)(Qb + base) = q;
  { uint2 qb; qb.x = pk2(q.x, q.y); qb.y = pk2(q.z, q.w);
    *(uint2*)(SQb + base) = qb; }
  float4 k = *(float4*)(Kb + base);
  k.x = k.x > 0.f ? k.x + 1.f : __expf(k.x);
  k.y = k.y > 0.f ? k.y + 1.f : __expf(k.y);
  k.z = k.z > 0.f ? k.z + 1.f : __expf(k.z);
  k.w = k.w > 0.f ? k.w + 1.f : __expf(k.w);
  *(float4*)(Kb + base) = k;
  { uint2 kb; kb.x = pk2(k.x, k.y); kb.y = pk2(k.z, k.w);
    *(uint2*)(SKb + base) = kb; }
  float pq = q.x * z4.x + q.y * z4.y + q.z * z4.z + q.w * z4.w;
  float pk = k.x * z4.x + k.y * z4.y + k.z * z4.z + k.w * z4.w;
#pragma unroll
  for (int off = 32; off; off >>= 1) {
    pq += __shfl_down(pq, off);
    pk += __shfl_down(pk, off);
  }
  if (lane == 0) { dq[r] = pq; dk[r] = pk; }
}

// ---------------------------------------------------------------------------
// Per-head MFMA GEMM (gemm_lds-style gld16 staging, BK=64, XOR swizzle):
// acc[m,e] = sum_d A16[m,h*256+d] * memT[h][e][d].
// mode 0: blend = g*acc/den + (1-g)*At -> bf16 (bfout)
// mode 1: bfout = bf16(Vb - acc/den)   (the W operand for mem update)
// grid (2, 64, 4).
// ---------------------------------------------------------------------------
__global__ __launch_bounds__(256) void memread_mfma(const u16* __restrict__ A16,
                                                    const u16* __restrict__ memT,
                                                    const float* __restrict__ dens,
                                                    const float* __restrict__ betas,
                                                    const float* __restrict__ At,
                                                    const float* __restrict__ Vb,
                                                    u16* __restrict__ bfout, int mode) {
  __shared__ u16 sA[128 * 64];
  __shared__ u16 sB[128 * 64];
  const int h = blockIdx.z;
  const int tid = threadIdx.x, lane = tid & 63, w = tid >> 6;
  const int quad = lane >> 4, l15 = lane & 15;
  const int mw = (w >> 1) * 64, ew = (w & 1) * 64;
  const int m0 = blockIdx.y * 128, e0t = blockIdx.x * 128;
  const int r0 = tid >> 3;
  const int seg = ((tid & 7) ^ (r0 & 7)) * 8;
  const u16* ga0 = A16 + (size_t)(m0 + r0) * Dsz + h * HDsz + seg;
  const u16* gb0 = memT + (size_t)h * 65536 + (size_t)(e0t + r0) * HDsz + seg;
  f32x4 acc[4][4] = {};
  for (int k0 = 0; k0 < HDsz; k0 += 64) {
    __syncthreads();
#pragma unroll
    for (int i = 0; i < 4; ++i) {
      gld16(ga0 + (size_t)(i * 32) * Dsz + k0, sA + i * 2048 + w * 512);
      gld16(gb0 + (size_t)(i * 32) * HDsz + k0, sB + i * 2048 + w * 512);
    }
    __syncthreads();
#pragma unroll
    for (int dd = 0; dd < 2; ++dd) {
      bf16x8 af[4], bfr[4];
#pragma unroll
      for (int i = 0; i < 4; ++i) {
        const int sl = ((quad + 4 * dd) ^ (l15 & 7)) * 8;
        af[i] = *(const bf16x8*)&sA[(mw + i * 16 + l15) * 64 + sl];
        bfr[i] = *(const bf16x8*)&sB[(ew + i * 16 + l15) * 64 + sl];
      }
#pragma unroll
      for (int i = 0; i < 4; ++i)
#pragma unroll
        for (int j = 0; j < 4; ++j)
          acc[i][j] = __builtin_amdgcn_mfma_f32_16x16x32_bf16(af[i], bfr[j], acc[i][j], 0, 0, 0);
    }
  }
  const float g = 1.f / (1.f + __expf(-betas[h]));
#pragma unroll
  for (int i = 0; i < 4; ++i) {
#pragma unroll
    for (int r = 0; r < 4; ++r) {
      const int m = m0 + mw + i * 16 + quad * 4 + r;
      const int b = m >> 11, s = m & 2047;
      const int rowidx = ((b << 2) + h) * Ssz + s;
      const float inv = 1.f / (dens[rowidx] + 1e-6f);
#pragma unroll
      for (int j = 0; j < 4; ++j) {
        const int e = e0t + ew + j * 16 + l15;
        const float av = acc[i][j][r] * inv;
        if (mode == 0) {
          const float a = At[(size_t)rowidx * HDsz + e];
          bfout[(size_t)m * Dsz + h * HDsz + e] = f2b(g * av + (1.f - g) * a);
        } else {
          const float vv = Vb[(size_t)m * Dsz + h * HDsz + e];
          bfout[(size_t)m * Dsz + h * HDsz + e] = f2b(vv - av);
        }
      }
    }
  }
}

// ---------------------------------------------------------------------------
// mem partials (gld16 dual-staged GEMM over k=s):
// P[(h*16+chunk)][d][e] = sum_{s in chunk} SKt[bh][d][s] * Wt[bh][e][s]
// grid (4 de, 4 h, 16 chunk); K=512 per chunk, BK=64.
// ---------------------------------------------------------------------------
__global__ __launch_bounds__(256) void mem_update_mfma(const u16* __restrict__ SKt,
                                                       const u16* __restrict__ Wt,
                                                       float* __restrict__ P) {
  __shared__ u16 sA[128 * 64];
  __shared__ u16 sB[128 * 64];
  const int de = blockIdx.x;
  const int d0 = (de >> 1) * 128, e0 = (de & 1) * 128;
  const int h = blockIdx.y, chunk = blockIdx.z;
  const int b = chunk >> 2, s0 = (chunk & 3) * 512;
  const int bh = b * 4 + h;
  const int tid = threadIdx.x, lane = tid & 63, w = tid >> 6;
  const int quad = lane >> 4, l15 = lane & 15;
  const int dw = (w >> 1) * 64, ew = (w & 1) * 64;
  const int r0 = tid >> 3;
  const int seg = ((tid & 7) ^ (r0 & 7)) * 8;
  const u16* ga0 = SKt + ((size_t)bh * HDsz + d0 + r0) * Ssz + s0 + seg;
  const u16* gb0 = Wt + ((size_t)bh * HDsz + e0 + r0) * Ssz + s0 + seg;
  f32x4 acc[4][4] = {};
  for (int kk = 0; kk < 512; kk += 64) {
    __syncthreads();
#pragma unroll
    for (int i = 0; i < 4; ++i) {
      gld16(ga0 + (size_t)(i * 32) * Ssz + kk, sA + i * 2048 + w * 512);
      gld16(gb0 + (size_t)(i * 32) * Ssz + kk, sB + i * 2048 + w * 512);
    }
    __syncthreads();
#pragma unroll
    for (int dd = 0; dd < 2; ++dd) {
      bf16x8 af[4], bfr[4];
#pragma unroll
      for (int i = 0; i < 4; ++i) {
        const int sl = ((quad + 4 * dd) ^ (l15 & 7)) * 8;
        af[i] = *(const bf16x8*)&sA[(dw + i * 16 + l15) * 64 + sl];
        bfr[i] = *(const bf16x8*)&sB[(ew + i * 16 + l15) * 64 + sl];
      }
#pragma unroll
      for (int i = 0; i < 4; ++i)
#pragma unroll
        for (int j = 0; j < 4; ++j)
          acc[i][j] = __builtin_amdgcn_mfma_f32_16x16x32_bf16(af[i], bfr[j], acc[i][j], 0, 0, 0);
    }
  }
  float* Pp = P + ((size_t)(h * 16 + chunk)) * 65536;
#pragma unroll
  for (int i = 0; i < 4; ++i)
#pragma unroll
    for (int r = 0; r < 4; ++r) {
      const int d = d0 + dw + i * 16 + quad * 4 + r;
#pragma unroll
      for (int j = 0; j < 4; ++j) {
        const int e = e0 + ew + j * 16 + l15;
        Pp[(size_t)d * HDsz + e] = acc[i][j][r];
      }
    }
}

// ---------------------------------------------------------------------------
// outmem = mem + 0.25 * sum_{chunk} P[h*16+chunk]
// ---------------------------------------------------------------------------
__global__ __launch_bounds__(256) void mem_reduce(const float4* __restrict__ P,
                                                  const float4* __restrict__ mem,
                                                  float4* __restrict__ outmem) {
  const int gid = blockIdx.x * 256 + threadIdx.x;
  const int h = gid >> 14, off = gid & 16383;
  float sx = 0.f, sy = 0.f, sz = 0.f, sw = 0.f;
#pragma unroll 4
  for (int c = 0; c < 16; ++c) {
    float4 v = P[((size_t)(h * 16 + c) << 14) + off];
    sx += v.x; sy += v.y; sz += v.z; sw += v.w;
  }
  float4 m = mem[gid];
  float4 o;
  o.x = m.x + 0.25f * sx; o.y = m.y + 0.25f * sy;
  o.z = m.z + 0.25f * sz; o.w = m.w + 0.25f * sw;
  outmem[gid] = o;
}

// ---------------------------------------------------------------------------
// z_new[h][d] = z[h][d] + (1/B) sum_{b,s} sk[b,h,s,d]   (fp32 source)
// ---------------------------------------------------------------------------
__global__ __launch_bounds__(256) void z_update(const float* __restrict__ SK,
                                                const float* __restrict__ z_in,
                                                float* __restrict__ z_out) {
  __shared__ float4 red[256];
  const int h = blockIdx.x >> 7, chunk = blockIdx.x & 127;
  const int wid = threadIdx.x >> 6, lane = threadIdx.x & 63;
  const int m0 = chunk * 64;
  float4 s = {0.f, 0.f, 0.f, 0.f};
#pragma unroll
  for (int i = 0; i < 16; ++i) {
    const int row = m0 + i * 4 + wid;
    float4 v = *(const float4*)(SK + (size_t)row * Dsz + h * HDsz + lane * 4);
    s.x += v.x; s.y += v.y; s.z += v.z; s.w += v.w;
  }
  red[wid * 64 + lane] = s;
  __syncthreads();
  if (wid == 0) {
    float4 a = red[lane], b = red[64 + lane], c = red[128 + lane], d = red[192 + lane];
    a.x = (a.x + b.x + c.x + d.x) * 0.25f;
    a.y = (a.y + b.y + c.y + d.y) * 0.25f;
    a.z = (a.z + b.z + c.z + d.z) * 0.25f;
    a.w = (a.w + b.w + c.w + d.w) * 0.25f;
    if (chunk == 0) {
      const float4 z4 = *(const float4*)(z_in + h * HDsz + lane * 4);
      a.x += z4.x; a.y += z4.y; a.z += z4.z; a.w += z4.w;
    }
    float* zp = z_out + h * HDsz + lane * 4;
    atomicAdd(zp + 0, a.x);
    atomicAdd(zp + 1, a.y);
    atomicAdd(zp + 2, a.z);
    atomicAdd(zp + 3, a.w);
  }
}

// ---------------------------------------------------------------------------
extern "C" void kernel_launch(void* const* d_in, const int* in_sizes, int n_in,
                              void* d_out, int out_size, void* d_ws, size_t ws_size,
                              hipStream_t stream) {
  (void)in_sizes; (void)n_in; (void)out_size; (void)ws_size;
  const float* Hs = (const float*)d_in[0];
  const float* Wq = (const float*)d_in[1];
  const float* Wk = (const float*)d_in[2];
  const float* Wv = (const float*)d_in[3];
  const float* Wo = (const float*)d_in[4];
  const float* bo = (const float*)d_in[5];
  const float* betas = (const float*)d_in[6];
  const float* mem = (const float*)d_in[7];
  const float* z = (const float*)d_in[8];

  // fp32 workspace region
  float* ws = (float*)d_ws;
  float* Qb = ws;                    // 8388608 : Q fp32 -> sq (dead after eludens)
  float* Kb = ws + 8388608;          // K fp32 -> sk (z_update reads late)
  float* Vb = ws + 16777216;         // V fp32
  float* At = ws + 25165824;         // attn out fp32 [bh][s][e]
  float* dq = ws + 33554432;         // 32768
  float* dk = ws + 33587200;         // 32768
  float* mlb = ws + 33619968;        // 81920 (4 planes x 20480)
  // bf16 region
  u16* ub = (u16*)(ws + 33701888);
  u16* Wqb = ub;                     // 4 x 1048576 weight copies
  u16* Wkb = ub + 1048576;
  u16* Wvb = ub + 2097152;
  u16* Wob = ub + 3145728;
  u16* Qbf = ub + 4194304;           // bf16 Q (log2e-scaled); later bf16 blend
  u16* Kbf = ub + 12582912;
  u16* Vt = ub + 20971520;           // 8388608 u16: Hs bf16 first, then V^T
  u16* Hsb = Vt;                     // alias: dead once transpose_v runs
  u16* SQb = ub + 29360128;          // NEW: bf16 sq [m][1024]
  u16* memT = ub + 37748736;         // 262144 u16: mem^T bf16 [h][e][d]
  // time-sliced aliases:
  u16* SKb = Kbf;                    // bf16 sk (Kbf dead after attn)
  u16* SKt = Vt;                     // sk^T [bh][d][s] (Vt dead after attn)
  u16* Wb16 = (u16*)At;              // bf16 W [m][1024] (At dead after memread0)
  u16* Wt = (u16*)Qb;                // W^T [bh][e][s] (Qb fp32 dead after eludens)
  float* Pb = (float*)d_out;         // split-attn partials (21 MB), dead after merge
  float* P = (float*)d_out;          // mem partials (16.8 MB), written after attn,
                                     // read by mem_reduce, then out overwrites

  float* out = (float*)d_out;                 // 8192x1024
  float* outmem = out + (size_t)Msz * Dsz;    // 4x256x256
  float* outz = outmem + Hsz * HDsz * HDsz;   // 4x256

  hipMemsetAsync(outz, 0, (size_t)(Hsz * HDsz) * sizeof(float), stream);

  cvt_bf16<<<1024, 256, 0, stream>>>((const float4*)Wq, Wqb);
  cvt_bf16<<<1024, 256, 0, stream>>>((const float4*)Wk, Wkb);
  cvt_bf16<<<1024, 256, 0, stream>>>((const float4*)Wv, Wvb);
  cvt_bf16<<<1024, 256, 0, stream>>>((const float4*)Wo, Wob);
  cvt_bf16<<<8192, 256, 0, stream>>>((const float4*)Hs, Hsb);
  transpose_mem<<<dim3(8, 8, 4), 256, 0, stream>>>(mem, memT);

  dim3 gg(8, 64);  // N/128, M/128
  gemm_lds<<<gg, 256, 0, stream>>>(Hsb, Wqb, nullptr, Qb, Qbf, LOG2E);
  gemm_lds<<<gg, 256, 0, stream>>>(Hsb, Wkb, nullptr, Kb, Kbf, 1.f);
  gemm_lds<<<gg, 256, 0, stream>>>(Hsb, Wvb, nullptr, Vb, nullptr, 1.f);

  transpose_v<<<dim3(64, 8, 16), 256, 0, stream>>>(Vb, Vt);
  attn_mfma<<<dim3(52, 16), 256, 0, stream>>>(Qbf, Kbf, Vt, At, Pb, mlb);
  attn_merge<<<dim3(20, 16), 256, 0, stream>>>(At, Pb, mlb);

  eludens<<<8192, 256, 0, stream>>>(Qb, Kb, z, dq, dk, SQb, SKb);
  transpose_b16<<<dim3(64, 8, 16), 256, 0, stream>>>(SKb, SKt);

  memread_mfma<<<dim3(2, 64, 4), 256, 0, stream>>>(SQb, memT, dq, betas, At, nullptr, Qbf, 0);
  memread_mfma<<<dim3(2, 64, 4), 256, 0, stream>>>(SKb, memT, dk, betas, nullptr, Vb, Wb16, 1);
  transpose_b16<<<dim3(64, 8, 16), 256, 0, stream>>>(Wb16, Wt);

  mem_update_mfma<<<dim3(4, 4, 16), 256, 0, stream>>>(SKt, Wt, P);
  mem_reduce<<<256, 256, 0, stream>>>((const float4*)P, (const float4*)mem, (float4*)outmem);
  z_update<<<512, 256, 0, stream>>>(Kb, z, outz);

  gemm_lds<<<gg, 256, 0, stream>>>(Qbf, Wob, bo, out, nullptr, 1.f);
}

// Round 10
// 445.645 us; speedup vs baseline: 1.5392x; 1.0930x over previous
//
#include <hip/hip_runtime.h>

// Problem constants (B,S,D,H fixed by the reference)
#define Bsz 4
#define Ssz 2048
#define Dsz 1024
#define Hsz 4
#define HDsz 256
#define Msz 8192  // Bsz*Ssz
#define LOG2E 1.4426950408889634f

typedef unsigned short u16;
typedef __attribute__((ext_vector_type(8))) short bf16x8;  // 8 bf16 in 4 VGPRs
typedef __attribute__((ext_vector_type(4))) float f32x4;

__device__ __forceinline__ u16 f2b(float f) {  // fp32 -> bf16 RNE
  unsigned u = __float_as_uint(f);
  return (u16)((u + 0x7FFFu + ((u >> 16) & 1u)) >> 16);
}
__device__ __forceinline__ unsigned pk2(float a, float b) {
  return (unsigned)f2b(a) | ((unsigned)f2b(b) << 16);
}
__device__ __forceinline__ float b2f(unsigned lo16) {  // bf16 bits -> f32
  return __uint_as_float(lo16 << 16);
}
__device__ __forceinline__ float ex2(float x) {  // 2^x, single v_exp_f32
#if __has_builtin(__builtin_amdgcn_exp2f)
  return __builtin_amdgcn_exp2f(x);
#else
  return exp2f(x);
#endif
}

// async global->LDS, 16B per lane; LDS dest = wave-uniform base + lane*16
typedef const unsigned int __attribute__((address_space(1)))* gcp;
typedef unsigned int __attribute__((address_space(3)))* lcp;
__device__ __forceinline__ void gld16(const u16* g, u16* l) {
  __builtin_amdgcn_global_load_lds((gcp)g, (lcp)l, 16, 0, 0);
}

// ---------------------------------------------------------------------------
// fp32 -> bf16 elementwise (Hs)
// ---------------------------------------------------------------------------
__global__ __launch_bounds__(256) void cvt_bf16(const float4* __restrict__ in,
                                                u16* __restrict__ outp) {
  size_t i = (size_t)blockIdx.x * 256 + threadIdx.x;
  float4 v = in[i];
  uint2 r; r.x = pk2(v.x, v.y); r.y = pk2(v.z, v.w);
  *(uint2*)(outp + i * 4) = r;
}

// ---------------------------------------------------------------------------
// all 4 weight matrices fp32 -> bf16 in one launch; grid 4096.
// Each weight = 1048576 elements; weight stride in outp = 1048576 u16
// (ROUND-9 BUG: was 4194304 -> K/V/O landed in wrong regions).
// ---------------------------------------------------------------------------
__global__ __launch_bounds__(256) void cvt_w4(const float4* __restrict__ w0,
                                              const float4* __restrict__ w1,
                                              const float4* __restrict__ w2,
                                              const float4* __restrict__ w3,
                                              u16* __restrict__ outp) {
  const int blk = blockIdx.x, wsel = blk >> 10;
  const float4* src = (wsel == 0) ? w0 : (wsel == 1) ? w1 : (wsel == 2) ? w2 : w3;
  const size_t i = (size_t)(blk & 1023) * 256 + threadIdx.x;
  float4 v = src[i];
  uint2 r; r.x = pk2(v.x, v.y); r.y = pk2(v.z, v.w);
  *(uint2*)(outp + (size_t)wsel * 1048576 + i * 4) = r;
}

// ---------------------------------------------------------------------------
// bf16 MFMA GEMM: C[M,N] = A[M,K]*W[N,K]^T (+bias).
// 128x128 tile, BK=64, global_load_lds width-16 staging, XOR slot swizzle
// on the GLOBAL source + same involution on ds_read (conflict-free b128).
// XCD-aware block swizzle (T1).
// Epilogues:
//   dens == nullptr: optional C32 (+bias) and Cbf (bf16, scaled by cbfs).
//   dens != nullptr (fused elu+dens, replaces the old eludens pass):
//     Cbf[idx]  = f2b(val*cbfs)          (raw proj for attention)
//     selu[idx] = f2b(elu(val)+1)        (sq / sk)
//     dens[row] += sum_col (elu(val)+1)*zvec[h][col]  (4xshfl + 1 atomic/row)
// ---------------------------------------------------------------------------
__global__ __launch_bounds__(256) void gemm_lds(const u16* __restrict__ A16,
                                                const u16* __restrict__ Wb,
                                                const float* __restrict__ bias,
                                                float* __restrict__ C32,
                                                u16* __restrict__ Cbf,
                                                float cbfs,
                                                u16* __restrict__ selu,
                                                float* __restrict__ dens,
                                                const float* __restrict__ zvec) {
  __shared__ u16 sA[128 * 64];
  __shared__ u16 sB[128 * 64];
  const int tid = threadIdx.x;
  const int lane = tid & 63, quad = lane >> 4, l15 = lane & 15;
  const int w = tid >> 6;
  const int mw = (w >> 1) * 64, nw = (w & 1) * 64;
  const int bid = blockIdx.y * 8 + blockIdx.x;
  const int nb = (bid & 7) * 64 + (bid >> 3);   // XCD swizzle
  const int m0 = (nb >> 3) * 128, n0 = (nb & 7) * 128;
  const int r0 = tid >> 3;
  const int seg = ((tid & 7) ^ (r0 & 7)) * 8;   // logical col (elems)
  const u16* ga0 = A16 + (size_t)(m0 + r0) * Dsz + seg;
  const u16* gb0 = Wb + (size_t)(n0 + r0) * Dsz + seg;
  f32x4 acc[4][4] = {};
  for (int k0 = 0; k0 < Dsz; k0 += 64) {
    __syncthreads();
#pragma unroll
    for (int i = 0; i < 4; ++i) {
      gld16(ga0 + (size_t)(i * 32) * Dsz + k0, sA + i * 2048 + w * 512);
      gld16(gb0 + (size_t)(i * 32) * Dsz + k0, sB + i * 2048 + w * 512);
    }
    __syncthreads();  // compiler drains vmcnt before barrier
#pragma unroll
    for (int dd = 0; dd < 2; ++dd) {
      bf16x8 af[4], bfr[4];
#pragma unroll
      for (int i = 0; i < 4; ++i) {
        const int sl = ((quad + 4 * dd) ^ (l15 & 7)) * 8;
        af[i] = *(const bf16x8*)&sA[(mw + i * 16 + l15) * 64 + sl];
        bfr[i] = *(const bf16x8*)&sB[(nw + i * 16 + l15) * 64 + sl];
      }
#pragma unroll
      for (int i = 0; i < 4; ++i)
#pragma unroll
        for (int j = 0; j < 4; ++j)
          acc[i][j] = __builtin_amdgcn_mfma_f32_16x16x32_bf16(af[i], bfr[j], acc[i][j], 0, 0, 0);
    }
  }
  if (dens) {
    const int h = n0 >> 8;  // 128-col tile lies within one head
    float zq[4];
#pragma unroll
    for (int j = 0; j < 4; ++j)
      zq[j] = zvec[h * HDsz + ((n0 & 255) + nw + j * 16 + l15)];
#pragma unroll
    for (int i = 0; i < 4; ++i) {
#pragma unroll
      for (int r = 0; r < 4; ++r) {
        const int m = m0 + mw + i * 16 + quad * 4 + r;
        float pdv = 0.f;
#pragma unroll
        for (int j = 0; j < 4; ++j) {
          const int n = n0 + nw + j * 16 + l15;
          const float val = acc[i][j][r];
          const float sv = val > 0.f ? val + 1.f : __expf(val);
          const size_t idx = (size_t)m * Dsz + n;
          Cbf[idx] = f2b(val * cbfs);
          selu[idx] = f2b(sv);
          pdv += sv * zq[j];
        }
        pdv += __shfl_xor(pdv, 1);
        pdv += __shfl_xor(pdv, 2);
        pdv += __shfl_xor(pdv, 4);
        pdv += __shfl_xor(pdv, 8);
        if (l15 == 0) {
          const int b = m >> 11, s = m & 2047;
          atomicAdd(dens + ((b << 2) + h) * Ssz + s, pdv);
        }
      }
    }
  } else {
#pragma unroll
    for (int j = 0; j < 4; ++j) {
      const int n = n0 + nw + j * 16 + l15;
      const float bv = bias ? bias[n] : 0.f;
#pragma unroll
      for (int i = 0; i < 4; ++i) {
#pragma unroll
        for (int r = 0; r < 4; ++r) {
          const int m = m0 + mw + i * 16 + quad * 4 + r;
          const float val = acc[i][j][r] + bv;
          const size_t idx = (size_t)m * Dsz + n;
          if (C32) C32[idx] = val;
          if (Cbf) Cbf[idx] = f2b(val * cbfs);
        }
      }
    }
  }
}

// ---------------------------------------------------------------------------
// V [b][s][h*256+e] fp32 -> V^T bf16 [bh][e][s]
// ---------------------------------------------------------------------------
__global__ __launch_bounds__(256) void transpose_v(const float* __restrict__ V,
                                                   u16* __restrict__ Vt) {
  __shared__ u16 tile[32 * 36];
  const int t = threadIdx.x;
  const int s0 = blockIdx.x * 32, e0 = blockIdx.y * 32, bh = blockIdx.z;
  const int b = bh >> 2, h = bh & 3;
  {
    const int s_l = t >> 3, e8 = (t & 7) * 4;
    float4 v = *(const float4*)(V + ((size_t)(b * Ssz) + s0 + s_l) * Dsz + h * HDsz + e0 + e8);
    uint2 r; r.x = pk2(v.x, v.y); r.y = pk2(v.z, v.w);
    *(uint2*)&tile[s_l * 36 + e8] = r;
  }
  __syncthreads();
  {
    const int e_l = t >> 3, s4 = (t & 7) * 4;
    u16 a = tile[(s4 + 0) * 36 + e_l], b2 = tile[(s4 + 1) * 36 + e_l];
    u16 c = tile[(s4 + 2) * 36 + e_l], d = tile[(s4 + 3) * 36 + e_l];
    uint2 r; r.x = (unsigned)a | ((unsigned)b2 << 16);
    r.y = (unsigned)c | ((unsigned)d << 16);
    *(uint2*)(Vt + ((size_t)bh * HDsz + e0 + e_l) * Ssz + s0 + s4) = r;
  }
}

// ---------------------------------------------------------------------------
// bf16 [b,s][h*256+c] -> bf16 [bh][c][s]  (used for SKb->SKt and Wb16->Wt)
// ---------------------------------------------------------------------------
__global__ __launch_bounds__(256) void transpose_b16(const u16* __restrict__ src,
                                                     u16* __restrict__ dst) {
  __shared__ u16 tile[32 * 36];
  const int t = threadIdx.x;
  const int s0 = blockIdx.x * 32, c0 = blockIdx.y * 32, bh = blockIdx.z;
  const int b = bh >> 2, h = bh & 3;
  {
    const int s_l = t >> 3, c8 = (t & 7) * 4;
    uint2 v = *(const uint2*)(src + ((size_t)(b * Ssz) + s0 + s_l) * Dsz + h * HDsz + c0 + c8);
    *(uint2*)&tile[s_l * 36 + c8] = v;
  }
  __syncthreads();
  {
    const int c_l = t >> 3, s4 = (t & 7) * 4;
    u16 a = tile[(s4 + 0) * 36 + c_l], b2 = tile[(s4 + 1) * 36 + c_l];
    u16 c = tile[(s4 + 2) * 36 + c_l], d = tile[(s4 + 3) * 36 + c_l];
    uint2 r; r.x = (unsigned)a | ((unsigned)b2 << 16);
    r.y = (unsigned)c | ((unsigned)d << 16);
    *(uint2*)(dst + ((size_t)bh * HDsz + c0 + c_l) * Ssz + s0 + s4) = r;
  }
}

// ---------------------------------------------------------------------------
// mem fp32 [h][d][e] -> memT bf16 [h][e][d].  grid (8, 8, 4).
// ---------------------------------------------------------------------------
__global__ __launch_bounds__(256) void transpose_mem(const float* __restrict__ mem,
                                                     u16* __restrict__ memT) {
  __shared__ u16 tile[32 * 36];
  const int t = threadIdx.x;
  const int d0 = blockIdx.x * 32, e0 = blockIdx.y * 32, h = blockIdx.z;
  {
    const int d_l = t >> 3, e8 = (t & 7) * 4;
    float4 v = *(const float4*)(mem + (size_t)h * 65536 + (size_t)(d0 + d_l) * HDsz + e0 + e8);
    uint2 r; r.x = pk2(v.x, v.y); r.y = pk2(v.z, v.w);
    *(uint2*)&tile[d_l * 36 + e8] = r;
  }
  __syncthreads();
  {
    const int e_l = t >> 3, d4 = (t & 7) * 4;
    u16 a = tile[(d4 + 0) * 36 + e_l], b2 = tile[(d4 + 1) * 36 + e_l];
    u16 c = tile[(d4 + 2) * 36 + e_l], d = tile[(d4 + 3) * 36 + e_l];
    uint2 r; r.x = (unsigned)a | ((unsigned)b2 << 16);
    r.y = (unsigned)c | ((unsigned)d << 16);
    *(uint2*)(memT + (size_t)h * 65536 + (size_t)(e0 + e_l) * HDsz + d0 + d4) = r;
  }
}

// ---------------------------------------------------------------------------
// Flash attention, bf16 MFMA, flash-decoding split-K.  EXP2-DOMAIN.
// (unchanged: 64-row Q-block, sK dbuf + sV single = 48KB, 3 blocks/CU,
// defer-max, pack-then-shuffle, ex2.)
// ---------------------------------------------------------------------------
__global__ __launch_bounds__(256) void attn_mfma(const u16* __restrict__ Qg,
                                                 const u16* __restrict__ Kg,
                                                 const u16* __restrict__ Vtg,
                                                 float* __restrict__ At,
                                                 float* __restrict__ Pb,
                                                 float* __restrict__ mlb) {
  // entry = qt | (cc<<6) | (split<<7); sorted by chunk size desc
  static const unsigned char tab[52] = {
      (unsigned char)(31|0x80), (unsigned char)(31|0xC0),
      (unsigned char)(30|0x80), (unsigned char)(30|0xC0),
      (unsigned char)(29|0x80), (unsigned char)(29|0xC0),
      (unsigned char)(28|0x80), (unsigned char)(28|0xC0),
      (unsigned char)(27|0x80), (unsigned char)(27|0xC0),
      (unsigned char)(26|0x80), (unsigned char)(26|0xC0),
      (unsigned char)(25|0x80), (unsigned char)(25|0xC0),
      (unsigned char)(24|0x80), (unsigned char)(24|0xC0),
      (unsigned char)(23|0x80), (unsigned char)(23|0xC0),
      11,
      (unsigned char)(22|0x80), (unsigned char)(22|0xC0),
      (unsigned char)(21|0x80), (unsigned char)(21|0xC0),
      10,
      (unsigned char)(20|0x80), (unsigned char)(20|0xC0),
      (unsigned char)(19|0x80), (unsigned char)(19|0xC0),
      9,
      (unsigned char)(18|0x80), (unsigned char)(18|0xC0),
      (unsigned char)(17|0x80), (unsigned char)(17|0xC0),
      8,
      (unsigned char)(16|0x80), (unsigned char)(16|0xC0),
      (unsigned char)(15|0x80), (unsigned char)(15|0xC0),
      7,
      (unsigned char)(14|0x80), (unsigned char)(14|0xC0),
      (unsigned char)(13|0x80), (unsigned char)(13|0xC0),
      6,
      (unsigned char)(12|0x80), (unsigned char)(12|0xC0),
      5, 4, 3, 2, 1, 0};
  const int e = tab[blockIdx.x];
  const int qt = e & 63, cc = (e >> 6) & 1;
  const bool split = (e >> 7) != 0;
  const int bh = blockIdx.y, b = bh >> 2, h = bh & 3;
  const int tid = threadIdx.x, w = tid >> 6, lane = tid & 63;
  const int quad = lane >> 4, l15 = lane & 15;
  __shared__ u16 sK[2][32 * 256];   // [buf][s-row][d-col], slots swizzled by row&7
  __shared__ u16 sV[256 * 32];      // [e-row][s-col], slots swizzled by (row>>1)&3
  const int q0w = qt * 64 + w * 16;
  bf16x8 qf[8];
  {
    const u16* qp = Qg + ((size_t)(b * Ssz) + q0w + l15) * Dsz + h * HDsz + quad * 8;
#pragma unroll
    for (int dd = 0; dd < 8; ++dd) qf[dd] = *(const bf16x8*)(qp + dd * 32);
  }
  f32x4 o[16] = {};
  float m_old = -1e30f, l = 0.f;
  const int nkt = 2 * qt + 2, half = qt + 1;
  const int kt_lo = (split && cc) ? half : 0;
  const int kt_hi = (split && !cc) ? half : nkt;
  const u16* kstage = Kg + ((size_t)(b * Ssz) + (tid >> 5)) * Dsz + h * HDsz
                      + (((tid & 31) ^ ((tid >> 5) & 7)) << 3);
  const u16* vstage = Vtg + ((size_t)bh * HDsz + (tid >> 2)) * Ssz
                      + (((tid & 3) ^ ((tid >> 3) & 3)) << 3);
  int bufc = 0;
  {  // prologue: prefetch first K tile into buffer 0
    const u16* kp = kstage + (size_t)(kt_lo * 32) * Dsz;
#pragma unroll
    for (int i = 0; i < 4; ++i)
      gld16(kp + (size_t)i * 8 * Dsz, &sK[0][w * 512 + i * 2048]);
  }
  for (int kt = kt_lo; kt < kt_hi; ++kt) {
    const int j0 = kt * 32;
    __syncthreads();  // A: K(kt) landed; all waves done with sV (PV of kt-1)
    {  // stage V(kt) into the single V buffer; lands by barrier B
      const u16* vp = vstage + kt * 32;
#pragma unroll
      for (int i = 0; i < 4; ++i)
        gld16(vp + (size_t)i * 64 * Ssz, &sV[w * 512 + i * 2048]);
    }
    if (kt + 1 < kt_hi) {  // prefetch next K tile into the other buffer
      const u16* kp = kstage + (size_t)((kt + 1) * 32) * Dsz;
      const int bn = bufc ^ 1;
#pragma unroll
      for (int i = 0; i < 4; ++i)
        gld16(kp + (size_t)i * 8 * Dsz, &sK[bn][w * 512 + i * 2048]);
    }
    // QK^T: two half-chains per score vector (halves dependent-MFMA depth)
    f32x4 s0a = {}, s0b = {}, s1a = {}, s1b = {};
#pragma unroll
    for (int dd = 0; dd < 4; ++dd) {
      const int c0 = ((dd * 4 + quad) ^ (l15 & 7)) << 3;  // (16+l15)&7 == l15&7
      const int c1 = (((dd + 4) * 4 + quad) ^ (l15 & 7)) << 3;
      bf16x8 a0 = *(const bf16x8*)&sK[bufc][l15 * 256 + c0];
      bf16x8 a1 = *(const bf16x8*)&sK[bufc][(16 + l15) * 256 + c0];
      bf16x8 b0 = *(const bf16x8*)&sK[bufc][l15 * 256 + c1];
      bf16x8 b1 = *(const bf16x8*)&sK[bufc][(16 + l15) * 256 + c1];
      s0a = __builtin_amdgcn_mfma_f32_16x16x32_bf16(a0, qf[dd], s0a, 0, 0, 0);
      s1a = __builtin_amdgcn_mfma_f32_16x16x32_bf16(a1, qf[dd], s1a, 0, 0, 0);
      s0b = __builtin_amdgcn_mfma_f32_16x16x32_bf16(b0, qf[dd + 4], s0b, 0, 0, 0);
      s1b = __builtin_amdgcn_mfma_f32_16x16x32_bf16(b1, qf[dd + 4], s1b, 0, 0, 0);
    }
    f32x4 s0v = s0a + s0b, s1v = s1a + s1b;
    const int qg = q0w + l15;
    float p[8];
#pragma unroll
    for (int r = 0; r < 4; ++r) {
      const int kg = j0 + quad * 4 + r;
      p[r] = (kg <= qg) ? s0v[r] : -1e30f;
      p[4 + r] = (kg + 16 <= qg) ? s1v[r] : -1e30f;
    }
    float mt = fmaxf(fmaxf(fmaxf(p[0], p[1]), fmaxf(p[2], p[3])),
                     fmaxf(fmaxf(p[4], p[5]), fmaxf(p[6], p[7])));
    mt = fmaxf(mt, __shfl_xor(mt, 16));
    mt = fmaxf(mt, __shfl_xor(mt, 32));
    // defer-max: keep m_old when max growth <= 11 (log2 units; p <= 2^11)
    const bool keep = __all(mt - m_old <= 11.0f);
    const float m_new = keep ? m_old : fmaxf(m_old, mt);
    float ts = 0.f;
#pragma unroll
    for (int i = 0; i < 8; ++i) { p[i] = ex2(p[i] - m_new); ts += p[i]; }
    ts += __shfl_xor(ts, 16);
    ts += __shfl_xor(ts, 32);
    if (keep) {
      l += ts;
    } else {
      const float alpha = ex2(m_old - m_new);
      l = l * alpha + ts;
      m_old = m_new;
      const float a0_ = __shfl(alpha, (lane & 48) | (quad * 4 + 0));
      const float a1_ = __shfl(alpha, (lane & 48) | (quad * 4 + 1));
      const float a2_ = __shfl(alpha, (lane & 48) | (quad * 4 + 2));
      const float a3_ = __shfl(alpha, (lane & 48) | (quad * 4 + 3));
#pragma unroll
      for (int ds = 0; ds < 16; ++ds) {
        o[ds][0] *= a0_; o[ds][1] *= a1_; o[ds][2] *= a2_; o[ds][3] *= a3_;
      }
    }
    const unsigned a0p = pk2(p[0], p[1]), a1p = pk2(p[2], p[3]);
    const unsigned b0p = pk2(p[4], p[5]), b1p = pk2(p[6], p[7]);
    const int sAl = l15 | ((quad & 1) << 5);
    const int sBl = sAl | 16;
    const unsigned xa0 = __shfl(a0p, sAl), xa1 = __shfl(a1p, sAl);
    const unsigned xb0 = __shfl(b0p, sAl), xb1 = __shfl(b1p, sAl);
    const unsigned ya0 = __shfl(a0p, sBl), ya1 = __shfl(a1p, sBl);
    const unsigned yb0 = __shfl(b0p, sBl), yb1 = __shfl(b1p, sBl);
    const bool hi2 = quad >= 2;
    uint4 pkv;
    pkv.x = hi2 ? xb0 : xa0;
    pkv.y = hi2 ? xb1 : xa1;
    pkv.z = hi2 ? yb0 : ya0;
    pkv.w = hi2 ? yb1 : ya1;
    bf16x8 pf = *(bf16x8*)&pkv;
    const int vc0 = (quad ^ ((l15 >> 1) & 3)) << 3;  // (row>>1)&3 == (l15>>1)&3
    __syncthreads();  // B: V(kt) landed (also early-drains K(kt+1))
#pragma unroll
    for (int ds = 0; ds < 16; ++ds) {
      bf16x8 bv = *(const bf16x8*)&sV[(ds * 16 + l15) * 32 + vc0];
      o[ds] = __builtin_amdgcn_mfma_f32_16x16x32_bf16(pf, bv, o[ds], 0, 0, 0);
    }
    bufc ^= 1;
  }
  if (!split) {
    float lr[4];
#pragma unroll
    for (int r = 0; r < 4; ++r) lr[r] = 1.f / __shfl(l, (lane & 48) | (quad * 4 + r));
    float* ob = At + ((size_t)bh * Ssz + q0w + quad * 4) * HDsz + l15;
#pragma unroll
    for (int r = 0; r < 4; ++r)
#pragma unroll
      for (int ds = 0; ds < 16; ++ds)
        ob[(size_t)r * HDsz + ds * 16] = o[ds][r] * lr[r];
  } else {
    float* dst;
    if (cc == 0)
      dst = At + ((size_t)bh * Ssz + q0w + quad * 4) * HDsz + l15;
    else
      dst = Pb + ((size_t)((bh * 20 + (qt - 12)) * 64) + w * 16 + quad * 4) * HDsz + l15;
#pragma unroll
    for (int r = 0; r < 4; ++r)
#pragma unroll
      for (int ds = 0; ds < 16; ++ds)
        dst[(size_t)r * HDsz + ds * 16] = o[ds][r];
    if (lane < 16) {
      const int idx = (bh * 20 + (qt - 12)) * 64 + w * 16 + l15;
      mlb[cc * 40960 + idx] = m_old;   // log2-domain
      mlb[cc * 40960 + 20480 + idx] = l;
    }
  }
}

// ---------------------------------------------------------------------------
// Merge the two split-K chunks for qt>=12 (log2-domain m).  grid (20, 16).
// ---------------------------------------------------------------------------
__global__ __launch_bounds__(256) void attn_merge(float* __restrict__ At,
                                                  const float* __restrict__ Pb,
                                                  const float* __restrict__ mlb) {
  const int qx = blockIdx.x, bh = blockIdx.y;
  const int t = threadIdx.x;
  const int slot = (bh * 20 + qx) * 64;
  float4* abase = (float4*)(At + ((size_t)bh * Ssz + (12 + qx) * 64) * HDsz);
  const float4* pbase = (const float4*)(Pb + (size_t)slot * HDsz);
#pragma unroll
  for (int i = 0; i < 16; ++i) {
    const int f = i * 256 + t;  // f4 index 0..4095, coalesced
    const int qr = f >> 6;
    const int idx = slot + qr;
    const float m0 = mlb[idx], l0 = mlb[20480 + idx];
    const float m1 = mlb[40960 + idx], l1 = mlb[61440 + idx];
    const float mm = fmaxf(m0, m1);
    const float w0 = ex2(m0 - mm), w1 = ex2(m1 - mm);
    const float inv = 1.f / (l0 * w0 + l1 * w1);
    float4 av = abase[f];
    float4 pv = pbase[f];
    float4 ov;
    ov.x = (av.x * w0 + pv.x * w1) * inv;
    ov.y = (av.y * w0 + pv.y * w1) * inv;
    ov.z = (av.z * w0 + pv.z * w1) * inv;
    ov.w = (av.w * w0 + pv.w * w1) * inv;
    abase[f] = ov;
  }
}

// ---------------------------------------------------------------------------
// Per-head MFMA GEMM (gld16 staging, BK=64, XOR swizzle):
// acc[m,e] = sum_d A16[m,h*256+d] * memT[h][e][d].
// mode 0: blend = g*acc/den + (1-g)*At -> bf16 (bfout)
// mode 1: bfout = bf16(Vb - acc/den)   (the W operand for mem update)
// grid (2, 64, 4).
// ---------------------------------------------------------------------------
__global__ __launch_bounds__(256) void memread_mfma(const u16* __restrict__ A16,
                                                    const u16* __restrict__ memT,
                                                    const float* __restrict__ dens,
                                                    const float* __restrict__ betas,
                                                    const float* __restrict__ At,
                                                    const float* __restrict__ Vb,
                                                    u16* __restrict__ bfout, int mode) {
  __shared__ u16 sA[128 * 64];
  __shared__ u16 sB[128 * 64];
  const int h = blockIdx.z;
  const int tid = threadIdx.x, lane = tid & 63, w = tid >> 6;
  const int quad = lane >> 4, l15 = lane & 15;
  const int mw = (w >> 1) * 64, ew = (w & 1) * 64;
  const int m0 = blockIdx.y * 128, e0t = blockIdx.x * 128;
  const int r0 = tid >> 3;
  const int seg = ((tid & 7) ^ (r0 & 7)) * 8;
  const u16* ga0 = A16 + (size_t)(m0 + r0) * Dsz + h * HDsz + seg;
  const u16* gb0 = memT + (size_t)h * 65536 + (size_t)(e0t + r0) * HDsz + seg;
  f32x4 acc[4][4] = {};
  for (int k0 = 0; k0 < HDsz; k0 += 64) {
    __syncthreads();
#pragma unroll
    for (int i = 0; i < 4; ++i) {
      gld16(ga0 + (size_t)(i * 32) * Dsz + k0, sA + i * 2048 + w * 512);
      gld16(gb0 + (size_t)(i * 32) * HDsz + k0, sB + i * 2048 + w * 512);
    }
    __syncthreads();
#pragma unroll
    for (int dd = 0; dd < 2; ++dd) {
      bf16x8 af[4], bfr[4];
#pragma unroll
      for (int i = 0; i < 4; ++i) {
        const int sl = ((quad + 4 * dd) ^ (l15 & 7)) * 8;
        af[i] = *(const bf16x8*)&sA[(mw + i * 16 + l15) * 64 + sl];
        bfr[i] = *(const bf16x8*)&sB[(ew + i * 16 + l15) * 64 + sl];
      }
#pragma unroll
      for (int i = 0; i < 4; ++i)
#pragma unroll
        for (int j = 0; j < 4; ++j)
          acc[i][j] = __builtin_amdgcn_mfma_f32_16x16x32_bf16(af[i], bfr[j], acc[i][j], 0, 0, 0);
    }
  }
  const float g = 1.f / (1.f + __expf(-betas[h]));
#pragma unroll
  for (int i = 0; i < 4; ++i) {
#pragma unroll
    for (int r = 0; r < 4; ++r) {
      const int m = m0 + mw + i * 16 + quad * 4 + r;
      const int b = m >> 11, s = m & 2047;
      const int rowidx = ((b << 2) + h) * Ssz + s;
      const float inv = 1.f / (dens[rowidx] + 1e-6f);
#pragma unroll
      for (int j = 0; j < 4; ++j) {
        const int e = e0t + ew + j * 16 + l15;
        const float av = acc[i][j][r] * inv;
        if (mode == 0) {
          const float a = At[(size_t)rowidx * HDsz + e];
          bfout[(size_t)m * Dsz + h * HDsz + e] = f2b(g * av + (1.f - g) * a);
        } else {
          const float vv = Vb[(size_t)m * Dsz + h * HDsz + e];
          bfout[(size_t)m * Dsz + h * HDsz + e] = f2b(vv - av);
        }
      }
    }
  }
}

// ---------------------------------------------------------------------------
// mem partials (gld16 dual-staged GEMM over k=s):
// P[(h*16+chunk)][d][e] = sum_{s in chunk} SKt[bh][d][s] * Wt[bh][e][s]
// grid (4 de, 4 h, 16 chunk); K=512 per chunk, BK=64.
// ---------------------------------------------------------------------------
__global__ __launch_bounds__(256) void mem_update_mfma(const u16* __restrict__ SKt,
                                                       const u16* __restrict__ Wt,
                                                       float* __restrict__ P) {
  __shared__ u16 sA[128 * 64];
  __shared__ u16 sB[128 * 64];
  const int de = blockIdx.x;
  const int d0 = (de >> 1) * 128, e0 = (de & 1) * 128;
  const int h = blockIdx.y, chunk = blockIdx.z;
  const int b = chunk >> 2, s0 = (chunk & 3) * 512;
  const int bh = b * 4 + h;
  const int tid = threadIdx.x, lane = tid & 63, w = tid >> 6;
  const int quad = lane >> 4, l15 = lane & 15;
  const int dw = (w >> 1) * 64, ew = (w & 1) * 64;
  const int r0 = tid >> 3;
  const int seg = ((tid & 7) ^ (r0 & 7)) * 8;
  const u16* ga0 = SKt + ((size_t)bh * HDsz + d0 + r0) * Ssz + s0 + seg;
  const u16* gb0 = Wt + ((size_t)bh * HDsz + e0 + r0) * Ssz + s0 + seg;
  f32x4 acc[4][4] = {};
  for (int kk = 0; kk < 512; kk += 64) {
    __syncthreads();
#pragma unroll
    for (int i = 0; i < 4; ++i) {
      gld16(ga0 + (size_t)(i * 32) * Ssz + kk, sA + i * 2048 + w * 512);
      gld16(gb0 + (size_t)(i * 32) * Ssz + kk, sB + i * 2048 + w * 512);
    }
    __syncthreads();
#pragma unroll
    for (int dd = 0; dd < 2; ++dd) {
      bf16x8 af[4], bfr[4];
#pragma unroll
      for (int i = 0; i < 4; ++i) {
        const int sl = ((quad + 4 * dd) ^ (l15 & 7)) * 8;
        af[i] = *(const bf16x8*)&sA[(dw + i * 16 + l15) * 64 + sl];
        bfr[i] = *(const bf16x8*)&sB[(ew + i * 16 + l15) * 64 + sl];
      }
#pragma unroll
      for (int i = 0; i < 4; ++i)
#pragma unroll
        for (int j = 0; j < 4; ++j)
          acc[i][j] = __builtin_amdgcn_mfma_f32_16x16x32_bf16(af[i], bfr[j], acc[i][j], 0, 0, 0);
    }
  }
  float* Pp = P + ((size_t)(h * 16 + chunk)) * 65536;
#pragma unroll
  for (int i = 0; i < 4; ++i)
#pragma unroll
    for (int r = 0; r < 4; ++r) {
      const int d = d0 + dw + i * 16 + quad * 4 + r;
#pragma unroll
      for (int j = 0; j < 4; ++j) {
        const int e = e0 + ew + j * 16 + l15;
        Pp[(size_t)d * HDsz + e] = acc[i][j][r];
      }
    }
}

// ---------------------------------------------------------------------------
// outmem = mem + 0.25 * sum_{chunk} P[h*16+chunk]
// ---------------------------------------------------------------------------
__global__ __launch_bounds__(256) void mem_reduce(const float4* __restrict__ P,
                                                  const float4* __restrict__ mem,
                                                  float4* __restrict__ outmem) {
  const int gid = blockIdx.x * 256 + threadIdx.x;
  const int h = gid >> 14, off = gid & 16383;
  float sx = 0.f, sy = 0.f, sz = 0.f, sw = 0.f;
#pragma unroll 4
  for (int c = 0; c < 16; ++c) {
    float4 v = P[((size_t)(h * 16 + c) << 14) + off];
    sx += v.x; sy += v.y; sz += v.z; sw += v.w;
  }
  float4 m = mem[gid];
  float4 o;
  o.x = m.x + 0.25f * sx; o.y = m.y + 0.25f * sy;
  o.z = m.z + 0.25f * sz; o.w = m.w + 0.25f * sw;
  outmem[gid] = o;
}

// ---------------------------------------------------------------------------
// z_new[h][d] = z[h][d] + (1/B) sum_{b,s} sk[b,h,s,d]   (bf16 SKb source)
// grid 512 (4 h x 128 chunks of 64 rows), block reduce, 1 atomic add/block.
// ---------------------------------------------------------------------------
__global__ __launch_bounds__(256) void z_update(const u16* __restrict__ SKb,
                                                const float* __restrict__ z_in,
                                                float* __restrict__ z_out) {
  __shared__ float4 red[256];
  const int h = blockIdx.x >> 7, chunk = blockIdx.x & 127;
  const int wid = threadIdx.x >> 6, lane = threadIdx.x & 63;
  const int m0 = chunk * 64;
  float4 s = {0.f, 0.f, 0.f, 0.f};
#pragma unroll
  for (int i = 0; i < 16; ++i) {
    const int row = m0 + i * 4 + wid;
    uint2 v = *(const uint2*)(SKb + (size_t)row * Dsz + h * HDsz + lane * 4);
    s.x += b2f(v.x & 0xFFFFu);
    s.y += __uint_as_float(v.x & 0xFFFF0000u);
    s.z += b2f(v.y & 0xFFFFu);
    s.w += __uint_as_float(v.y & 0xFFFF0000u);
  }
  red[wid * 64 + lane] = s;
  __syncthreads();
  if (wid == 0) {
    float4 a = red[lane], b = red[64 + lane], c = red[128 + lane], d = red[192 + lane];
    a.x = (a.x + b.x + c.x + d.x) * 0.25f;
    a.y = (a.y + b.y + c.y + d.y) * 0.25f;
    a.z = (a.z + b.z + c.z + d.z) * 0.25f;
    a.w = (a.w + b.w + c.w + d.w) * 0.25f;
    if (chunk == 0) {
      const float4 z4 = *(const float4*)(z_in + h * HDsz + lane * 4);
      a.x += z4.x; a.y += z4.y; a.z += z4.z; a.w += z4.w;
    }
    float* zp = z_out + h * HDsz + lane * 4;
    atomicAdd(zp + 0, a.x);
    atomicAdd(zp + 1, a.y);
    atomicAdd(zp + 2, a.z);
    atomicAdd(zp + 3, a.w);
  }
}

// ---------------------------------------------------------------------------
extern "C" void kernel_launch(void* const* d_in, const int* in_sizes, int n_in,
                              void* d_out, int out_size, void* d_ws, size_t ws_size,
                              hipStream_t stream) {
  (void)in_sizes; (void)n_in; (void)out_size; (void)ws_size;
  const float* Hs = (const float*)d_in[0];
  const float* Wq = (const float*)d_in[1];
  const float* Wk = (const float*)d_in[2];
  const float* Wv = (const float*)d_in[3];
  const float* Wo = (const float*)d_in[4];
  const float* bo = (const float*)d_in[5];
  const float* betas = (const float*)d_in[6];
  const float* mem = (const float*)d_in[7];
  const float* z = (const float*)d_in[8];

  // fp32 workspace region
  float* ws = (float*)d_ws;
  float* Qb = ws;                    // 8388608 floats: now only hosts Wt (bf16)
  float* Kb = ws + 8388608;          // now only hosts SKb (bf16)
  float* Vb = ws + 16777216;         // V fp32
  float* At = ws + 25165824;         // attn out fp32 [bh][s][e]
  float* dq = ws + 33554432;         // 32768 (atomic accum, fused gemm epilogue)
  float* dk = ws + 33587200;         // 32768
  float* mlb = ws + 33619968;        // 81920 (4 planes x 20480)
  // bf16 region
  u16* ub = (u16*)(ws + 33701888);
  u16* Wqb = ub;                     // 4 x 1048576 weight copies (cvt_w4)
  u16* Wkb = ub + 1048576;
  u16* Wvb = ub + 2097152;
  u16* Wob = ub + 3145728;
  u16* Qbf = ub + 4194304;           // bf16 Q (log2e-scaled); later bf16 blend
  u16* Kbf = ub + 12582912;          // bf16 K (attn operand)
  u16* Vt = ub + 20971520;           // 8388608 u16: Hs bf16 first, then V^T
  u16* Hsb = Vt;                     // alias: dead once transpose_v runs
  u16* SQb = ub + 29360128;          // bf16 sq [m][1024] (gemm epilogue)
  u16* memT = ub + 37748736;         // 262144 u16: mem^T bf16 [h][e][d]
  // time-sliced aliases:
  u16* SKb = (u16*)Kb;               // bf16 sk (Kb fp32 region now unused)
  u16* SKt = Vt;                     // sk^T [bh][d][s] (Vt dead after attn)
  u16* Wb16 = (u16*)At;              // bf16 W [m][1024] (At dead after memread0)
  u16* Wt = (u16*)Qb;                // W^T [bh][e][s] (Qb region unused)
  float* Pb = (float*)d_out;         // split-attn partials (21 MB), dead after merge
  float* P = (float*)d_out;          // mem partials (16.8 MB)

  float* out = (float*)d_out;                 // 8192x1024
  float* outmem = out + (size_t)Msz * Dsz;    // 4x256x256
  float* outz = outmem + Hsz * HDsz * HDsz;   // 4x256

  hipMemsetAsync(outz, 0, (size_t)(Hsz * HDsz) * sizeof(float), stream);
  hipMemsetAsync(dq, 0, (size_t)65536 * sizeof(float), stream);  // dq+dk

  cvt_w4<<<4096, 256, 0, stream>>>((const float4*)Wq, (const float4*)Wk,
                                   (const float4*)Wv, (const float4*)Wo, ub);
  cvt_bf16<<<8192, 256, 0, stream>>>((const float4*)Hs, Hsb);
  transpose_mem<<<dim3(8, 8, 4), 256, 0, stream>>>(mem, memT);

  dim3 gg(8, 64);  // N/128, M/128
  // Q/K projections with fused elu+dens epilogue (replaces eludens pass)
  gemm_lds<<<gg, 256, 0, stream>>>(Hsb, Wqb, nullptr, nullptr, Qbf, LOG2E, SQb, dq, z);
  gemm_lds<<<gg, 256, 0, stream>>>(Hsb, Wkb, nullptr, nullptr, Kbf, 1.f, SKb, dk, z);
  gemm_lds<<<gg, 256, 0, stream>>>(Hsb, Wvb, nullptr, Vb, nullptr, 1.f, nullptr, nullptr, nullptr);

  transpose_v<<<dim3(64, 8, 16), 256, 0, stream>>>(Vb, Vt);
  attn_mfma<<<dim3(52, 16), 256, 0, stream>>>(Qbf, Kbf, Vt, At, Pb, mlb);
  attn_merge<<<dim3(20, 16), 256, 0, stream>>>(At, Pb, mlb);

  transpose_b16<<<dim3(64, 8, 16), 256, 0, stream>>>(SKb, SKt);

  memread_mfma<<<dim3(2, 64, 4), 256, 0, stream>>>(SQb, memT, dq, betas, At, nullptr, Qbf, 0);
  memread_mfma<<<dim3(2, 64, 4), 256, 0, stream>>>(SKb, memT, dk, betas, nullptr, Vb, Wb16, 1);
  transpose_b16<<<dim3(64, 8, 16), 256, 0, stream>>>(Wb16, Wt);

  mem_update_mfma<<<dim3(4, 4, 16), 256, 0, stream>>>(SKt, Wt, P);
  mem_reduce<<<256, 256, 0, stream>>>((const float4*)P, (const float4*)mem, (float4*)outmem);
  z_update<<<512, 256, 0, stream>>>(SKb, z, outz);

  gemm_lds<<<gg, 256, 0, stream>>>(Qbf, Wob, bo, out, nullptr, 1.f, nullptr, nullptr, nullptr);
}